// Round 7
// baseline (136.815 us; speedup 1.0000x reference)
//
#include <hip/hip_runtime.h>
#include <math.h>

#define N_DETC 128
#define N_TC   2048
#define N_FC   1025
#define NXC    128
#define NYC    256
#define NBCC   16     // B*C = 8*2

typedef float f32x2 __attribute__((ext_vector_type(2)));

__device__ __forceinline__ float2 cmulf(float2 a, float2 b){
    return make_float2(a.x*b.x - a.y*b.y, a.x*b.y + a.y*b.x);
}

#if __has_builtin(__builtin_amdgcn_sinf) && __has_builtin(__builtin_amdgcn_cosf)
__device__ __forceinline__ float sin_rev(float tf){ return __builtin_amdgcn_sinf(tf); }   // sin(2*pi*tf)
__device__ __forceinline__ float cos_rev(float tf){ return __builtin_amdgcn_cosf(tf); }
#else
__device__ __forceinline__ float sin_rev(float tf){ return __sinf(6.28318530718f * tf); }
__device__ __forceinline__ float cos_rev(float tf){ return __cosf(6.28318530718f * tf); }
#endif

// complex MAC via packed fp32 FMA:
//   acc.lo += s.lo*p.lo - s.hi*p.hi   (aR += Sr*pc - Si*ps)
//   acc.hi += s.lo*p.hi + s.hi*p.lo   (aI += Sr*ps + Si*pc)
#define CMAC(accv, sv, pv)                                                                 \
    asm("v_pk_fma_f32 %0, %1, %2, %0 op_sel:[0,0,0] op_sel_hi:[0,1,1]"                     \
        : "+v"(accv) : "v"(sv), "v"(pv));                                                  \
    asm("v_pk_fma_f32 %0, %1, %2, %0 op_sel:[1,1,0] op_sel_hi:[1,0,1] neg_lo:[0,1,0]"      \
        : "+v"(accv) : "v"(sv), "v"(pv));

// ---------------- stats stage 1 ----------------
__global__ __launch_bounds__(256) void k_stats1(const float* __restrict__ sino,
                                                float* __restrict__ psum,
                                                float* __restrict__ psq){
    int bc    = blockIdx.x >> 6;
    int chunk = blockIdx.x & 63;
    const float4* p = (const float4*)(sino + (size_t)bc * (N_DETC * N_TC)) + (size_t)chunk * 1024;
    float s = 0.f, q = 0.f;
    #pragma unroll
    for (int i = 0; i < 4; ++i){
        float4 v = p[threadIdx.x + i * 256];
        s += v.x + v.y + v.z + v.w;
        q += v.x*v.x + v.y*v.y + v.z*v.z + v.w*v.w;
    }
    #pragma unroll
    for (int m = 1; m < 64; m <<= 1){
        s += __shfl_xor(s, m, 64);
        q += __shfl_xor(q, m, 64);
    }
    __shared__ float ls[4], lq[4];
    int w = threadIdx.x >> 6, lane = threadIdx.x & 63;
    if (lane == 0){ ls[w] = s; lq[w] = q; }
    __syncthreads();
    if (threadIdx.x == 0){
        psum[blockIdx.x] = ls[0] + ls[1] + ls[2] + ls[3];
        psq[blockIdx.x]  = lq[0] + lq[1] + lq[2] + lq[3];
    }
}

// ---------------- stats stage 2 ----------------
__global__ void k_stats2(const float* __restrict__ psum,
                         const float* __restrict__ psq,
                         const float* __restrict__ apod,
                         float* __restrict__ stat){
    int bc = blockIdx.x, t = threadIdx.x;   // 64 threads
    float s = psum[bc * 64 + t], q = psq[bc * 64 + t];
    float a = (bc == 0) ? (apod[t] + apod[t + 64]) : 0.f;
    #pragma unroll
    for (int m = 1; m < 64; m <<= 1){
        s += __shfl_xor(s, m, 64);
        q += __shfl_xor(q, m, 64);
        a += __shfl_xor(a, m, 64);
    }
    if (t == 0){
        const float inv_n = 1.f / (float)(N_DETC * N_TC);
        float mean = s * inv_n;
        float var  = q * inv_n - mean * mean;
        stat[bc]      = mean;
        stat[16 + bc] = rsqrtf(fmaxf(var, 0.f) + 1.1920929e-7f);
        if (bc == 0) stat[32] = a;
    }
}

// ---------------- temporal FFT ----------------
__global__ __launch_bounds__(256) void k_tfft(const float* __restrict__ sino,
                                              const float* __restrict__ apod,
                                              const float* __restrict__ stat,
                                              float2* __restrict__ spec){
    int row = blockIdx.x;            // bc*128 + d
    int bc = row >> 7, d = row & 127;
    __shared__ float2 a[N_TC];       // 16 KB
    float mean = stat[bc];
    float scl  = stat[16 + bc] * apod[d];
    const float* p = sino + (size_t)row * N_TC;
    for (int t = threadIdx.x; t < N_TC; t += 256){
        float v = (p[t] - mean) * scl;
        int r = __brev((unsigned)t) >> 21;   // 11-bit reverse
        a[r] = make_float2(v, 0.f);
    }
    __syncthreads();
    for (int s = 1; s <= 11; ++s){
        int half = 1 << (s - 1);
        for (int j = threadIdx.x; j < N_TC / 2; j += 256){
            int g = j >> (s - 1);
            int k = j & (half - 1);
            int i1 = (g << s) + k;
            int i2 = i1 + half;
            float ang = -(float)M_PI * (float)k / (float)half;
            float sn, cs; __sincosf(ang, &sn, &cs);
            float2 u = a[i1], v = a[i2];
            float2 t = make_float2(v.x * cs - v.y * sn, v.x * sn + v.y * cs);
            a[i1] = make_float2(u.x + t.x, u.y + t.y);
            a[i2] = make_float2(u.x - t.x, u.y - t.y);
        }
        __syncthreads();
    }
    float2* o = spec + (size_t)row * N_FC;
    for (int f = threadIdx.x; f < N_FC; f += 256) o[f] = a[f];
}

// ---------------- fused detector FFT + mask/weight + transpose + kzJ table ----------------
__global__ __launch_bounds__(256) void k_dft(const float2* __restrict__ spec,
                                             float* __restrict__ spec_th,
                                             float4* __restrict__ kzJ){
    int bid = blockIdx.x;
    int f = (bid < 1024) ? ((bid & 7) * 128 + (bid >> 3)) : 1024;  // XCD-contiguous f ranges
    __shared__ float2 col[16][128];   // 16 KB
    int tid = threadIdx.x;
    #pragma unroll
    for (int k2 = 0; k2 < 8; ++k2){
        int idx = tid + (k2 << 8);            // 0..2047
        int bc = idx >> 7, kd = idx & 127;
        col[bc][__brev((unsigned)kd) >> 25] = spec[((size_t)(bc * 128 + kd)) * N_FC + f];
    }
    float fr = (float)f * 19531.25f;          // Hz
    float oc = fr * (1.0f / 1540.0f);         // cycles/m
    if (tid < 128){
        int kd = tid;
        int sdx = (kd < 64) ? kd : kd - 128;
        float b = (float)sdx * 26.0416666f;   // 1/(128*3e-4) cycles/m
        float kq = oc * oc - b * b;
        float kzr = (kq > 0.f) ? sqrtf(kq) : 0.f;
        float tj = 9.6e-3f * kzr;             // 64*DY*kz in revolutions
        tj -= floorf(tj);
        kzJ[(size_t)kd * N_FC + f] = make_float4(kzr, cos_rev(tj), sin_rev(tj), 0.f);
    }
    __syncthreads();
    for (int s = 1; s <= 7; ++s){
        int half = 1 << (s - 1);
        #pragma unroll
        for (int k2 = 0; k2 < 4; ++k2){
            int j = tid + (k2 << 8);          // 0..1023 : bc*64 + butterfly
            int bc = j >> 6, jj = j & 63;
            int g = jj >> (s - 1);
            int k = jj & (half - 1);
            int i1 = (g << s) + k;
            int i2 = i1 + half;
            float ang = -(float)M_PI * (float)k / (float)half;
            float sn, cs; __sincosf(ang, &sn, &cs);
            float2 u = col[bc][i1], v = col[bc][i2];
            float2 t = make_float2(v.x * cs - v.y * sn, v.x * sn + v.y * cs);
            col[bc][i1] = make_float2(u.x + t.x, u.y + t.y);
            col[bc][i2] = make_float2(u.x - t.x, u.y - t.y);
        }
        __syncthreads();
    }
    float fw = (f == 0 || f == 1024) ? 1.f : 2.f;
    #pragma unroll
    for (int k2 = 0; k2 < 8; ++k2){
        int idx = tid + (k2 << 8);            // 0..2047
        int bc = idx & 15, kd = idx >> 4;
        int sdx = (kd < 64) ? kd : kd - 128;
        float b = (float)sdx * 26.0416666f;
        float m = (oc * oc - b * b > 0.f) ? fw : 0.f;
        float2 v = col[bc][kd];
        int h = bc >> 3;
        float* dst = spec_th + ((size_t)h * (128 * N_FC) + (size_t)kd * N_FC + f) * 16 + ((bc & 7) << 1);
        *(float2*)dst = make_float2(v.x * m, v.y * m);
    }
}

// ---------------- band: wave=(kd,bch,fc); lane=y base, J-chain, packed-fp32 CMAC ----------------
__global__ __launch_bounds__(256, 4) void k_band(const float* __restrict__ spec_th,
                                                 const float4* __restrict__ kzJ,
                                                 float2* __restrict__ band_p){
    int blk = blockIdx.x;               // kd*8 + bch*4 + q
    int q   = blk & 3;
    int bch = (blk >> 2) & 1;
    int kd  = blk >> 3;
    int w    = __builtin_amdgcn_readfirstlane(threadIdx.x >> 6);
    int lane = threadIdx.x & 63;
    int fc  = q * 4 + w;                // 0..15
    int f0  = fc * 64;
    int nf  = (fc == 15) ? 65 : 64;
    const f32x2* sp = (const f32x2*)(spec_th + ((size_t)bch * 128 * N_FC + (size_t)kd * N_FC + f0) * 16);
    const float4* kj = kzJ + (size_t)kd * N_FC + f0;

    float ym0 = 1.0e-3f + 1.5e-4f * (float)lane;

    f32x2 acc[8][4];
    #pragma unroll
    for (int b = 0; b < 8; ++b)
        #pragma unroll
        for (int qy = 0; qy < 4; ++qy) acc[b][qy] = (f32x2){0.f, 0.f};

    f32x2 c[8], n[8];
    #pragma unroll
    for (int b = 0; b < 8; ++b) c[b] = sp[b];
    float4 ck = kj[0];

    for (int it = 0; it < nf; ++it){
        const f32x2* spn = sp + 8;
        #pragma unroll
        for (int b = 0; b < 8; ++b) n[b] = spn[b];
        float4 nk = kj[it + 1];

        float t  = ym0 * ck.x;
        float tf = t - floorf(t);
        float ps = sin_rev(tf);
        float pc = cos_rev(tf);
        float Jr = ck.y, Ji = ck.z;

        #pragma unroll
        for (int qy = 0; qy < 4; ++qy){
            f32x2 pcps; pcps.x = pc; pcps.y = ps;
            CMAC(acc[0][qy], c[0], pcps);
            CMAC(acc[1][qy], c[1], pcps);
            CMAC(acc[2][qy], c[2], pcps);
            CMAC(acc[3][qy], c[3], pcps);
            CMAC(acc[4][qy], c[4], pcps);
            CMAC(acc[5][qy], c[5], pcps);
            CMAC(acc[6][qy], c[6], pcps);
            CMAC(acc[7][qy], c[7], pcps);
            if (qy < 3){
                float t1  = pc * Jr;
                float npc = fmaf(-ps, Ji, t1);
                float t2  = pc * Ji;
                float nps = fmaf(ps, Jr, t2);
                pc = npc; ps = nps;
            }
        }
        #pragma unroll
        for (int b = 0; b < 8; ++b) c[b] = n[b];
        ck = nk;
        sp = spn;
    }

    // block reduction across 4 waves (fc sub-chunks)
    __shared__ float2 red[2][2048];     // 32 KB
    float2* slot = red[w & 1];
    if (w < 2){
        #pragma unroll
        for (int b = 0; b < 8; ++b)
            #pragma unroll
            for (int qy = 0; qy < 4; ++qy)
                slot[b * 256 + qy * 64 + lane] = make_float2(acc[b][qy].x, acc[b][qy].y);
    }
    __syncthreads();
    if (w >= 2){
        #pragma unroll
        for (int b = 0; b < 8; ++b)
            #pragma unroll
            for (int qy = 0; qy < 4; ++qy){
                float2 v = slot[b * 256 + qy * 64 + lane];
                v.x += acc[b][qy].x; v.y += acc[b][qy].y;
                slot[b * 256 + qy * 64 + lane] = v;
            }
    }
    __syncthreads();
    int t = threadIdx.x;
    float2* ob = band_p + ((size_t)(q * 128 + kd) * 16 + bch * 8) * 256;
    #pragma unroll
    for (int i = 0; i < 8; ++i){
        int idx = i * 256 + t;
        float2 v0 = red[0][idx], v1 = red[1][idx];
        ob[idx] = make_float2(v0.x + v1.x, v0.y + v1.y);
    }
}

// ---------------- final: sum 4 f-partials, 128-pt inverse DFT over kd, magnitude ----------------
__global__ __launch_bounds__(256) void k_final(const float2* __restrict__ band_p,
                                               const float* __restrict__ stat,
                                               float* __restrict__ out){
    int blk = blockIdx.x;            // bc*32 + yt
    int bc = blk >> 5, yt = blk & 31;
    __shared__ float2 ld[128][9];
    int tid = threadIdx.x;
    #pragma unroll
    for (int k2 = 0; k2 < 4; ++k2){
        int idx = tid + k2 * 256;
        int kd = idx >> 3, yi = idx & 7;
        float2 s = make_float2(0.f, 0.f);
        #pragma unroll
        for (int p = 0; p < 4; ++p){
            float2 v = band_p[(((size_t)(p * 128 + kd) * 16) + bc) * 256 + yt * 8 + yi];
            s.x += v.x; s.y += v.y;
        }
        ld[kd][yi] = s;
    }
    __syncthreads();
    int x = tid & 127, h = tid >> 7;
    float ang = (float)(2.0 * M_PI / 128.0) * (float)x;
    float sn, cs; sincosf(ang, &sn, &cs);
    float2 w = make_float2(cs, sn);
    float2 p = make_float2(1.f, 0.f);
    float aR[4] = {0.f,0.f,0.f,0.f}, aI[4] = {0.f,0.f,0.f,0.f};
    for (int kd = 0; kd < 128; ++kd){
        #pragma unroll
        for (int qq = 0; qq < 4; ++qq){
            float2 b = ld[kd][h * 4 + qq];
            aR[qq] += b.x * p.x - b.y * p.y;
            aI[qq] += b.x * p.y + b.y * p.x;
        }
        p = cmulf(p, w);
    }
    float invnorm = 1.f / (fmaxf(stat[32], 1.1920929e-7f) * 2048.f);
    #pragma unroll
    for (int qq = 0; qq < 4; ++qq){
        int y = yt * 8 + h * 4 + qq;
        out[((size_t)bc * 256 + y) * 128 + x] = sqrtf(aR[qq]*aR[qq] + aI[qq]*aI[qq]) * invnorm;
    }
}

extern "C" void kernel_launch(void* const* d_in, const int* in_sizes, int n_in,
                              void* d_out, int out_size, void* d_ws, size_t ws_size,
                              hipStream_t stream){
    const float* sino = (const float*)d_in[0];
    const float* apod = (const float*)d_in[1];
    float* out = (float*)d_out;
    float* W = (float*)d_ws;
    // workspace layout (floats):
    //   [0..63]        stat
    //   [64..1087]     psum
    //   [1088..2111]   psq
    //   spec    : 16*128*1025*2    = 4,198,400   (dead after k_dft; aliased by band_p)
    //   spec_th : 2*128*1025*16    = 4,198,400
    //   kzJ     : 128*1025*4 + 16  =   524,816
    float* psum = W + 64;
    float* psq  = W + 1088;
    float2* spec    = (float2*)(W + 2112);
    float*  spec_th = W + 2112 + 4198400;
    float4* kzJ     = (float4*)(W + 2112 + 4198400 + 4198400);
    float2* band_p  = spec;   // 4*128*16*256 float2 = 4,194,304 floats <= spec size

    k_stats1<<<NBCC * 64, 256, 0, stream>>>(sino, psum, psq);
    k_stats2<<<NBCC, 64, 0, stream>>>(psum, psq, apod, W);
    k_tfft  <<<NBCC * N_DETC, 256, 0, stream>>>(sino, apod, W, spec);
    k_dft   <<<N_FC, 256, 0, stream>>>(spec, spec_th, kzJ);
    k_band  <<<1024, 256, 0, stream>>>(spec_th, kzJ, band_p);
    k_final <<<NBCC * 32, 256, 0, stream>>>(band_p, W, out);
}

// Round 8
// 121.544 us; speedup vs baseline: 1.1256x; 1.1256x over previous
//
#include <hip/hip_runtime.h>
#include <math.h>

#define N_DETC 128
#define N_TC   2048
#define N_FC   1025
#define N_FP   1056    // padded f (33 K-steps of 32)
#define NXC    128
#define NYC    256
#define NBCC   16      // B*C = 8*2

typedef short bf16x8 __attribute__((ext_vector_type(8)));
typedef float f32x4  __attribute__((ext_vector_type(4)));

__device__ __forceinline__ float2 cmulf(float2 a, float2 b){
    return make_float2(a.x*b.x - a.y*b.y, a.x*b.y + a.y*b.x);
}

#if __has_builtin(__builtin_amdgcn_sinf) && __has_builtin(__builtin_amdgcn_cosf)
__device__ __forceinline__ float sin_rev(float tf){ return __builtin_amdgcn_sinf(tf); }   // sin(2*pi*tf)
__device__ __forceinline__ float cos_rev(float tf){ return __builtin_amdgcn_cosf(tf); }
#else
__device__ __forceinline__ float sin_rev(float tf){ return __sinf(6.28318530718f * tf); }
__device__ __forceinline__ float cos_rev(float tf){ return __cosf(6.28318530718f * tf); }
#endif

__device__ __forceinline__ ushort cvt_bf16(float x){
    uint u = __float_as_uint(x);
    return (ushort)((u + 0x7FFFu + ((u >> 16) & 1u)) >> 16);   // RNE
}

// ---------------- stats stage 1 ----------------
__global__ __launch_bounds__(256) void k_stats1(const float* __restrict__ sino,
                                                float* __restrict__ psum,
                                                float* __restrict__ psq){
    int bc    = blockIdx.x >> 6;
    int chunk = blockIdx.x & 63;
    const float4* p = (const float4*)(sino + (size_t)bc * (N_DETC * N_TC)) + (size_t)chunk * 1024;
    float s = 0.f, q = 0.f;
    #pragma unroll
    for (int i = 0; i < 4; ++i){
        float4 v = p[threadIdx.x + i * 256];
        s += v.x + v.y + v.z + v.w;
        q += v.x*v.x + v.y*v.y + v.z*v.z + v.w*v.w;
    }
    #pragma unroll
    for (int m = 1; m < 64; m <<= 1){
        s += __shfl_xor(s, m, 64);
        q += __shfl_xor(q, m, 64);
    }
    __shared__ float ls[4], lq[4];
    int w = threadIdx.x >> 6, lane = threadIdx.x & 63;
    if (lane == 0){ ls[w] = s; lq[w] = q; }
    __syncthreads();
    if (threadIdx.x == 0){
        psum[blockIdx.x] = ls[0] + ls[1] + ls[2] + ls[3];
        psq[blockIdx.x]  = lq[0] + lq[1] + lq[2] + lq[3];
    }
}

// ---------------- stats stage 2 ----------------
__global__ void k_stats2(const float* __restrict__ psum,
                         const float* __restrict__ psq,
                         const float* __restrict__ apod,
                         float* __restrict__ stat){
    int bc = blockIdx.x, t = threadIdx.x;   // 64 threads
    float s = psum[bc * 64 + t], q = psq[bc * 64 + t];
    float a = (bc == 0) ? (apod[t] + apod[t + 64]) : 0.f;
    #pragma unroll
    for (int m = 1; m < 64; m <<= 1){
        s += __shfl_xor(s, m, 64);
        q += __shfl_xor(q, m, 64);
        a += __shfl_xor(a, m, 64);
    }
    if (t == 0){
        const float inv_n = 1.f / (float)(N_DETC * N_TC);
        float mean = s * inv_n;
        float var  = q * inv_n - mean * mean;
        stat[bc]      = mean;
        stat[16 + bc] = rsqrtf(fmaxf(var, 0.f) + 1.1920929e-7f);
        if (bc == 0) stat[32] = a;
    }
}

// ---------------- temporal FFT ----------------
__global__ __launch_bounds__(256) void k_tfft(const float* __restrict__ sino,
                                              const float* __restrict__ apod,
                                              const float* __restrict__ stat,
                                              float2* __restrict__ spec){
    int row = blockIdx.x;            // bc*128 + d
    int bc = row >> 7, d = row & 127;
    __shared__ float2 a[N_TC];       // 16 KB
    float mean = stat[bc];
    float scl  = stat[16 + bc] * apod[d];
    const float* p = sino + (size_t)row * N_TC;
    for (int t = threadIdx.x; t < N_TC; t += 256){
        float v = (p[t] - mean) * scl;
        int r = __brev((unsigned)t) >> 21;   // 11-bit reverse
        a[r] = make_float2(v, 0.f);
    }
    __syncthreads();
    for (int s = 1; s <= 11; ++s){
        int half = 1 << (s - 1);
        for (int j = threadIdx.x; j < N_TC / 2; j += 256){
            int g = j >> (s - 1);
            int k = j & (half - 1);
            int i1 = (g << s) + k;
            int i2 = i1 + half;
            float ang = -(float)M_PI * (float)k / (float)half;
            float sn, cs; __sincosf(ang, &sn, &cs);
            float2 u = a[i1], v = a[i2];
            float2 t = make_float2(v.x * cs - v.y * sn, v.x * sn + v.y * cs);
            a[i1] = make_float2(u.x + t.x, u.y + t.y);
            a[i2] = make_float2(u.x - t.x, u.y - t.y);
        }
        __syncthreads();
    }
    float2* o = spec + (size_t)row * N_FC;
    for (int f = threadIdx.x; f < N_FC; f += 256) o[f] = a[f];
}

// ---------------- fused detector FFT + mask/weight -> bf16 A-planes + (kz,J1) table ----------------
__global__ __launch_bounds__(256) void k_dft(const float2* __restrict__ spec,
                                             ushort* __restrict__ Arp,
                                             ushort* __restrict__ Aip,
                                             float4* __restrict__ kzJ){
    int bid = blockIdx.x;
    int f = (bid < 1024) ? ((bid & 7) * 128 + (bid >> 3)) : 1024;  // XCD-contiguous f ranges
    __shared__ float2 col[16][128];   // 16 KB
    int tid = threadIdx.x;
    #pragma unroll
    for (int k2 = 0; k2 < 8; ++k2){
        int idx = tid + (k2 << 8);            // 0..2047
        int bc = idx >> 7, kd = idx & 127;
        col[bc][__brev((unsigned)kd) >> 25] = spec[((size_t)(bc * 128 + kd)) * N_FC + f];
    }
    float fr = (float)f * 19531.25f;          // Hz
    float oc = fr * (1.0f / 1540.0f);         // cycles/m
    if (tid < 128){
        int kd = tid;
        int sdx = (kd < 64) ? kd : kd - 128;
        float b = (float)sdx * 26.0416666f;   // 1/(128*3e-4) cycles/m
        float kq = oc * oc - b * b;
        float kzr = (kq > 0.f) ? sqrtf(kq) : 0.f;
        float tj = 1.5e-4f * kzr;             // DY*kz in revolutions
        tj -= floorf(tj);
        kzJ[(size_t)kd * N_FP + f] = make_float4(kzr, cos_rev(tj), sin_rev(tj), 0.f);
    }
    __syncthreads();
    for (int s = 1; s <= 7; ++s){
        int half = 1 << (s - 1);
        #pragma unroll
        for (int k2 = 0; k2 < 4; ++k2){
            int j = tid + (k2 << 8);          // 0..1023 : bc*64 + butterfly
            int bc = j >> 6, jj = j & 63;
            int g = jj >> (s - 1);
            int k = jj & (half - 1);
            int i1 = (g << s) + k;
            int i2 = i1 + half;
            float ang = -(float)M_PI * (float)k / (float)half;
            float sn, cs; __sincosf(ang, &sn, &cs);
            float2 u = col[bc][i1], v = col[bc][i2];
            float2 t = make_float2(v.x * cs - v.y * sn, v.x * sn + v.y * cs);
            col[bc][i1] = make_float2(u.x + t.x, u.y + t.y);
            col[bc][i2] = make_float2(u.x - t.x, u.y - t.y);
        }
        __syncthreads();
    }
    float fw = (f == 0 || f == 1024) ? 1.f : 2.f;
    #pragma unroll
    for (int k2 = 0; k2 < 8; ++k2){
        int idx = tid + (k2 << 8);            // 0..2047
        int bc = idx & 15, kd = idx >> 4;
        int sdx = (kd < 64) ? kd : kd - 128;
        float b = (float)sdx * 26.0416666f;
        float m = (oc * oc - b * b > 0.f) ? fw : 0.f;
        float2 v = col[bc][kd];
        size_t o = ((size_t)kd * 16 + bc) * N_FP + f;
        Arp[o] = cvt_bf16(v.x * m);
        Aip[o] = cvt_bf16(v.y * m);
    }
}

// ---------------- band via MFMA: per kd, C[bc][y] = sum_f A[bc][f] * phase[f][y] ----------------
// block = (kd, y-half of 128); 8 waves x 16-y tiles; B phase tile generated in LDS per K-step.
__global__ __launch_bounds__(512) void k_band(const ushort* __restrict__ Ar,
                                              const ushort* __restrict__ Ai,
                                              const float4* __restrict__ kzJ,
                                              float2* __restrict__ band_b){
    int kd = blockIdx.x >> 1;
    int yh = blockIdx.x & 1;
    int tid  = threadIdx.x;
    int wid  = tid >> 6;
    int lane = tid & 63;
    // phase-gen assignment: thread owns f-pair fp (2 adjacent f) x 4 consecutive y
    int fp = tid & 15;          // 0..15 -> f = 32t + 2*fp (+0/1)
    int yq = tid >> 4;          // 0..31 -> y = 4*yq (+0..3)
    float ymg = 1.0e-3f + 1.5e-4f * (float)(yh * 128 + yq * 4);

    // LDS B tiles: [buf][plane re/im][y 0..127][40 bf16 padded (32 used)]
    __shared__ ushort Bls[2][2][128][40];   // 40960 B

    // MFMA fragment addressing
    int arow = lane & 15;                   // A row (bc) / B-C col (y)
    int koff = (lane >> 4) * 8;             // k offset within K=32
    int ylocal = wid * 16 + arow;           // B row (y within half)
    const ushort* Arp = Ar + ((size_t)kd * 16 + arow) * N_FP + koff;
    const ushort* Aip = Ai + ((size_t)kd * 16 + arow) * N_FP + koff;
    const float4* kjb = kzJ + (size_t)kd * N_FP;

    auto GENC = [&](float4 k0, float4 k1, int buf){
        float t0 = ymg * k0.x; t0 -= floorf(t0);
        float t1 = ymg * k1.x; t1 -= floorf(t1);
        float cA = cos_rev(t0), sA = sin_rev(t0);
        float cB = cos_rev(t1), sB = sin_rev(t1);
        #pragma unroll
        for (int j = 0; j < 4; ++j){
            int y = yq * 4 + j;
            uint br, bi;
            asm("v_cvt_pk_bf16_f32 %0, %1, %2" : "=v"(br) : "v"(cA), "v"(cB));
            asm("v_cvt_pk_bf16_f32 %0, %1, %2" : "=v"(bi) : "v"(sA), "v"(sB));
            *(uint*)&Bls[buf][0][y][fp * 2] = br;
            *(uint*)&Bls[buf][1][y][fp * 2] = bi;
            if (j < 3){
                float nA = fmaf(cA, k0.y, -(sA * k0.z));
                float mA = fmaf(sA, k0.y,  (cA * k0.z));
                cA = nA; sA = mA;
                float nB = fmaf(cB, k1.y, -(sB * k1.z));
                float mB = fmaf(sB, k1.y,  (cB * k1.z));
                cB = nB; sB = mB;
            }
        }
    };

    f32x4 P1 = {0.f,0.f,0.f,0.f}, P2 = P1, P3 = P1, P4 = P1;

    bf16x8 car = *(const bf16x8*)(Arp);
    bf16x8 cai = *(const bf16x8*)(Aip);
    GENC(kjb[fp * 2], kjb[fp * 2 + 1], 0);
    __syncthreads();

    for (int t = 0; t < 33; ++t){
        bf16x8 nar, nai;
        float4 k0, k1;
        if (t < 32){
            nar = *(const bf16x8*)(Arp + (t + 1) * 32);
            nai = *(const bf16x8*)(Aip + (t + 1) * 32);
            k0 = kjb[(t + 1) * 32 + fp * 2];
            k1 = kjb[(t + 1) * 32 + fp * 2 + 1];
        }
        int buf = t & 1;
        bf16x8 br = *(const bf16x8*)&Bls[buf][0][ylocal][koff];
        bf16x8 bi = *(const bf16x8*)&Bls[buf][1][ylocal][koff];
        P1 = __builtin_amdgcn_mfma_f32_16x16x32_bf16(car, br, P1, 0, 0, 0);
        P2 = __builtin_amdgcn_mfma_f32_16x16x32_bf16(cai, bi, P2, 0, 0, 0);
        P3 = __builtin_amdgcn_mfma_f32_16x16x32_bf16(car, bi, P3, 0, 0, 0);
        P4 = __builtin_amdgcn_mfma_f32_16x16x32_bf16(cai, br, P4, 0, 0, 0);
        if (t < 32){
            GENC(k0, k1, buf ^ 1);
        }
        __syncthreads();
        if (t < 32){ car = nar; cai = nai; }
    }

    // epilogue: C/D layout col=lane&15 (y), row=(lane>>4)*4+reg (bc)
    int y = yh * 128 + wid * 16 + (lane & 15);
    #pragma unroll
    for (int r = 0; r < 4; ++r){
        int bc = (lane >> 4) * 4 + r;
        band_b[((size_t)kd * 16 + bc) * 256 + y] = make_float2(P1[r] - P2[r], P3[r] + P4[r]);
    }
}

// ---------------- final: 128-pt inverse DFT over kd, magnitude, norm ----------------
__global__ __launch_bounds__(256) void k_final(const float2* __restrict__ band_b,
                                               const float* __restrict__ stat,
                                               float* __restrict__ out){
    int blk = blockIdx.x;            // bc*32 + yt
    int bc = blk >> 5, yt = blk & 31;
    __shared__ float2 ld[128][9];
    int tid = threadIdx.x;
    #pragma unroll
    for (int k2 = 0; k2 < 4; ++k2){
        int idx = tid + k2 * 256;
        int kd = idx >> 3, yi = idx & 7;
        ld[kd][yi] = band_b[((size_t)kd * 16 + bc) * 256 + yt * 8 + yi];
    }
    __syncthreads();
    int x = tid & 127, h = tid >> 7;
    float ang = (float)(2.0 * M_PI / 128.0) * (float)x;
    float sn, cs; sincosf(ang, &sn, &cs);
    float2 w = make_float2(cs, sn);
    float2 p = make_float2(1.f, 0.f);
    float aR[4] = {0.f,0.f,0.f,0.f}, aI[4] = {0.f,0.f,0.f,0.f};
    for (int kd = 0; kd < 128; ++kd){
        #pragma unroll
        for (int qq = 0; qq < 4; ++qq){
            float2 b = ld[kd][h * 4 + qq];
            aR[qq] += b.x * p.x - b.y * p.y;
            aI[qq] += b.x * p.y + b.y * p.x;
        }
        p = cmulf(p, w);
    }
    float invnorm = 1.f / (fmaxf(stat[32], 1.1920929e-7f) * 2048.f);
    #pragma unroll
    for (int qq = 0; qq < 4; ++qq){
        int y = yt * 8 + h * 4 + qq;
        out[((size_t)bc * 256 + y) * 128 + x] = sqrtf(aR[qq]*aR[qq] + aI[qq]*aI[qq]) * invnorm;
    }
}

extern "C" void kernel_launch(void* const* d_in, const int* in_sizes, int n_in,
                              void* d_out, int out_size, void* d_ws, size_t ws_size,
                              hipStream_t stream){
    const float* sino = (const float*)d_in[0];
    const float* apod = (const float*)d_in[1];
    float* out = (float*)d_out;
    float* W = (float*)d_ws;
    // workspace layout (float offsets):
    //   [0..63]       stat
    //   [64..1087]    psum
    //   [1088..2111]  psq
    //   2112          spec   : 16*128*1025 float2 = 4,198,400 floats (dead after k_dft; aliased by band_b)
    //   +4,198,400    Ar     : 16*128*1056 ushort = 2,162,688 u16 (1,081,344 floats)
    //   then          Ai     : same size
    //   then          kzJ    : 128*1056 float4 = 540,672 floats
    float* psum = W + 64;
    float* psq  = W + 1088;
    float2* spec  = (float2*)(W + 2112);
    ushort* Arp   = (ushort*)(W + 2112 + 4198400);
    ushort* Aip   = Arp + (size_t)16 * 128 * N_FP;
    float4* kzJ   = (float4*)(W + 2112 + 4198400 + 2162688);
    float2* band_b = spec;   // 128*16*256 float2 = 1,048,576 floats <= spec size

    // zero-fill A planes (f padding 1025..1055) and kzJ (pad entries -> benign phases)
    hipMemsetAsync(Arp, 0, (size_t)2 * 2162688 * sizeof(ushort), stream);
    hipMemsetAsync(kzJ, 0, (size_t)540672 * sizeof(float), stream);

    k_stats1<<<NBCC * 64, 256, 0, stream>>>(sino, psum, psq);
    k_stats2<<<NBCC, 64, 0, stream>>>(psum, psq, apod, W);
    k_tfft  <<<NBCC * N_DETC, 256, 0, stream>>>(sino, apod, W, spec);
    k_dft   <<<N_FC, 256, 0, stream>>>(spec, Arp, Aip, kzJ);
    k_band  <<<256, 512, 0, stream>>>(Arp, Aip, kzJ, band_b);
    k_final <<<NBCC * 32, 256, 0, stream>>>(band_b, W, out);
}

// Round 9
// 115.495 us; speedup vs baseline: 1.1846x; 1.0524x over previous
//
#include <hip/hip_runtime.h>
#include <math.h>

#define N_DETC 128
#define N_TC   2048
#define N_FC   1025
#define N_FP   1056    // padded f (33 K-steps of 32)
#define NXC    128
#define NYC    256
#define NBCC   16      // B*C = 8*2

typedef short bf16x8 __attribute__((ext_vector_type(8)));
typedef float f32x4  __attribute__((ext_vector_type(4)));

__device__ __forceinline__ float2 cmulf(float2 a, float2 b){
    return make_float2(a.x*b.x - a.y*b.y, a.x*b.y + a.y*b.x);
}

#if __has_builtin(__builtin_amdgcn_sinf) && __has_builtin(__builtin_amdgcn_cosf)
__device__ __forceinline__ float sin_rev(float tf){ return __builtin_amdgcn_sinf(tf); }   // sin(2*pi*tf)
__device__ __forceinline__ float cos_rev(float tf){ return __builtin_amdgcn_cosf(tf); }
#else
__device__ __forceinline__ float sin_rev(float tf){ return __sinf(6.28318530718f * tf); }
__device__ __forceinline__ float cos_rev(float tf){ return __cosf(6.28318530718f * tf); }
#endif

__device__ __forceinline__ ushort cvt_bf16(float x){
    uint u = __float_as_uint(x);
    return (ushort)((u + 0x7FFFu + ((u >> 16) & 1u)) >> 16);   // RNE
}

// ---------------- stats stage 1 ----------------
__global__ __launch_bounds__(256) void k_stats1(const float* __restrict__ sino,
                                                float* __restrict__ psum,
                                                float* __restrict__ psq){
    int bc    = blockIdx.x >> 6;
    int chunk = blockIdx.x & 63;
    const float4* p = (const float4*)(sino + (size_t)bc * (N_DETC * N_TC)) + (size_t)chunk * 1024;
    float s = 0.f, q = 0.f;
    #pragma unroll
    for (int i = 0; i < 4; ++i){
        float4 v = p[threadIdx.x + i * 256];
        s += v.x + v.y + v.z + v.w;
        q += v.x*v.x + v.y*v.y + v.z*v.z + v.w*v.w;
    }
    #pragma unroll
    for (int m = 1; m < 64; m <<= 1){
        s += __shfl_xor(s, m, 64);
        q += __shfl_xor(q, m, 64);
    }
    __shared__ float ls[4], lq[4];
    int w = threadIdx.x >> 6, lane = threadIdx.x & 63;
    if (lane == 0){ ls[w] = s; lq[w] = q; }
    __syncthreads();
    if (threadIdx.x == 0){
        psum[blockIdx.x] = ls[0] + ls[1] + ls[2] + ls[3];
        psq[blockIdx.x]  = lq[0] + lq[1] + lq[2] + lq[3];
    }
}

// ---------------- stats stage 2 ----------------
__global__ void k_stats2(const float* __restrict__ psum,
                         const float* __restrict__ psq,
                         const float* __restrict__ apod,
                         float* __restrict__ stat){
    int bc = blockIdx.x, t = threadIdx.x;   // 64 threads
    float s = psum[bc * 64 + t], q = psq[bc * 64 + t];
    float a = (bc == 0) ? (apod[t] + apod[t + 64]) : 0.f;
    #pragma unroll
    for (int m = 1; m < 64; m <<= 1){
        s += __shfl_xor(s, m, 64);
        q += __shfl_xor(q, m, 64);
        a += __shfl_xor(a, m, 64);
    }
    if (t == 0){
        const float inv_n = 1.f / (float)(N_DETC * N_TC);
        float mean = s * inv_n;
        float var  = q * inv_n - mean * mean;
        stat[bc]      = mean;
        stat[16 + bc] = rsqrtf(fmaxf(var, 0.f) + 1.1920929e-7f);
        if (bc == 0) stat[32] = a;
    }
}

// ---------------- temporal FFT ----------------
__global__ __launch_bounds__(256) void k_tfft(const float* __restrict__ sino,
                                              const float* __restrict__ apod,
                                              const float* __restrict__ stat,
                                              float2* __restrict__ spec){
    int row = blockIdx.x;            // bc*128 + d
    int bc = row >> 7, d = row & 127;
    __shared__ float2 a[N_TC];       // 16 KB
    float mean = stat[bc];
    float scl  = stat[16 + bc] * apod[d];
    const float* p = sino + (size_t)row * N_TC;
    for (int t = threadIdx.x; t < N_TC; t += 256){
        float v = (p[t] - mean) * scl;
        int r = __brev((unsigned)t) >> 21;   // 11-bit reverse
        a[r] = make_float2(v, 0.f);
    }
    __syncthreads();
    for (int s = 1; s <= 11; ++s){
        int half = 1 << (s - 1);
        for (int j = threadIdx.x; j < N_TC / 2; j += 256){
            int g = j >> (s - 1);
            int k = j & (half - 1);
            int i1 = (g << s) + k;
            int i2 = i1 + half;
            float ang = -(float)M_PI * (float)k / (float)half;
            float sn, cs; __sincosf(ang, &sn, &cs);
            float2 u = a[i1], v = a[i2];
            float2 t = make_float2(v.x * cs - v.y * sn, v.x * sn + v.y * cs);
            a[i1] = make_float2(u.x + t.x, u.y + t.y);
            a[i2] = make_float2(u.x - t.x, u.y - t.y);
        }
        __syncthreads();
    }
    float2* o = spec + (size_t)row * N_FC;
    for (int f = threadIdx.x; f < N_FC; f += 256) o[f] = a[f];
}

// ---------------- fused detector FFT + mask/weight -> bf16 A-planes + (kz,J1) table ----------------
// blocks 0..1024: real f columns. blocks 1025..1055: zero-fill pad column f = bid.
__global__ __launch_bounds__(256) void k_dft(const float2* __restrict__ spec,
                                             ushort* __restrict__ Arp,
                                             ushort* __restrict__ Aip,
                                             float4* __restrict__ kzJ){
    int bid = blockIdx.x;
    int tid = threadIdx.x;
    if (bid >= N_FC){
        // pad column f = bid (1025..1055): A = 0, kzJ = (kz=0, J=1+0i)
        int f = bid;
        for (int row = tid; row < 2048; row += 256){
            size_t o = (size_t)row * N_FP + f;
            Arp[o] = 0; Aip[o] = 0;
        }
        if (tid < 128) kzJ[(size_t)tid * N_FP + f] = make_float4(0.f, 1.f, 0.f, 0.f);
        return;
    }
    int f = (bid < 1024) ? ((bid & 7) * 128 + (bid >> 3)) : 1024;  // XCD-contiguous f ranges
    __shared__ float2 col[16][128];   // 16 KB
    #pragma unroll
    for (int k2 = 0; k2 < 8; ++k2){
        int idx = tid + (k2 << 8);            // 0..2047
        int bc = idx >> 7, kd = idx & 127;
        col[bc][__brev((unsigned)kd) >> 25] = spec[((size_t)(bc * 128 + kd)) * N_FC + f];
    }
    float fr = (float)f * 19531.25f;          // Hz
    float oc = fr * (1.0f / 1540.0f);         // cycles/m
    if (tid < 128){
        int kd = tid;
        int sdx = (kd < 64) ? kd : kd - 128;
        float b = (float)sdx * 26.0416666f;   // 1/(128*3e-4) cycles/m
        float kq = oc * oc - b * b;
        float kzr = (kq > 0.f) ? sqrtf(kq) : 0.f;
        float tj = 1.5e-4f * kzr;             // DY*kz in revolutions
        tj -= floorf(tj);
        kzJ[(size_t)kd * N_FP + f] = make_float4(kzr, cos_rev(tj), sin_rev(tj), 0.f);
    }
    __syncthreads();
    for (int s = 1; s <= 7; ++s){
        int half = 1 << (s - 1);
        #pragma unroll
        for (int k2 = 0; k2 < 4; ++k2){
            int j = tid + (k2 << 8);          // 0..1023 : bc*64 + butterfly
            int bc = j >> 6, jj = j & 63;
            int g = jj >> (s - 1);
            int k = jj & (half - 1);
            int i1 = (g << s) + k;
            int i2 = i1 + half;
            float ang = -(float)M_PI * (float)k / (float)half;
            float sn, cs; __sincosf(ang, &sn, &cs);
            float2 u = col[bc][i1], v = col[bc][i2];
            float2 t = make_float2(v.x * cs - v.y * sn, v.x * sn + v.y * cs);
            col[bc][i1] = make_float2(u.x + t.x, u.y + t.y);
            col[bc][i2] = make_float2(u.x - t.x, u.y - t.y);
        }
        __syncthreads();
    }
    float fw = (f == 0 || f == 1024) ? 1.f : 2.f;
    #pragma unroll
    for (int k2 = 0; k2 < 8; ++k2){
        int idx = tid + (k2 << 8);            // 0..2047
        int bc = idx & 15, kd = idx >> 4;
        int sdx = (kd < 64) ? kd : kd - 128;
        float b = (float)sdx * 26.0416666f;
        float m = (oc * oc - b * b > 0.f) ? fw : 0.f;
        float2 v = col[bc][kd];
        size_t o = ((size_t)kd * 16 + bc) * N_FP + f;
        Arp[o] = cvt_bf16(v.x * m);
        Aip[o] = cvt_bf16(v.y * m);
    }
}

// ---------------- band via MFMA: per kd, C[bc][y] = sum_f A[bc][f] * phase[f][y] ----------------
// block = (kd, y-half of 128); 8 waves x 16-y tiles; B phase tile generated in LDS per K-step.
__global__ __launch_bounds__(512) void k_band(const ushort* __restrict__ Ar,
                                              const ushort* __restrict__ Ai,
                                              const float4* __restrict__ kzJ,
                                              float2* __restrict__ band_b){
    int kd = blockIdx.x >> 1;
    int yh = blockIdx.x & 1;
    int tid  = threadIdx.x;
    int wid  = tid >> 6;
    int lane = tid & 63;
    // phase-gen assignment: thread owns f-pair fp (2 adjacent f) x 4 consecutive y
    int fp = tid & 15;          // 0..15 -> f = 32t + 2*fp (+0/1)
    int yq = tid >> 4;          // 0..31 -> y = 4*yq (+0..3)
    float ymg = 1.0e-3f + 1.5e-4f * (float)(yh * 128 + yq * 4);

    // LDS B tiles: [buf][plane re/im][y 0..127][40 bf16 padded (32 used)]
    __shared__ ushort Bls[2][2][128][40];   // 40960 B

    // MFMA fragment addressing
    int arow = lane & 15;                   // A row (bc) / B-C col (y)
    int koff = (lane >> 4) * 8;             // k offset within K=32
    int ylocal = wid * 16 + arow;           // B row (y within half)
    const ushort* Arp = Ar + ((size_t)kd * 16 + arow) * N_FP + koff;
    const ushort* Aip = Ai + ((size_t)kd * 16 + arow) * N_FP + koff;
    const float4* kjb = kzJ + (size_t)kd * N_FP;

    auto GENC = [&](float4 k0, float4 k1, int buf){
        float t0 = ymg * k0.x; t0 -= floorf(t0);
        float t1 = ymg * k1.x; t1 -= floorf(t1);
        float cA = cos_rev(t0), sA = sin_rev(t0);
        float cB = cos_rev(t1), sB = sin_rev(t1);
        #pragma unroll
        for (int j = 0; j < 4; ++j){
            int y = yq * 4 + j;
            uint br, bi;
            asm("v_cvt_pk_bf16_f32 %0, %1, %2" : "=v"(br) : "v"(cA), "v"(cB));
            asm("v_cvt_pk_bf16_f32 %0, %1, %2" : "=v"(bi) : "v"(sA), "v"(sB));
            *(uint*)&Bls[buf][0][y][fp * 2] = br;
            *(uint*)&Bls[buf][1][y][fp * 2] = bi;
            if (j < 3){
                float nA = fmaf(cA, k0.y, -(sA * k0.z));
                float mA = fmaf(sA, k0.y,  (cA * k0.z));
                cA = nA; sA = mA;
                float nB = fmaf(cB, k1.y, -(sB * k1.z));
                float mB = fmaf(sB, k1.y,  (cB * k1.z));
                cB = nB; sB = mB;
            }
        }
    };

    f32x4 P1 = {0.f,0.f,0.f,0.f}, P2 = P1, P3 = P1, P4 = P1;

    bf16x8 car = *(const bf16x8*)(Arp);
    bf16x8 cai = *(const bf16x8*)(Aip);
    GENC(kjb[fp * 2], kjb[fp * 2 + 1], 0);
    __syncthreads();

    for (int t = 0; t < 33; ++t){
        bf16x8 nar, nai;
        float4 k0, k1;
        if (t < 32){
            nar = *(const bf16x8*)(Arp + (t + 1) * 32);
            nai = *(const bf16x8*)(Aip + (t + 1) * 32);
            k0 = kjb[(t + 1) * 32 + fp * 2];
            k1 = kjb[(t + 1) * 32 + fp * 2 + 1];
        }
        int buf = t & 1;
        bf16x8 br = *(const bf16x8*)&Bls[buf][0][ylocal][koff];
        bf16x8 bi = *(const bf16x8*)&Bls[buf][1][ylocal][koff];
        P1 = __builtin_amdgcn_mfma_f32_16x16x32_bf16(car, br, P1, 0, 0, 0);
        P2 = __builtin_amdgcn_mfma_f32_16x16x32_bf16(cai, bi, P2, 0, 0, 0);
        P3 = __builtin_amdgcn_mfma_f32_16x16x32_bf16(car, bi, P3, 0, 0, 0);
        P4 = __builtin_amdgcn_mfma_f32_16x16x32_bf16(cai, br, P4, 0, 0, 0);
        if (t < 32){
            GENC(k0, k1, buf ^ 1);
        }
        __syncthreads();
        if (t < 32){ car = nar; cai = nai; }
    }

    // epilogue: C/D layout col=lane&15 (y), row=(lane>>4)*4+reg (bc)
    int y = yh * 128 + wid * 16 + (lane & 15);
    #pragma unroll
    for (int r = 0; r < 4; ++r){
        int bc = (lane >> 4) * 4 + r;
        band_b[((size_t)kd * 16 + bc) * 256 + y] = make_float2(P1[r] - P2[r], P3[r] + P4[r]);
    }
}

// ---------------- final: 128-pt inverse DFT over kd, magnitude, norm ----------------
__global__ __launch_bounds__(256) void k_final(const float2* __restrict__ band_b,
                                               const float* __restrict__ stat,
                                               float* __restrict__ out){
    int blk = blockIdx.x;            // bc*32 + yt
    int bc = blk >> 5, yt = blk & 31;
    __shared__ float2 ld[128][9];
    int tid = threadIdx.x;
    #pragma unroll
    for (int k2 = 0; k2 < 4; ++k2){
        int idx = tid + k2 * 256;
        int kd = idx >> 3, yi = idx & 7;
        ld[kd][yi] = band_b[((size_t)kd * 16 + bc) * 256 + yt * 8 + yi];
    }
    __syncthreads();
    int x = tid & 127, h = tid >> 7;
    float ang = (float)(2.0 * M_PI / 128.0) * (float)x;
    float sn, cs; sincosf(ang, &sn, &cs);
    float2 w = make_float2(cs, sn);
    float2 p = make_float2(1.f, 0.f);
    float aR[4] = {0.f,0.f,0.f,0.f}, aI[4] = {0.f,0.f,0.f,0.f};
    for (int kd = 0; kd < 128; ++kd){
        #pragma unroll
        for (int qq = 0; qq < 4; ++qq){
            float2 b = ld[kd][h * 4 + qq];
            aR[qq] += b.x * p.x - b.y * p.y;
            aI[qq] += b.x * p.y + b.y * p.x;
        }
        p = cmulf(p, w);
    }
    float invnorm = 1.f / (fmaxf(stat[32], 1.1920929e-7f) * 2048.f);
    #pragma unroll
    for (int qq = 0; qq < 4; ++qq){
        int y = yt * 8 + h * 4 + qq;
        out[((size_t)bc * 256 + y) * 128 + x] = sqrtf(aR[qq]*aR[qq] + aI[qq]*aI[qq]) * invnorm;
    }
}

extern "C" void kernel_launch(void* const* d_in, const int* in_sizes, int n_in,
                              void* d_out, int out_size, void* d_ws, size_t ws_size,
                              hipStream_t stream){
    const float* sino = (const float*)d_in[0];
    const float* apod = (const float*)d_in[1];
    float* out = (float*)d_out;
    float* W = (float*)d_ws;
    // workspace layout (float offsets):
    //   [0..63]       stat
    //   [64..1087]    psum
    //   [1088..2111]  psq
    //   2112          spec   : 16*128*1025 float2 = 4,198,400 floats (dead after k_dft; aliased by band_b)
    //   +4,198,400    Ar     : 16*128*1056 ushort = 2,162,688 u16 (1,081,344 floats)
    //   then          Ai     : same size
    //   then          kzJ    : 128*1056 float4 = 540,672 floats
    float* psum = W + 64;
    float* psq  = W + 1088;
    float2* spec  = (float2*)(W + 2112);
    ushort* Arp   = (ushort*)(W + 2112 + 4198400);
    ushort* Aip   = Arp + (size_t)16 * 128 * N_FP;
    float4* kzJ   = (float4*)(W + 2112 + 4198400 + 2162688);
    float2* band_b = spec;   // 128*16*256 float2 = 1,048,576 floats <= spec size

    k_stats1<<<NBCC * 64, 256, 0, stream>>>(sino, psum, psq);
    k_stats2<<<NBCC, 64, 0, stream>>>(psum, psq, apod, W);
    k_tfft  <<<NBCC * N_DETC, 256, 0, stream>>>(sino, apod, W, spec);
    k_dft   <<<N_FP, 256, 0, stream>>>(spec, Arp, Aip, kzJ);   // 1025 real + 31 pad blocks
    k_band  <<<256, 512, 0, stream>>>(Arp, Aip, kzJ, band_b);
    k_final <<<NBCC * 32, 256, 0, stream>>>(band_b, W, out);
}

// Round 10
// 103.918 us; speedup vs baseline: 1.3166x; 1.1114x over previous
//
#include <hip/hip_runtime.h>
#include <math.h>

#define N_DETC 128
#define N_TC   2048
#define N_FC   1025
#define N_FP   1056    // padded f (33 K-steps of 32)
#define NXC    128
#define NYC    256
#define NBCC   16      // B*C = 8*2

typedef short bf16x8 __attribute__((ext_vector_type(8)));
typedef float f32x4  __attribute__((ext_vector_type(4)));

__device__ __forceinline__ float2 cmulf(float2 a, float2 b){
    return make_float2(a.x*b.x - a.y*b.y, a.x*b.y + a.y*b.x);
}

#if __has_builtin(__builtin_amdgcn_sinf) && __has_builtin(__builtin_amdgcn_cosf)
__device__ __forceinline__ float sin_rev(float tf){ return __builtin_amdgcn_sinf(tf); }   // sin(2*pi*tf)
__device__ __forceinline__ float cos_rev(float tf){ return __builtin_amdgcn_cosf(tf); }
#else
__device__ __forceinline__ float sin_rev(float tf){ return __sinf(6.28318530718f * tf); }
__device__ __forceinline__ float cos_rev(float tf){ return __cosf(6.28318530718f * tf); }
#endif

__device__ __forceinline__ ushort cvt_bf16(float x){
    uint u = __float_as_uint(x);
    return (ushort)((u + 0x7FFFu + ((u >> 16) & 1u)) >> 16);   // RNE
}

// ---------------- stats stage 1 ----------------
__global__ __launch_bounds__(256) void k_stats1(const float* __restrict__ sino,
                                                float* __restrict__ psum,
                                                float* __restrict__ psq){
    int bc    = blockIdx.x >> 6;
    int chunk = blockIdx.x & 63;
    const float4* p = (const float4*)(sino + (size_t)bc * (N_DETC * N_TC)) + (size_t)chunk * 1024;
    float s = 0.f, q = 0.f;
    #pragma unroll
    for (int i = 0; i < 4; ++i){
        float4 v = p[threadIdx.x + i * 256];
        s += v.x + v.y + v.z + v.w;
        q += v.x*v.x + v.y*v.y + v.z*v.z + v.w*v.w;
    }
    #pragma unroll
    for (int m = 1; m < 64; m <<= 1){
        s += __shfl_xor(s, m, 64);
        q += __shfl_xor(q, m, 64);
    }
    __shared__ float ls[4], lq[4];
    int w = threadIdx.x >> 6, lane = threadIdx.x & 63;
    if (lane == 0){ ls[w] = s; lq[w] = q; }
    __syncthreads();
    if (threadIdx.x == 0){
        psum[blockIdx.x] = ls[0] + ls[1] + ls[2] + ls[3];
        psq[blockIdx.x]  = lq[0] + lq[1] + lq[2] + lq[3];
    }
}

// ---------------- stats stage 2 ----------------
__global__ void k_stats2(const float* __restrict__ psum,
                         const float* __restrict__ psq,
                         const float* __restrict__ apod,
                         float* __restrict__ stat){
    int bc = blockIdx.x, t = threadIdx.x;   // 64 threads
    float s = psum[bc * 64 + t], q = psq[bc * 64 + t];
    float a = (bc == 0) ? (apod[t] + apod[t + 64]) : 0.f;
    #pragma unroll
    for (int m = 1; m < 64; m <<= 1){
        s += __shfl_xor(s, m, 64);
        q += __shfl_xor(q, m, 64);
        a += __shfl_xor(a, m, 64);
    }
    if (t == 0){
        const float inv_n = 1.f / (float)(N_DETC * N_TC);
        float mean = s * inv_n;
        float var  = q * inv_n - mean * mean;
        stat[bc]      = mean;
        stat[16 + bc] = rsqrtf(fmaxf(var, 0.f) + 1.1920929e-7f);
        if (bc == 0) stat[32] = a;
    }
}

// ---------------- temporal rFFT via half-size complex FFT + untangle ----------------
__global__ __launch_bounds__(256) void k_tfft(const float* __restrict__ sino,
                                              const float* __restrict__ apod,
                                              const float* __restrict__ stat,
                                              float2* __restrict__ spec){
    int row = blockIdx.x;            // bc*128 + d
    int bc = row >> 7, d = row & 127;
    __shared__ float2 z[1024];       // 8 KB
    float mean = stat[bc];
    float scl  = stat[16 + bc] * apod[d];
    const float2* p = (const float2*)(sino + (size_t)row * N_TC);
    for (int n = threadIdx.x; n < 1024; n += 256){
        float2 v = p[n];             // x[2n], x[2n+1]
        int r = __brev((unsigned)n) >> 22;   // 10-bit reverse
        z[r] = make_float2((v.x - mean) * scl, (v.y - mean) * scl);
    }
    __syncthreads();
    for (int s = 1; s <= 10; ++s){
        int half = 1 << (s - 1);
        for (int j = threadIdx.x; j < 512; j += 256){
            int g = j >> (s - 1);
            int k = j & (half - 1);
            int i1 = (g << s) + k;
            int i2 = i1 + half;
            float ang = -(float)M_PI * (float)k / (float)half;
            float sn, cs; __sincosf(ang, &sn, &cs);
            float2 u = z[i1], v = z[i2];
            float2 t = make_float2(v.x * cs - v.y * sn, v.x * sn + v.y * cs);
            z[i1] = make_float2(u.x + t.x, u.y + t.y);
            z[i2] = make_float2(u.x - t.x, u.y - t.y);
        }
        __syncthreads();
    }
    // untangle: X[k] = E + W*O, W = e^{-i*pi*k/1024}
    float2* o = spec + (size_t)row * N_FC;
    for (int k = threadIdx.x; k < 1025; k += 256){
        float2 A = z[k & 1023];
        float2 Bv = z[(1024 - k) & 1023];
        float Br = Bv.x, Bi = -Bv.y;         // conj
        float Er = 0.5f * (A.x + Br), Ei = 0.5f * (A.y + Bi);
        float Dr = 0.5f * (A.x - Br), Di = 0.5f * (A.y - Bi);
        float Or = Di, Oi = -Dr;             // O = -i*D
        float ang = -(float)M_PI * (float)k * (1.0f / 1024.0f);
        float sn, cs; __sincosf(ang, &sn, &cs);   // W = (cs, sn), sn already negative branch
        float Xr = Er + cs * Or - sn * Oi;
        float Xi = Ei + cs * Oi + sn * Or;
        o[k] = make_float2(Xr, Xi);
    }
}

// ---------------- detector FFT, tile-coalesced: block=(f-tile of 32, bc) ----------------
// loads spec[bc][kd][f0..f0+31] coalesced, 7-stage FFT over kd in LDS,
// mask+fw, bf16 convert, stores Ar/Ai rows as full 64B lines. bc==0 blocks write kzJ.
__global__ __launch_bounds__(256) void k_dft(const float2* __restrict__ spec,
                                             ushort* __restrict__ Arp,
                                             ushort* __restrict__ Aip,
                                             float4* __restrict__ kzJ){
    int bid = blockIdx.x;
    int ft = bid >> 4, bc = bid & 15;
    int f0 = ft << 5;
    int tid = threadIdx.x;
    __shared__ float2 tile[128][33];      // 33.8 KB, padded
    __shared__ ushort stAr[128][40];      // 10 KB, 16B-aligned rows (80 B)
    __shared__ ushort stAi[128][40];      // 10 KB

    int fl  = tid & 31;
    int kd0 = tid >> 5;                   // 0..7
    int f = f0 + fl;
    bool fok = (f <= 1024);
    float fr = (float)f * 19531.25f;      // Hz
    float oc = fr * (1.0f / 1540.0f);     // cycles/m

    #pragma unroll
    for (int i = 0; i < 16; ++i){
        int kd = kd0 + (i << 3);
        int rkd = __brev((unsigned)kd) >> 25;   // 7-bit reverse
        float2 v = fok ? spec[((size_t)(bc * 128 + kd)) * N_FC + f] : make_float2(0.f, 0.f);
        tile[rkd][fl] = v;
    }
    if (bc == 0){
        #pragma unroll
        for (int i = 0; i < 16; ++i){
            int kd = kd0 + (i << 3);
            int sdx = (kd < 64) ? kd : kd - 128;
            float bb = (float)sdx * 26.0416666f;   // 1/(128*3e-4) cycles/m
            float kq = oc * oc - bb * bb;
            float kzr = (fok && kq > 0.f) ? sqrtf(kq) : 0.f;
            float tj = 1.5e-4f * kzr;              // DY*kz revolutions
            tj -= floorf(tj);
            kzJ[(size_t)kd * N_FP + f] = make_float4(kzr, cos_rev(tj), sin_rev(tj), 0.f);
        }
    }
    __syncthreads();
    for (int s = 1; s <= 7; ++s){
        int half = 1 << (s - 1);
        #pragma unroll
        for (int it = 0; it < 8; ++it){
            int task = tid + (it << 8);    // 0..2047
            int ff = task & 31, j = task >> 5;   // j = 0..63 butterfly pair
            int g = j >> (s - 1), k = j & (half - 1);
            int i1 = (g << s) + k, i2 = i1 + half;
            float ang = -(float)M_PI * (float)k / (float)half;
            float sn, cs; __sincosf(ang, &sn, &cs);
            float2 u = tile[i1][ff], v = tile[i2][ff];
            float2 t = make_float2(v.x * cs - v.y * sn, v.x * sn + v.y * cs);
            tile[i1][ff] = make_float2(u.x + t.x, u.y + t.y);
            tile[i2][ff] = make_float2(u.x - t.x, u.y - t.y);
        }
        __syncthreads();
    }
    float fw = (f == 0 || f == 1024) ? 1.f : 2.f;
    #pragma unroll
    for (int i = 0; i < 16; ++i){
        int kd = kd0 + (i << 3);
        int sdx = (kd < 64) ? kd : kd - 128;
        float bb = (float)sdx * 26.0416666f;
        float m = (fok && (oc * oc - bb * bb > 0.f)) ? fw : 0.f;
        float2 v = tile[kd][fl];
        stAr[kd][fl] = cvt_bf16(v.x * m);
        stAi[kd][fl] = cvt_bf16(v.y * m);
    }
    __syncthreads();
    // coalesced 64B-line stores: thread -> (kd = tid>>1, half = tid&1), 2x uint4 each plane
    int kds = tid >> 1, hf = tid & 1;
    size_t rowoff = ((size_t)kds * 16 + bc) * N_FP + f0 + hf * 16;
    uint4 r0 = *(const uint4*)&stAr[kds][hf * 16];
    uint4 r1 = *(const uint4*)&stAr[kds][hf * 16 + 8];
    uint4 i0 = *(const uint4*)&stAi[kds][hf * 16];
    uint4 i1v = *(const uint4*)&stAi[kds][hf * 16 + 8];
    ((uint4*)(Arp + rowoff))[0] = r0;
    ((uint4*)(Arp + rowoff))[1] = r1;
    ((uint4*)(Aip + rowoff))[0] = i0;
    ((uint4*)(Aip + rowoff))[1] = i1v;
}

// ---------------- band via MFMA: per kd, C[bc][y] = sum_f A[bc][f] * phase[f][y] ----------------
// block = (kd, y-half of 128); 8 waves x 16-y tiles; B phase tile generated in LDS per K-step.
__global__ __launch_bounds__(512) void k_band(const ushort* __restrict__ Ar,
                                              const ushort* __restrict__ Ai,
                                              const float4* __restrict__ kzJ,
                                              float2* __restrict__ band_b){
    int kd = blockIdx.x >> 1;
    int yh = blockIdx.x & 1;
    int tid  = threadIdx.x;
    int wid  = tid >> 6;
    int lane = tid & 63;
    // phase-gen assignment: thread owns f-pair fp (2 adjacent f) x 4 consecutive y
    int fp = tid & 15;          // 0..15 -> f = 32t + 2*fp (+0/1)
    int yq = tid >> 4;          // 0..31 -> y = 4*yq (+0..3)
    float ymg = 1.0e-3f + 1.5e-4f * (float)(yh * 128 + yq * 4);

    // LDS B tiles: [buf][plane re/im][y 0..127][40 bf16 padded (32 used)]
    __shared__ ushort Bls[2][2][128][40];   // 40960 B

    // MFMA fragment addressing
    int arow = lane & 15;                   // A row (bc) / B-C col (y)
    int koff = (lane >> 4) * 8;             // k offset within K=32
    int ylocal = wid * 16 + arow;           // B row (y within half)
    const ushort* Arp = Ar + ((size_t)kd * 16 + arow) * N_FP + koff;
    const ushort* Aip = Ai + ((size_t)kd * 16 + arow) * N_FP + koff;
    const float4* kjb = kzJ + (size_t)kd * N_FP;

    auto GENC = [&](float4 k0, float4 k1, int buf){
        float t0 = ymg * k0.x; t0 -= floorf(t0);
        float t1 = ymg * k1.x; t1 -= floorf(t1);
        float cA = cos_rev(t0), sA = sin_rev(t0);
        float cB = cos_rev(t1), sB = sin_rev(t1);
        #pragma unroll
        for (int j = 0; j < 4; ++j){
            int y = yq * 4 + j;
            uint br, bi;
            asm("v_cvt_pk_bf16_f32 %0, %1, %2" : "=v"(br) : "v"(cA), "v"(cB));
            asm("v_cvt_pk_bf16_f32 %0, %1, %2" : "=v"(bi) : "v"(sA), "v"(sB));
            *(uint*)&Bls[buf][0][y][fp * 2] = br;
            *(uint*)&Bls[buf][1][y][fp * 2] = bi;
            if (j < 3){
                float nA = fmaf(cA, k0.y, -(sA * k0.z));
                float mA = fmaf(sA, k0.y,  (cA * k0.z));
                cA = nA; sA = mA;
                float nB = fmaf(cB, k1.y, -(sB * k1.z));
                float mB = fmaf(sB, k1.y,  (cB * k1.z));
                cB = nB; sB = mB;
            }
        }
    };

    f32x4 P1 = {0.f,0.f,0.f,0.f}, P2 = P1, P3 = P1, P4 = P1;

    bf16x8 car = *(const bf16x8*)(Arp);
    bf16x8 cai = *(const bf16x8*)(Aip);
    GENC(kjb[fp * 2], kjb[fp * 2 + 1], 0);
    __syncthreads();

    for (int t = 0; t < 33; ++t){
        bf16x8 nar, nai;
        float4 k0, k1;
        if (t < 32){
            nar = *(const bf16x8*)(Arp + (t + 1) * 32);
            nai = *(const bf16x8*)(Aip + (t + 1) * 32);
            k0 = kjb[(t + 1) * 32 + fp * 2];
            k1 = kjb[(t + 1) * 32 + fp * 2 + 1];
        }
        int buf = t & 1;
        bf16x8 br = *(const bf16x8*)&Bls[buf][0][ylocal][koff];
        bf16x8 bi = *(const bf16x8*)&Bls[buf][1][ylocal][koff];
        P1 = __builtin_amdgcn_mfma_f32_16x16x32_bf16(car, br, P1, 0, 0, 0);
        P2 = __builtin_amdgcn_mfma_f32_16x16x32_bf16(cai, bi, P2, 0, 0, 0);
        P3 = __builtin_amdgcn_mfma_f32_16x16x32_bf16(car, bi, P3, 0, 0, 0);
        P4 = __builtin_amdgcn_mfma_f32_16x16x32_bf16(cai, br, P4, 0, 0, 0);
        if (t < 32){
            GENC(k0, k1, buf ^ 1);
        }
        __syncthreads();
        if (t < 32){ car = nar; cai = nai; }
    }

    // epilogue: C/D layout col=lane&15 (y), row=(lane>>4)*4+reg (bc)
    int y = yh * 128 + wid * 16 + (lane & 15);
    #pragma unroll
    for (int r = 0; r < 4; ++r){
        int bc = (lane >> 4) * 4 + r;
        band_b[((size_t)kd * 16 + bc) * 256 + y] = make_float2(P1[r] - P2[r], P3[r] + P4[r]);
    }
}

// ---------------- final: 128-pt inverse DFT over kd, magnitude, norm ----------------
__global__ __launch_bounds__(256) void k_final(const float2* __restrict__ band_b,
                                               const float* __restrict__ stat,
                                               float* __restrict__ out){
    int blk = blockIdx.x;            // bc*32 + yt
    int bc = blk >> 5, yt = blk & 31;
    __shared__ float2 ld[128][9];
    int tid = threadIdx.x;
    #pragma unroll
    for (int k2 = 0; k2 < 4; ++k2){
        int idx = tid + k2 * 256;
        int kd = idx >> 3, yi = idx & 7;
        ld[kd][yi] = band_b[((size_t)kd * 16 + bc) * 256 + yt * 8 + yi];
    }
    __syncthreads();
    int x = tid & 127, h = tid >> 7;
    float ang = (float)(2.0 * M_PI / 128.0) * (float)x;
    float sn, cs; sincosf(ang, &sn, &cs);
    float2 w = make_float2(cs, sn);
    float2 p = make_float2(1.f, 0.f);
    float aR[4] = {0.f,0.f,0.f,0.f}, aI[4] = {0.f,0.f,0.f,0.f};
    for (int kd = 0; kd < 128; ++kd){
        #pragma unroll
        for (int qq = 0; qq < 4; ++qq){
            float2 b = ld[kd][h * 4 + qq];
            aR[qq] += b.x * p.x - b.y * p.y;
            aI[qq] += b.x * p.y + b.y * p.x;
        }
        p = cmulf(p, w);
    }
    float invnorm = 1.f / (fmaxf(stat[32], 1.1920929e-7f) * 2048.f);
    #pragma unroll
    for (int qq = 0; qq < 4; ++qq){
        int y = yt * 8 + h * 4 + qq;
        out[((size_t)bc * 256 + y) * 128 + x] = sqrtf(aR[qq]*aR[qq] + aI[qq]*aI[qq]) * invnorm;
    }
}

extern "C" void kernel_launch(void* const* d_in, const int* in_sizes, int n_in,
                              void* d_out, int out_size, void* d_ws, size_t ws_size,
                              hipStream_t stream){
    const float* sino = (const float*)d_in[0];
    const float* apod = (const float*)d_in[1];
    float* out = (float*)d_out;
    float* W = (float*)d_ws;
    // workspace layout (float offsets):
    //   [0..63]       stat
    //   [64..1087]    psum
    //   [1088..2111]  psq
    //   2112          spec   : 16*128*1025 float2 = 4,198,400 floats (dead after k_dft; aliased by band_b)
    //   +4,198,400    Ar     : 16*128*1056 ushort = 2,162,688 u16 (1,081,344 floats)
    //   then          Ai     : same size
    //   then          kzJ    : 128*1056 float4 = 540,672 floats
    float* psum = W + 64;
    float* psq  = W + 1088;
    float2* spec  = (float2*)(W + 2112);
    ushort* Arp   = (ushort*)(W + 2112 + 4198400);
    ushort* Aip   = Arp + (size_t)16 * 128 * N_FP;
    float4* kzJ   = (float4*)(W + 2112 + 4198400 + 2162688);
    float2* band_b = spec;   // 128*16*256 float2 = 1,048,576 floats <= spec size

    k_stats1<<<NBCC * 64, 256, 0, stream>>>(sino, psum, psq);
    k_stats2<<<NBCC, 64, 0, stream>>>(psum, psq, apod, W);
    k_tfft  <<<NBCC * N_DETC, 256, 0, stream>>>(sino, apod, W, spec);
    k_dft   <<<33 * 16, 256, 0, stream>>>(spec, Arp, Aip, kzJ);   // f-tile x bc, pad folded in
    k_band  <<<256, 512, 0, stream>>>(Arp, Aip, kzJ, band_b);
    k_final <<<NBCC * 32, 256, 0, stream>>>(band_b, W, out);
}

// Round 11
// 90.090 us; speedup vs baseline: 1.5186x; 1.1535x over previous
//
#include <hip/hip_runtime.h>
#include <math.h>

#define N_DETC 128
#define N_TC   2048
#define N_FC   1025
#define N_FP   1056    // padded f (33 K-steps of 32)
#define NXC    128
#define NYC    256
#define NBCC   16      // B*C = 8*2

#define MPAD(i) ((i) + ((i) >> 5))   // LDS anti-conflict padding map

typedef short bf16x8 __attribute__((ext_vector_type(8)));
typedef float f32x4  __attribute__((ext_vector_type(4)));

__device__ __forceinline__ float2 cmulf(float2 a, float2 b){
    return make_float2(a.x*b.x - a.y*b.y, a.x*b.y + a.y*b.x);
}

#if __has_builtin(__builtin_amdgcn_sinf) && __has_builtin(__builtin_amdgcn_cosf)
__device__ __forceinline__ float sin_rev(float tf){ return __builtin_amdgcn_sinf(tf); }   // sin(2*pi*tf)
__device__ __forceinline__ float cos_rev(float tf){ return __builtin_amdgcn_cosf(tf); }
#else
__device__ __forceinline__ float sin_rev(float tf){ return __sinf(6.28318530718f * tf); }
__device__ __forceinline__ float cos_rev(float tf){ return __cosf(6.28318530718f * tf); }
#endif

__device__ __forceinline__ ushort cvt_bf16(float x){
    uint u = __float_as_uint(x);
    return (ushort)((u + 0x7FFFu + ((u >> 16) & 1u)) >> 16);   // RNE
}

// ---------------- stats stage 1 ----------------
__global__ __launch_bounds__(256) void k_stats1(const float* __restrict__ sino,
                                                float* __restrict__ psum,
                                                float* __restrict__ psq){
    int bc    = blockIdx.x >> 6;
    int chunk = blockIdx.x & 63;
    const float4* p = (const float4*)(sino + (size_t)bc * (N_DETC * N_TC)) + (size_t)chunk * 1024;
    float s = 0.f, q = 0.f;
    #pragma unroll
    for (int i = 0; i < 4; ++i){
        float4 v = p[threadIdx.x + i * 256];
        s += v.x + v.y + v.z + v.w;
        q += v.x*v.x + v.y*v.y + v.z*v.z + v.w*v.w;
    }
    #pragma unroll
    for (int m = 1; m < 64; m <<= 1){
        s += __shfl_xor(s, m, 64);
        q += __shfl_xor(q, m, 64);
    }
    __shared__ float ls[4], lq[4];
    int w = threadIdx.x >> 6, lane = threadIdx.x & 63;
    if (lane == 0){ ls[w] = s; lq[w] = q; }
    __syncthreads();
    if (threadIdx.x == 0){
        psum[blockIdx.x] = ls[0] + ls[1] + ls[2] + ls[3];
        psq[blockIdx.x]  = lq[0] + lq[1] + lq[2] + lq[3];
    }
}

// ---------------- temporal rFFT: half-size complex FFT, stage-paired, padded LDS ----------------
// stats2 folded in: each block reduces psum/psq for its bc.
__global__ __launch_bounds__(256) void k_tfft(const float* __restrict__ sino,
                                              const float* __restrict__ apod,
                                              const float* __restrict__ psum,
                                              const float* __restrict__ psq,
                                              float2* __restrict__ spec){
    int row = blockIdx.x;            // bc*128 + d
    int bc = row >> 7, d = row & 127;
    __shared__ float2 z[1055];       // padded via MPAD
    __shared__ float sm[2];
    int tid = threadIdx.x;
    if (tid < 64){
        float s = psum[bc * 64 + tid], q = psq[bc * 64 + tid];
        #pragma unroll
        for (int m = 1; m < 64; m <<= 1){
            s += __shfl_xor(s, m, 64);
            q += __shfl_xor(q, m, 64);
        }
        if (tid == 0){
            const float inv_n = 1.f / (float)(N_DETC * N_TC);
            float mean = s * inv_n;
            float var  = q * inv_n - mean * mean;
            sm[0] = mean;
            sm[1] = rsqrtf(fmaxf(var, 0.f) + 1.1920929e-7f);
        }
    }
    __syncthreads();
    float mean = sm[0];
    float scl  = sm[1] * apod[d];
    const float2* p = (const float2*)(sino + (size_t)row * N_TC);
    for (int n = tid; n < 1024; n += 256){
        float2 v = p[n];             // x[2n], x[2n+1]
        int r = __brev((unsigned)n) >> 22;   // 10-bit reverse
        z[MPAD(r)] = make_float2((v.x - mean) * scl, (v.y - mean) * scl);
    }
    __syncthreads();
    // 5 fused stage-pairs (== 10 radix-2 stages), one quad per thread
    #pragma unroll
    for (int st = 0; st < 5; ++st){
        int h = 1 << (2 * st);           // 1,4,16,64,256
        int q = tid;
        int k = q & (h - 1);
        int g = q >> (2 * st);
        int base = (g << (2 * st + 2)) + k;
        float2 x0 = z[MPAD(base)];
        float2 x1 = z[MPAD(base + h)];
        float2 x2 = z[MPAD(base + 2 * h)];
        float2 x3 = z[MPAD(base + 3 * h)];
        float a1 = -(float)M_PI * (float)k / (float)h;
        float s1, c1; __sincosf(a1, &s1, &c1);
        float a2 = 0.5f * a1;
        float s2, c2; __sincosf(a2, &s2, &c2);
        float2 t1 = make_float2(x1.x * c1 - x1.y * s1, x1.x * s1 + x1.y * c1);
        float2 t3 = make_float2(x3.x * c1 - x3.y * s1, x3.x * s1 + x3.y * c1);
        float2 y0 = make_float2(x0.x + t1.x, x0.y + t1.y);
        float2 y1 = make_float2(x0.x - t1.x, x0.y - t1.y);
        float2 y2 = make_float2(x2.x + t3.x, x2.y + t3.y);
        float2 y3 = make_float2(x2.x - t3.x, x2.y - t3.y);
        float2 u = make_float2(y2.x * c2 - y2.y * s2, y2.x * s2 + y2.y * c2);
        float2 v = make_float2(y3.x * c2 - y3.y * s2, y3.x * s2 + y3.y * c2);
        float2 w = make_float2(v.y, -v.x);           // -i * v
        z[MPAD(base)]         = make_float2(y0.x + u.x, y0.y + u.y);
        z[MPAD(base + 2 * h)] = make_float2(y0.x - u.x, y0.y - u.y);
        z[MPAD(base + h)]     = make_float2(y1.x + w.x, y1.y + w.y);
        z[MPAD(base + 3 * h)] = make_float2(y1.x - w.x, y1.y - w.y);
        __syncthreads();
    }
    // untangle: X[k] = E + W*O, W = e^{-i*pi*k/1024}
    float2* o = spec + (size_t)row * N_FC;
    for (int k = tid; k < 1025; k += 256){
        float2 A  = z[MPAD(k & 1023)];
        float2 Bv = z[MPAD((1024 - k) & 1023)];
        float Br = Bv.x, Bi = -Bv.y;         // conj
        float Er = 0.5f * (A.x + Br), Ei = 0.5f * (A.y + Bi);
        float Dr = 0.5f * (A.x - Br), Di = 0.5f * (A.y - Bi);
        float Or = Di, Oi = -Dr;             // O = -i*D
        float ang = -(float)M_PI * (float)k * (1.0f / 1024.0f);
        float sn, cs; __sincosf(ang, &sn, &cs);
        float Xr = Er + cs * Or - sn * Oi;
        float Xi = Ei + cs * Oi + sn * Or;
        o[k] = make_float2(Xr, Xi);
    }
}

// ---------------- detector FFT, tile-coalesced + stage-paired ----------------
__global__ __launch_bounds__(256) void k_dft(const float2* __restrict__ spec,
                                             ushort* __restrict__ Arp,
                                             ushort* __restrict__ Aip,
                                             float4* __restrict__ kzJ){
    int bid = blockIdx.x;
    int ft = bid >> 4, bc = bid & 15;
    int f0 = ft << 5;
    int tid = threadIdx.x;
    __shared__ float2 tile[128][33];      // 33.8 KB, padded
    __shared__ ushort stAr[128][40];      // 10 KB
    __shared__ ushort stAi[128][40];      // 10 KB

    int fl  = tid & 31;
    int kd0 = tid >> 5;                   // 0..7
    int f = f0 + fl;
    bool fok = (f <= 1024);
    float fr = (float)f * 19531.25f;      // Hz
    float oc = fr * (1.0f / 1540.0f);     // cycles/m

    #pragma unroll
    for (int i = 0; i < 16; ++i){
        int kd = kd0 + (i << 3);
        int rkd = __brev((unsigned)kd) >> 25;   // 7-bit reverse
        float2 v = fok ? spec[((size_t)(bc * 128 + kd)) * N_FC + f] : make_float2(0.f, 0.f);
        tile[rkd][fl] = v;
    }
    if (bc == 0){
        #pragma unroll
        for (int i = 0; i < 16; ++i){
            int kd = kd0 + (i << 3);
            int sdx = (kd < 64) ? kd : kd - 128;
            float bb = (float)sdx * 26.0416666f;   // 1/(128*3e-4) cycles/m
            float kq = oc * oc - bb * bb;
            float kzr = (fok && kq > 0.f) ? sqrtf(kq) : 0.f;
            float tj = 1.5e-4f * kzr;              // DY*kz revolutions
            tj -= floorf(tj);
            kzJ[(size_t)kd * N_FP + f] = make_float4(kzr, cos_rev(tj), sin_rev(tj), 0.f);
        }
    }
    __syncthreads();
    // 3 fused stage-pairs over kd (stages 1..6), then single stage 7
    #pragma unroll
    for (int st = 0; st < 3; ++st){
        int h = 1 << (2 * st);            // 1,4,16
        #pragma unroll
        for (int it = 0; it < 4; ++it){
            int task = tid + (it << 8);   // 0..1023
            int ff = task & 31;
            int q  = task >> 5;           // 0..31
            int k = q & (h - 1);
            int g = q >> (2 * st);
            int base = (g << (2 * st + 2)) + k;
            float2 x0 = tile[base][ff];
            float2 x1 = tile[base + h][ff];
            float2 x2 = tile[base + 2 * h][ff];
            float2 x3 = tile[base + 3 * h][ff];
            float a1 = -(float)M_PI * (float)k / (float)h;
            float s1, c1; __sincosf(a1, &s1, &c1);
            float a2 = 0.5f * a1;
            float s2, c2; __sincosf(a2, &s2, &c2);
            float2 t1 = make_float2(x1.x * c1 - x1.y * s1, x1.x * s1 + x1.y * c1);
            float2 t3 = make_float2(x3.x * c1 - x3.y * s1, x3.x * s1 + x3.y * c1);
            float2 y0 = make_float2(x0.x + t1.x, x0.y + t1.y);
            float2 y1 = make_float2(x0.x - t1.x, x0.y - t1.y);
            float2 y2 = make_float2(x2.x + t3.x, x2.y + t3.y);
            float2 y3 = make_float2(x2.x - t3.x, x2.y - t3.y);
            float2 u = make_float2(y2.x * c2 - y2.y * s2, y2.x * s2 + y2.y * c2);
            float2 v = make_float2(y3.x * c2 - y3.y * s2, y3.x * s2 + y3.y * c2);
            float2 w = make_float2(v.y, -v.x);
            tile[base][ff]         = make_float2(y0.x + u.x, y0.y + u.y);
            tile[base + 2 * h][ff] = make_float2(y0.x - u.x, y0.y - u.y);
            tile[base + h][ff]     = make_float2(y1.x + w.x, y1.y + w.y);
            tile[base + 3 * h][ff] = make_float2(y1.x - w.x, y1.y - w.y);
        }
        __syncthreads();
    }
    #pragma unroll
    for (int it = 0; it < 8; ++it){
        int task = tid + (it << 8);       // 0..2047
        int ff = task & 31, j = task >> 5;   // 0..63
        int i1 = j, i2 = j + 64;
        float ang = -(float)M_PI * (float)j * (1.0f / 64.0f);
        float sn, cs; __sincosf(ang, &sn, &cs);
        float2 u = tile[i1][ff], v = tile[i2][ff];
        float2 t = make_float2(v.x * cs - v.y * sn, v.x * sn + v.y * cs);
        tile[i1][ff] = make_float2(u.x + t.x, u.y + t.y);
        tile[i2][ff] = make_float2(u.x - t.x, u.y - t.y);
    }
    __syncthreads();
    float fw = (f == 0 || f == 1024) ? 1.f : 2.f;
    #pragma unroll
    for (int i = 0; i < 16; ++i){
        int kd = kd0 + (i << 3);
        int sdx = (kd < 64) ? kd : kd - 128;
        float bb = (float)sdx * 26.0416666f;
        float m = (fok && (oc * oc - bb * bb > 0.f)) ? fw : 0.f;
        float2 v = tile[kd][fl];
        stAr[kd][fl] = cvt_bf16(v.x * m);
        stAi[kd][fl] = cvt_bf16(v.y * m);
    }
    __syncthreads();
    int kds = tid >> 1, hf = tid & 1;
    size_t rowoff = ((size_t)kds * 16 + bc) * N_FP + f0 + hf * 16;
    uint4 r0 = *(const uint4*)&stAr[kds][hf * 16];
    uint4 r1 = *(const uint4*)&stAr[kds][hf * 16 + 8];
    uint4 i0 = *(const uint4*)&stAi[kds][hf * 16];
    uint4 i1v = *(const uint4*)&stAi[kds][hf * 16 + 8];
    ((uint4*)(Arp + rowoff))[0] = r0;
    ((uint4*)(Arp + rowoff))[1] = r1;
    ((uint4*)(Aip + rowoff))[0] = i0;
    ((uint4*)(Aip + rowoff))[1] = i1v;
}

// ---------------- band via MFMA: per kd, C[bc][y] = sum_f A[bc][f] * phase[f][y] ----------------
__global__ __launch_bounds__(512) void k_band(const ushort* __restrict__ Ar,
                                              const ushort* __restrict__ Ai,
                                              const float4* __restrict__ kzJ,
                                              float2* __restrict__ band_b){
    int kd = blockIdx.x >> 1;
    int yh = blockIdx.x & 1;
    int tid  = threadIdx.x;
    int wid  = tid >> 6;
    int lane = tid & 63;
    int fp = tid & 15;          // 0..15 -> f = 32t + 2*fp (+0/1)
    int yq = tid >> 4;          // 0..31 -> y = 4*yq (+0..3)
    float ymg = 1.0e-3f + 1.5e-4f * (float)(yh * 128 + yq * 4);

    __shared__ ushort Bls[2][2][128][40];   // 40960 B

    int arow = lane & 15;
    int koff = (lane >> 4) * 8;
    int ylocal = wid * 16 + arow;
    const ushort* Arp = Ar + ((size_t)kd * 16 + arow) * N_FP + koff;
    const ushort* Aip = Ai + ((size_t)kd * 16 + arow) * N_FP + koff;
    const float4* kjb = kzJ + (size_t)kd * N_FP;

    auto GENC = [&](float4 k0, float4 k1, int buf){
        float t0 = ymg * k0.x; t0 -= floorf(t0);
        float t1 = ymg * k1.x; t1 -= floorf(t1);
        float cA = cos_rev(t0), sA = sin_rev(t0);
        float cB = cos_rev(t1), sB = sin_rev(t1);
        #pragma unroll
        for (int j = 0; j < 4; ++j){
            int y = yq * 4 + j;
            uint br, bi;
            asm("v_cvt_pk_bf16_f32 %0, %1, %2" : "=v"(br) : "v"(cA), "v"(cB));
            asm("v_cvt_pk_bf16_f32 %0, %1, %2" : "=v"(bi) : "v"(sA), "v"(sB));
            *(uint*)&Bls[buf][0][y][fp * 2] = br;
            *(uint*)&Bls[buf][1][y][fp * 2] = bi;
            if (j < 3){
                float nA = fmaf(cA, k0.y, -(sA * k0.z));
                float mA = fmaf(sA, k0.y,  (cA * k0.z));
                cA = nA; sA = mA;
                float nB = fmaf(cB, k1.y, -(sB * k1.z));
                float mB = fmaf(sB, k1.y,  (cB * k1.z));
                cB = nB; sB = mB;
            }
        }
    };

    f32x4 P1 = {0.f,0.f,0.f,0.f}, P2 = P1, P3 = P1, P4 = P1;

    bf16x8 car = *(const bf16x8*)(Arp);
    bf16x8 cai = *(const bf16x8*)(Aip);
    GENC(kjb[fp * 2], kjb[fp * 2 + 1], 0);
    __syncthreads();

    for (int t = 0; t < 33; ++t){
        bf16x8 nar, nai;
        float4 k0, k1;
        if (t < 32){
            nar = *(const bf16x8*)(Arp + (t + 1) * 32);
            nai = *(const bf16x8*)(Aip + (t + 1) * 32);
            k0 = kjb[(t + 1) * 32 + fp * 2];
            k1 = kjb[(t + 1) * 32 + fp * 2 + 1];
        }
        int buf = t & 1;
        bf16x8 br = *(const bf16x8*)&Bls[buf][0][ylocal][koff];
        bf16x8 bi = *(const bf16x8*)&Bls[buf][1][ylocal][koff];
        P1 = __builtin_amdgcn_mfma_f32_16x16x32_bf16(car, br, P1, 0, 0, 0);
        P2 = __builtin_amdgcn_mfma_f32_16x16x32_bf16(cai, bi, P2, 0, 0, 0);
        P3 = __builtin_amdgcn_mfma_f32_16x16x32_bf16(car, bi, P3, 0, 0, 0);
        P4 = __builtin_amdgcn_mfma_f32_16x16x32_bf16(cai, br, P4, 0, 0, 0);
        if (t < 32){
            GENC(k0, k1, buf ^ 1);
        }
        __syncthreads();
        if (t < 32){ car = nar; cai = nai; }
    }

    int y = yh * 128 + wid * 16 + (lane & 15);
    #pragma unroll
    for (int r = 0; r < 4; ++r){
        int bc = (lane >> 4) * 4 + r;
        band_b[((size_t)kd * 16 + bc) * 256 + y] = make_float2(P1[r] - P2[r], P3[r] + P4[r]);
    }
}

// ---------------- final: 128-pt inverse DFT over kd, magnitude, norm (apod-sum inline) ----------------
__global__ __launch_bounds__(256) void k_final(const float2* __restrict__ band_b,
                                               const float* __restrict__ apod,
                                               float* __restrict__ out){
    int blk = blockIdx.x;            // bc*32 + yt
    int bc = blk >> 5, yt = blk & 31;
    __shared__ float2 ld[128][9];
    __shared__ float asum;
    int tid = threadIdx.x;
    if (tid < 64){
        float a = apod[tid] + apod[tid + 64];
        #pragma unroll
        for (int m = 1; m < 64; m <<= 1) a += __shfl_xor(a, m, 64);
        if (tid == 0) asum = a;
    }
    #pragma unroll
    for (int k2 = 0; k2 < 4; ++k2){
        int idx = tid + k2 * 256;
        int kd = idx >> 3, yi = idx & 7;
        ld[kd][yi] = band_b[((size_t)kd * 16 + bc) * 256 + yt * 8 + yi];
    }
    __syncthreads();
    int x = tid & 127, h = tid >> 7;
    float ang = (float)(2.0 * M_PI / 128.0) * (float)x;
    float sn, cs; sincosf(ang, &sn, &cs);
    float2 w = make_float2(cs, sn);
    float2 p = make_float2(1.f, 0.f);
    float aR[4] = {0.f,0.f,0.f,0.f}, aI[4] = {0.f,0.f,0.f,0.f};
    for (int kd = 0; kd < 128; ++kd){
        #pragma unroll
        for (int qq = 0; qq < 4; ++qq){
            float2 b = ld[kd][h * 4 + qq];
            aR[qq] += b.x * p.x - b.y * p.y;
            aI[qq] += b.x * p.y + b.y * p.x;
        }
        p = cmulf(p, w);
    }
    float invnorm = 1.f / (fmaxf(asum, 1.1920929e-7f) * 2048.f);
    #pragma unroll
    for (int qq = 0; qq < 4; ++qq){
        int y = yt * 8 + h * 4 + qq;
        out[((size_t)bc * 256 + y) * 128 + x] = sqrtf(aR[qq]*aR[qq] + aI[qq]*aI[qq]) * invnorm;
    }
}

extern "C" void kernel_launch(void* const* d_in, const int* in_sizes, int n_in,
                              void* d_out, int out_size, void* d_ws, size_t ws_size,
                              hipStream_t stream){
    const float* sino = (const float*)d_in[0];
    const float* apod = (const float*)d_in[1];
    float* out = (float*)d_out;
    float* W = (float*)d_ws;
    // workspace layout (float offsets):
    //   [64..1087]    psum
    //   [1088..2111]  psq
    //   2112          spec   : 16*128*1025 float2 = 4,198,400 floats (dead after k_dft; aliased by band_b)
    //   +4,198,400    Ar/Ai  : 16*128*1056 ushort each
    //   then          kzJ    : 128*1056 float4
    float* psum = W + 64;
    float* psq  = W + 1088;
    float2* spec  = (float2*)(W + 2112);
    ushort* Arp   = (ushort*)(W + 2112 + 4198400);
    ushort* Aip   = Arp + (size_t)16 * 128 * N_FP;
    float4* kzJ   = (float4*)(W + 2112 + 4198400 + 2162688);
    float2* band_b = spec;   // 128*16*256 float2 = 1,048,576 floats <= spec size

    k_stats1<<<NBCC * 64, 256, 0, stream>>>(sino, psum, psq);
    k_tfft  <<<NBCC * N_DETC, 256, 0, stream>>>(sino, apod, psum, psq, spec);
    k_dft   <<<33 * 16, 256, 0, stream>>>(spec, Arp, Aip, kzJ);
    k_band  <<<256, 512, 0, stream>>>(Arp, Aip, kzJ, band_b);
    k_final <<<NBCC * 32, 256, 0, stream>>>(band_b, apod, out);
}

// Round 12
// 69.832 us; speedup vs baseline: 1.9592x; 1.2901x over previous
//
#include <hip/hip_runtime.h>
#include <math.h>

#define N_DETC 128
#define N_TC   2048
#define N_FC   1025
#define N_FP   1056    // padded f (33 K-steps of 32)
#define NXC    128
#define NYC    256
#define NBCC   16      // B*C = 8*2

#define MPAD(i) ((i) + ((i) >> 5))   // LDS anti-conflict padding map

typedef short bf16x8 __attribute__((ext_vector_type(8)));
typedef float f32x4  __attribute__((ext_vector_type(4)));

__device__ __forceinline__ float2 cmulf(float2 a, float2 b){
    return make_float2(a.x*b.x - a.y*b.y, a.x*b.y + a.y*b.x);
}

#if __has_builtin(__builtin_amdgcn_sinf) && __has_builtin(__builtin_amdgcn_cosf)
__device__ __forceinline__ float sin_rev(float tf){ return __builtin_amdgcn_sinf(tf); }   // sin(2*pi*tf)
__device__ __forceinline__ float cos_rev(float tf){ return __builtin_amdgcn_cosf(tf); }
#else
__device__ __forceinline__ float sin_rev(float tf){ return __sinf(6.28318530718f * tf); }
__device__ __forceinline__ float cos_rev(float tf){ return __cosf(6.28318530718f * tf); }
#endif

__device__ __forceinline__ ushort cvt_bf16(float x){
    uint u = __float_as_uint(x);
    return (ushort)((u + 0x7FFFu + ((u >> 16) & 1u)) >> 16);   // RNE
}

// ---------------- stats stage 1 ----------------
__global__ __launch_bounds__(256) void k_stats1(const float* __restrict__ sino,
                                                float* __restrict__ psum,
                                                float* __restrict__ psq){
    int bc    = blockIdx.x >> 6;
    int chunk = blockIdx.x & 63;
    const float4* p = (const float4*)(sino + (size_t)bc * (N_DETC * N_TC)) + (size_t)chunk * 1024;
    float s = 0.f, q = 0.f;
    #pragma unroll
    for (int i = 0; i < 4; ++i){
        float4 v = p[threadIdx.x + i * 256];
        s += v.x + v.y + v.z + v.w;
        q += v.x*v.x + v.y*v.y + v.z*v.z + v.w*v.w;
    }
    #pragma unroll
    for (int m = 1; m < 64; m <<= 1){
        s += __shfl_xor(s, m, 64);
        q += __shfl_xor(q, m, 64);
    }
    __shared__ float ls[4], lq[4];
    int w = threadIdx.x >> 6, lane = threadIdx.x & 63;
    if (lane == 0){ ls[w] = s; lq[w] = q; }
    __syncthreads();
    if (threadIdx.x == 0){
        psum[blockIdx.x] = ls[0] + ls[1] + ls[2] + ls[3];
        psq[blockIdx.x]  = lq[0] + lq[1] + lq[2] + lq[3];
    }
}

// ---------------- temporal rFFT: half-size complex FFT, stage-paired, padded LDS ----------------
__global__ __launch_bounds__(256) void k_tfft(const float* __restrict__ sino,
                                              const float* __restrict__ apod,
                                              const float* __restrict__ psum,
                                              const float* __restrict__ psq,
                                              float2* __restrict__ spec){
    int row = blockIdx.x;            // bc*128 + d
    int bc = row >> 7, d = row & 127;
    __shared__ float2 z[1055];       // padded via MPAD
    __shared__ float sm[2];
    int tid = threadIdx.x;
    if (tid < 64){
        float s = psum[bc * 64 + tid], q = psq[bc * 64 + tid];
        #pragma unroll
        for (int m = 1; m < 64; m <<= 1){
            s += __shfl_xor(s, m, 64);
            q += __shfl_xor(q, m, 64);
        }
        if (tid == 0){
            const float inv_n = 1.f / (float)(N_DETC * N_TC);
            float mean = s * inv_n;
            float var  = q * inv_n - mean * mean;
            sm[0] = mean;
            sm[1] = rsqrtf(fmaxf(var, 0.f) + 1.1920929e-7f);
        }
    }
    __syncthreads();
    float mean = sm[0];
    float scl  = sm[1] * apod[d];
    const float2* p = (const float2*)(sino + (size_t)row * N_TC);
    for (int n = tid; n < 1024; n += 256){
        float2 v = p[n];             // x[2n], x[2n+1]
        int r = __brev((unsigned)n) >> 22;   // 10-bit reverse
        z[MPAD(r)] = make_float2((v.x - mean) * scl, (v.y - mean) * scl);
    }
    __syncthreads();
    #pragma unroll
    for (int st = 0; st < 5; ++st){
        int h = 1 << (2 * st);           // 1,4,16,64,256
        int q = tid;
        int k = q & (h - 1);
        int g = q >> (2 * st);
        int base = (g << (2 * st + 2)) + k;
        float2 x0 = z[MPAD(base)];
        float2 x1 = z[MPAD(base + h)];
        float2 x2 = z[MPAD(base + 2 * h)];
        float2 x3 = z[MPAD(base + 3 * h)];
        float a1 = -(float)M_PI * (float)k / (float)h;
        float s1, c1; __sincosf(a1, &s1, &c1);
        float a2 = 0.5f * a1;
        float s2, c2; __sincosf(a2, &s2, &c2);
        float2 t1 = make_float2(x1.x * c1 - x1.y * s1, x1.x * s1 + x1.y * c1);
        float2 t3 = make_float2(x3.x * c1 - x3.y * s1, x3.x * s1 + x3.y * c1);
        float2 y0 = make_float2(x0.x + t1.x, x0.y + t1.y);
        float2 y1 = make_float2(x0.x - t1.x, x0.y - t1.y);
        float2 y2 = make_float2(x2.x + t3.x, x2.y + t3.y);
        float2 y3 = make_float2(x2.x - t3.x, x2.y - t3.y);
        float2 u = make_float2(y2.x * c2 - y2.y * s2, y2.x * s2 + y2.y * c2);
        float2 v = make_float2(y3.x * c2 - y3.y * s2, y3.x * s2 + y3.y * c2);
        float2 w = make_float2(v.y, -v.x);           // -i * v
        z[MPAD(base)]         = make_float2(y0.x + u.x, y0.y + u.y);
        z[MPAD(base + 2 * h)] = make_float2(y0.x - u.x, y0.y - u.y);
        z[MPAD(base + h)]     = make_float2(y1.x + w.x, y1.y + w.y);
        z[MPAD(base + 3 * h)] = make_float2(y1.x - w.x, y1.y - w.y);
        __syncthreads();
    }
    float2* o = spec + (size_t)row * N_FC;
    for (int k = tid; k < 1025; k += 256){
        float2 A  = z[MPAD(k & 1023)];
        float2 Bv = z[MPAD((1024 - k) & 1023)];
        float Br = Bv.x, Bi = -Bv.y;         // conj
        float Er = 0.5f * (A.x + Br), Ei = 0.5f * (A.y + Bi);
        float Dr = 0.5f * (A.x - Br), Di = 0.5f * (A.y - Bi);
        float Or = Di, Oi = -Dr;             // O = -i*D
        float ang = -(float)M_PI * (float)k * (1.0f / 1024.0f);
        float sn, cs; __sincosf(ang, &sn, &cs);
        float Xr = Er + cs * Or - sn * Oi;
        float Xi = Ei + cs * Oi + sn * Or;
        o[k] = make_float2(Xr, Xi);
    }
}

// ---------------- detector FFT, tile-coalesced + stage-paired ----------------
__global__ __launch_bounds__(256) void k_dft(const float2* __restrict__ spec,
                                             ushort* __restrict__ Arp,
                                             ushort* __restrict__ Aip,
                                             float4* __restrict__ kzJ){
    int bid = blockIdx.x;
    int ft = bid >> 4, bc = bid & 15;
    int f0 = ft << 5;
    int tid = threadIdx.x;
    __shared__ float2 tile[128][33];
    __shared__ ushort stAr[128][40];
    __shared__ ushort stAi[128][40];

    int fl  = tid & 31;
    int kd0 = tid >> 5;
    int f = f0 + fl;
    bool fok = (f <= 1024);
    float fr = (float)f * 19531.25f;
    float oc = fr * (1.0f / 1540.0f);

    #pragma unroll
    for (int i = 0; i < 16; ++i){
        int kd = kd0 + (i << 3);
        int rkd = __brev((unsigned)kd) >> 25;
        float2 v = fok ? spec[((size_t)(bc * 128 + kd)) * N_FC + f] : make_float2(0.f, 0.f);
        tile[rkd][fl] = v;
    }
    if (bc == 0){
        #pragma unroll
        for (int i = 0; i < 16; ++i){
            int kd = kd0 + (i << 3);
            int sdx = (kd < 64) ? kd : kd - 128;
            float bb = (float)sdx * 26.0416666f;
            float kq = oc * oc - bb * bb;
            float kzr = (fok && kq > 0.f) ? sqrtf(kq) : 0.f;
            float tj = 1.5e-4f * kzr;
            tj -= floorf(tj);
            kzJ[(size_t)kd * N_FP + f] = make_float4(kzr, cos_rev(tj), sin_rev(tj), 0.f);
        }
    }
    __syncthreads();
    #pragma unroll
    for (int st = 0; st < 3; ++st){
        int h = 1 << (2 * st);
        #pragma unroll
        for (int it = 0; it < 4; ++it){
            int task = tid + (it << 8);
            int ff = task & 31;
            int q  = task >> 5;
            int k = q & (h - 1);
            int g = q >> (2 * st);
            int base = (g << (2 * st + 2)) + k;
            float2 x0 = tile[base][ff];
            float2 x1 = tile[base + h][ff];
            float2 x2 = tile[base + 2 * h][ff];
            float2 x3 = tile[base + 3 * h][ff];
            float a1 = -(float)M_PI * (float)k / (float)h;
            float s1, c1; __sincosf(a1, &s1, &c1);
            float a2 = 0.5f * a1;
            float s2, c2; __sincosf(a2, &s2, &c2);
            float2 t1 = make_float2(x1.x * c1 - x1.y * s1, x1.x * s1 + x1.y * c1);
            float2 t3 = make_float2(x3.x * c1 - x3.y * s1, x3.x * s1 + x3.y * c1);
            float2 y0 = make_float2(x0.x + t1.x, x0.y + t1.y);
            float2 y1 = make_float2(x0.x - t1.x, x0.y - t1.y);
            float2 y2 = make_float2(x2.x + t3.x, x2.y + t3.y);
            float2 y3 = make_float2(x2.x - t3.x, x2.y - t3.y);
            float2 u = make_float2(y2.x * c2 - y2.y * s2, y2.x * s2 + y2.y * c2);
            float2 v = make_float2(y3.x * c2 - y3.y * s2, y3.x * s2 + y3.y * c2);
            float2 w = make_float2(v.y, -v.x);
            tile[base][ff]         = make_float2(y0.x + u.x, y0.y + u.y);
            tile[base + 2 * h][ff] = make_float2(y0.x - u.x, y0.y - u.y);
            tile[base + h][ff]     = make_float2(y1.x + w.x, y1.y + w.y);
            tile[base + 3 * h][ff] = make_float2(y1.x - w.x, y1.y - w.y);
        }
        __syncthreads();
    }
    #pragma unroll
    for (int it = 0; it < 8; ++it){
        int task = tid + (it << 8);
        int ff = task & 31, j = task >> 5;
        int i1 = j, i2 = j + 64;
        float ang = -(float)M_PI * (float)j * (1.0f / 64.0f);
        float sn, cs; __sincosf(ang, &sn, &cs);
        float2 u = tile[i1][ff], v = tile[i2][ff];
        float2 t = make_float2(v.x * cs - v.y * sn, v.x * sn + v.y * cs);
        tile[i1][ff] = make_float2(u.x + t.x, u.y + t.y);
        tile[i2][ff] = make_float2(u.x - t.x, u.y - t.y);
    }
    __syncthreads();
    float fw = (f == 0 || f == 1024) ? 1.f : 2.f;
    #pragma unroll
    for (int i = 0; i < 16; ++i){
        int kd = kd0 + (i << 3);
        int sdx = (kd < 64) ? kd : kd - 128;
        float bb = (float)sdx * 26.0416666f;
        float m = (fok && (oc * oc - bb * bb > 0.f)) ? fw : 0.f;
        float2 v = tile[kd][fl];
        stAr[kd][fl] = cvt_bf16(v.x * m);
        stAi[kd][fl] = cvt_bf16(v.y * m);
    }
    __syncthreads();
    int kds = tid >> 1, hf = tid & 1;
    size_t rowoff = ((size_t)kds * 16 + bc) * N_FP + f0 + hf * 16;
    uint4 r0 = *(const uint4*)&stAr[kds][hf * 16];
    uint4 r1 = *(const uint4*)&stAr[kds][hf * 16 + 8];
    uint4 i0 = *(const uint4*)&stAi[kds][hf * 16];
    uint4 i1v = *(const uint4*)&stAi[kds][hf * 16 + 8];
    ((uint4*)(Arp + rowoff))[0] = r0;
    ((uint4*)(Arp + rowoff))[1] = r1;
    ((uint4*)(Aip + rowoff))[0] = i0;
    ((uint4*)(Aip + rowoff))[1] = i1v;
}

// ---------------- band via MFMA, f-split in 2 chunks: block=(kd, yh, fc) ----------------
__global__ __launch_bounds__(512) void k_band(const ushort* __restrict__ Ar,
                                              const ushort* __restrict__ Ai,
                                              const float4* __restrict__ kzJ,
                                              float2* __restrict__ band_p){
    int blk = blockIdx.x;
    int fc = blk & 1;
    int yh = (blk >> 1) & 1;
    int kd = blk >> 2;
    int nt = fc ? 17 : 16;
    int tid  = threadIdx.x;
    int wid  = tid >> 6;
    int lane = tid & 63;
    int fp = tid & 15;
    int yq = tid >> 4;
    float ymg = 1.0e-3f + 1.5e-4f * (float)(yh * 128 + yq * 4);

    __shared__ ushort Bls[2][2][128][40];

    int arow = lane & 15;
    int koff = (lane >> 4) * 8;
    int ylocal = wid * 16 + arow;
    const ushort* Arp = Ar + ((size_t)kd * 16 + arow) * N_FP + koff + fc * 512;
    const ushort* Aip = Ai + ((size_t)kd * 16 + arow) * N_FP + koff + fc * 512;
    const float4* kjb = kzJ + (size_t)kd * N_FP + fc * 512;

    auto GENC = [&](float4 k0, float4 k1, int buf){
        float t0 = ymg * k0.x; t0 -= floorf(t0);
        float t1 = ymg * k1.x; t1 -= floorf(t1);
        float cA = cos_rev(t0), sA = sin_rev(t0);
        float cB = cos_rev(t1), sB = sin_rev(t1);
        #pragma unroll
        for (int j = 0; j < 4; ++j){
            int y = yq * 4 + j;
            uint br, bi;
            asm("v_cvt_pk_bf16_f32 %0, %1, %2" : "=v"(br) : "v"(cA), "v"(cB));
            asm("v_cvt_pk_bf16_f32 %0, %1, %2" : "=v"(bi) : "v"(sA), "v"(sB));
            *(uint*)&Bls[buf][0][y][fp * 2] = br;
            *(uint*)&Bls[buf][1][y][fp * 2] = bi;
            if (j < 3){
                float nA = fmaf(cA, k0.y, -(sA * k0.z));
                float mA = fmaf(sA, k0.y,  (cA * k0.z));
                cA = nA; sA = mA;
                float nB = fmaf(cB, k1.y, -(sB * k1.z));
                float mB = fmaf(sB, k1.y,  (cB * k1.z));
                cB = nB; sB = mB;
            }
        }
    };

    f32x4 P1 = {0.f,0.f,0.f,0.f}, P2 = P1, P3 = P1, P4 = P1;

    bf16x8 car = *(const bf16x8*)(Arp);
    bf16x8 cai = *(const bf16x8*)(Aip);
    GENC(kjb[fp * 2], kjb[fp * 2 + 1], 0);
    __syncthreads();

    for (int t = 0; t < nt; ++t){
        bf16x8 nar, nai;
        float4 k0, k1;
        if (t < nt - 1){
            nar = *(const bf16x8*)(Arp + (t + 1) * 32);
            nai = *(const bf16x8*)(Aip + (t + 1) * 32);
            k0 = kjb[(t + 1) * 32 + fp * 2];
            k1 = kjb[(t + 1) * 32 + fp * 2 + 1];
        }
        int buf = t & 1;
        bf16x8 br = *(const bf16x8*)&Bls[buf][0][ylocal][koff];
        bf16x8 bi = *(const bf16x8*)&Bls[buf][1][ylocal][koff];
        P1 = __builtin_amdgcn_mfma_f32_16x16x32_bf16(car, br, P1, 0, 0, 0);
        P2 = __builtin_amdgcn_mfma_f32_16x16x32_bf16(cai, bi, P2, 0, 0, 0);
        P3 = __builtin_amdgcn_mfma_f32_16x16x32_bf16(car, bi, P3, 0, 0, 0);
        P4 = __builtin_amdgcn_mfma_f32_16x16x32_bf16(cai, br, P4, 0, 0, 0);
        if (t < nt - 1){
            GENC(k0, k1, buf ^ 1);
        }
        __syncthreads();
        if (t < nt - 1){ car = nar; cai = nai; }
    }

    int y = yh * 128 + wid * 16 + (lane & 15);
    #pragma unroll
    for (int r = 0; r < 4; ++r){
        int bc = (lane >> 4) * 4 + r;
        band_p[(((size_t)fc * 128 + kd) * 16 + bc) * 256 + y] = make_float2(P1[r] - P2[r], P3[r] + P4[r]);
    }
}

// ---------------- final: sum 2 partials, 128-pt inverse FFT over kd (stage-paired), |.| ----------------
__global__ __launch_bounds__(256) void k_final(const float2* __restrict__ band_p,
                                               const float* __restrict__ apod,
                                               float* __restrict__ out){
    int blk = blockIdx.x;            // bc*32 + yt
    int bc = blk >> 5, yt = blk & 31;
    __shared__ float2 tile[128][9];
    __shared__ float asum;
    int tid = threadIdx.x;
    if (tid < 64){
        float a = apod[tid] + apod[tid + 64];
        #pragma unroll
        for (int m = 1; m < 64; m <<= 1) a += __shfl_xor(a, m, 64);
        if (tid == 0) asum = a;
    }
    #pragma unroll
    for (int k2 = 0; k2 < 4; ++k2){
        int idx = tid + k2 * 256;
        int kd = idx >> 3, yi = idx & 7;
        size_t o0 = (((size_t)0 * 128 + kd) * 16 + bc) * 256 + yt * 8 + yi;
        size_t o1 = (((size_t)1 * 128 + kd) * 16 + bc) * 256 + yt * 8 + yi;
        float2 a = band_p[o0], b = band_p[o1];
        int rkd = __brev((unsigned)kd) >> 25;   // 7-bit reverse
        tile[rkd][yi] = make_float2(a.x + b.x, a.y + b.y);
    }
    __syncthreads();
    // inverse FFT over kd: 3 fused stage-pairs + 1 single stage, conj twiddles
    #pragma unroll
    for (int st = 0; st < 3; ++st){
        int h = 1 << (2 * st);            // 1,4,16
        int q  = tid >> 3;                // 0..31 quad
        int yi = tid & 7;
        int k = q & (h - 1);
        int g = q >> (2 * st);
        int base = (g << (2 * st + 2)) + k;
        float2 x0 = tile[base][yi];
        float2 x1 = tile[base + h][yi];
        float2 x2 = tile[base + 2 * h][yi];
        float2 x3 = tile[base + 3 * h][yi];
        float a1 = (float)M_PI * (float)k / (float)h;      // +ve: inverse
        float s1, c1; __sincosf(a1, &s1, &c1);
        float a2 = 0.5f * a1;
        float s2, c2; __sincosf(a2, &s2, &c2);
        float2 t1 = make_float2(x1.x * c1 - x1.y * s1, x1.x * s1 + x1.y * c1);
        float2 t3 = make_float2(x3.x * c1 - x3.y * s1, x3.x * s1 + x3.y * c1);
        float2 y0 = make_float2(x0.x + t1.x, x0.y + t1.y);
        float2 y1 = make_float2(x0.x - t1.x, x0.y - t1.y);
        float2 y2 = make_float2(x2.x + t3.x, x2.y + t3.y);
        float2 y3 = make_float2(x2.x - t3.x, x2.y - t3.y);
        float2 u = make_float2(y2.x * c2 - y2.y * s2, y2.x * s2 + y2.y * c2);
        float2 v = make_float2(y3.x * c2 - y3.y * s2, y3.x * s2 + y3.y * c2);
        float2 w = make_float2(-v.y, v.x);                 // +i * v (inverse)
        tile[base][yi]         = make_float2(y0.x + u.x, y0.y + u.y);
        tile[base + 2 * h][yi] = make_float2(y0.x - u.x, y0.y - u.y);
        tile[base + h][yi]     = make_float2(y1.x + w.x, y1.y + w.y);
        tile[base + 3 * h][yi] = make_float2(y1.x - w.x, y1.y - w.y);
        __syncthreads();
    }
    #pragma unroll
    for (int it = 0; it < 2; ++it){
        int task = tid + (it << 8);       // 0..511
        int yi = task & 7, j = task >> 3; // j = 0..63
        float ang = (float)M_PI * (float)j * (1.0f / 64.0f);
        float sn, cs; __sincosf(ang, &sn, &cs);
        float2 u = tile[j][yi], v = tile[j + 64][yi];
        float2 t = make_float2(v.x * cs - v.y * sn, v.x * sn + v.y * cs);
        tile[j][yi]      = make_float2(u.x + t.x, u.y + t.y);
        tile[j + 64][yi] = make_float2(u.x - t.x, u.y - t.y);
    }
    __syncthreads();
    float invnorm = 1.f / (fmaxf(asum, 1.1920929e-7f) * 2048.f);
    #pragma unroll
    for (int k2 = 0; k2 < 4; ++k2){
        int idx = tid + k2 * 256;
        int x = idx & 127, yi = idx >> 7;
        float2 v = tile[x][yi];
        int y = yt * 8 + yi;
        out[((size_t)bc * 256 + y) * 128 + x] = sqrtf(v.x * v.x + v.y * v.y) * invnorm;
    }
}

extern "C" void kernel_launch(void* const* d_in, const int* in_sizes, int n_in,
                              void* d_out, int out_size, void* d_ws, size_t ws_size,
                              hipStream_t stream){
    const float* sino = (const float*)d_in[0];
    const float* apod = (const float*)d_in[1];
    float* out = (float*)d_out;
    float* W = (float*)d_ws;
    // workspace layout (float offsets):
    //   [64..1087]    psum
    //   [1088..2111]  psq
    //   2112          spec   : 16*128*1025 float2 = 4,198,400 floats (dead after k_dft; aliased by band_p)
    //   +4,198,400    Ar/Ai  : 16*128*1056 ushort each
    //   then          kzJ    : 128*1056 float4
    float* psum = W + 64;
    float* psq  = W + 1088;
    float2* spec  = (float2*)(W + 2112);
    ushort* Arp   = (ushort*)(W + 2112 + 4198400);
    ushort* Aip   = Arp + (size_t)16 * 128 * N_FP;
    float4* kzJ   = (float4*)(W + 2112 + 4198400 + 2162688);
    float2* band_p = spec;   // 2*128*16*256 float2 = 2,097,152 floats... (8.4 MB) <= spec region (16.8 MB)

    k_stats1<<<NBCC * 64, 256, 0, stream>>>(sino, psum, psq);
    k_tfft  <<<NBCC * N_DETC, 256, 0, stream>>>(sino, apod, psum, psq, spec);
    k_dft   <<<33 * 16, 256, 0, stream>>>(spec, Arp, Aip, kzJ);
    k_band  <<<512, 512, 0, stream>>>(Arp, Aip, kzJ, band_p);
    k_final <<<NBCC * 32, 256, 0, stream>>>(band_p, apod, out);
}

// Round 13
// 65.469 us; speedup vs baseline: 2.0898x; 1.0666x over previous
//
#include <hip/hip_runtime.h>
#include <math.h>

#define N_DETC 128
#define N_TC   2048
#define N_FC   1025
#define N_FP   1056    // padded f (33 K-steps of 32)
#define NXC    128
#define NYC    256
#define NBCC   16      // B*C = 8*2

#define MPAD(i) ((i) + ((i) >> 5))   // LDS anti-conflict padding map

typedef short bf16x8 __attribute__((ext_vector_type(8)));
typedef float f32x4  __attribute__((ext_vector_type(4)));

__device__ __forceinline__ float2 cmulf(float2 a, float2 b){
    return make_float2(a.x*b.x - a.y*b.y, a.x*b.y + a.y*b.x);
}

#if __has_builtin(__builtin_amdgcn_sinf) && __has_builtin(__builtin_amdgcn_cosf)
__device__ __forceinline__ float sin_rev(float tf){ return __builtin_amdgcn_sinf(tf); }   // sin(2*pi*tf)
__device__ __forceinline__ float cos_rev(float tf){ return __builtin_amdgcn_cosf(tf); }
#else
__device__ __forceinline__ float sin_rev(float tf){ return __sinf(6.28318530718f * tf); }
__device__ __forceinline__ float cos_rev(float tf){ return __cosf(6.28318530718f * tf); }
#endif

__device__ __forceinline__ ushort cvt_bf16(float x){
    uint u = __float_as_uint(x);
    return (ushort)((u + 0x7FFFu + ((u >> 16) & 1u)) >> 16);   // RNE
}

// ---------------- temporal rFFT on RAW sino + per-row stats; bf16-packed spec ----------------
__global__ __launch_bounds__(256) void k_tfft(const float* __restrict__ sino,
                                              float* __restrict__ psum,
                                              float* __restrict__ psq,
                                              uint* __restrict__ spec_u){
    int row = blockIdx.x;            // bc*128 + d
    __shared__ float2 z[1055];       // padded via MPAD
    __shared__ float ls[4], lq[4];
    int tid = threadIdx.x;
    const float2* p = (const float2*)(sino + (size_t)row * N_TC);
    float s = 0.f, q = 0.f;
    for (int n = tid; n < 1024; n += 256){
        float2 v = p[n];             // x[2n], x[2n+1]
        s += v.x + v.y;
        q += v.x * v.x + v.y * v.y;
        int r = __brev((unsigned)n) >> 22;   // 10-bit reverse
        z[MPAD(r)] = v;
    }
    #pragma unroll
    for (int m = 1; m < 64; m <<= 1){
        s += __shfl_xor(s, m, 64);
        q += __shfl_xor(q, m, 64);
    }
    int w = tid >> 6, lane = tid & 63;
    if (lane == 0){ ls[w] = s; lq[w] = q; }
    __syncthreads();
    if (tid == 0){
        psum[row] = ls[0] + ls[1] + ls[2] + ls[3];
        psq[row]  = lq[0] + lq[1] + lq[2] + lq[3];
    }
    #pragma unroll
    for (int st = 0; st < 5; ++st){
        int h = 1 << (2 * st);           // 1,4,16,64,256
        int qd = tid;
        int k = qd & (h - 1);
        int g = qd >> (2 * st);
        int base = (g << (2 * st + 2)) + k;
        float2 x0 = z[MPAD(base)];
        float2 x1 = z[MPAD(base + h)];
        float2 x2 = z[MPAD(base + 2 * h)];
        float2 x3 = z[MPAD(base + 3 * h)];
        float a1 = -(float)M_PI * (float)k / (float)h;
        float s1, c1; __sincosf(a1, &s1, &c1);
        float a2 = 0.5f * a1;
        float s2, c2; __sincosf(a2, &s2, &c2);
        float2 t1 = make_float2(x1.x * c1 - x1.y * s1, x1.x * s1 + x1.y * c1);
        float2 t3 = make_float2(x3.x * c1 - x3.y * s1, x3.x * s1 + x3.y * c1);
        float2 y0 = make_float2(x0.x + t1.x, x0.y + t1.y);
        float2 y1 = make_float2(x0.x - t1.x, x0.y - t1.y);
        float2 y2 = make_float2(x2.x + t3.x, x2.y + t3.y);
        float2 y3 = make_float2(x2.x - t3.x, x2.y - t3.y);
        float2 u = make_float2(y2.x * c2 - y2.y * s2, y2.x * s2 + y2.y * c2);
        float2 v = make_float2(y3.x * c2 - y3.y * s2, y3.x * s2 + y3.y * c2);
        float2 wv = make_float2(v.y, -v.x);          // -i * v
        z[MPAD(base)]         = make_float2(y0.x + u.x, y0.y + u.y);
        z[MPAD(base + 2 * h)] = make_float2(y0.x - u.x, y0.y - u.y);
        z[MPAD(base + h)]     = make_float2(y1.x + wv.x, y1.y + wv.y);
        z[MPAD(base + 3 * h)] = make_float2(y1.x - wv.x, y1.y - wv.y);
        __syncthreads();
    }
    // untangle + bf16 pack: X[k] = E + W*O, W = e^{-i*pi*k/1024}
    uint* o = spec_u + (size_t)row * N_FC;
    for (int k = tid; k < 1025; k += 256){
        float2 A  = z[MPAD(k & 1023)];
        float2 Bv = z[MPAD((1024 - k) & 1023)];
        float Br = Bv.x, Bi = -Bv.y;         // conj
        float Er = 0.5f * (A.x + Br), Ei = 0.5f * (A.y + Bi);
        float Dr = 0.5f * (A.x - Br), Di = 0.5f * (A.y - Bi);
        float Or = Di, Oi = -Dr;             // O = -i*D
        float ang = -(float)M_PI * (float)k * (1.0f / 1024.0f);
        float sn, cs; __sincosf(ang, &sn, &cs);
        float Xr = Er + cs * Or - sn * Oi;
        float Xi = Ei + cs * Oi + sn * Or;
        uint pk;
        asm("v_cvt_pk_bf16_f32 %0, %1, %2" : "=v"(pk) : "v"(Xr), "v"(Xi));
        o[k] = pk;
    }
}

// ---------------- detector FFT: stats-finalize + standardize + DC fix + kd-FFT -> bf16 A ----------------
__global__ __launch_bounds__(256) void k_dft(const uint* __restrict__ spec_u,
                                             const float* __restrict__ psum,
                                             const float* __restrict__ psq,
                                             const float* __restrict__ apod,
                                             ushort* __restrict__ Arp,
                                             ushort* __restrict__ Aip,
                                             float4* __restrict__ kzJ){
    int bid = blockIdx.x;
    int ft = bid >> 4, bc = bid & 15;
    int f0 = ft << 5;
    int tid = threadIdx.x;
    __shared__ float2 tile[128][33];
    __shared__ ushort stAr[128][40];
    __shared__ ushort stAi[128][40];
    __shared__ float sm[2];

    if (tid < 64){
        float s = psum[bc * 128 + tid] + psum[bc * 128 + 64 + tid];
        float q = psq[bc * 128 + tid] + psq[bc * 128 + 64 + tid];
        #pragma unroll
        for (int m = 1; m < 64; m <<= 1){
            s += __shfl_xor(s, m, 64);
            q += __shfl_xor(q, m, 64);
        }
        if (tid == 0){
            const float inv_n = 1.f / (float)(N_DETC * N_TC);
            float mean = s * inv_n;
            float var  = q * inv_n - mean * mean;
            sm[0] = mean;
            sm[1] = rsqrtf(fmaxf(var, 0.f) + 1.1920929e-7f);
        }
    }
    __syncthreads();
    float mean = sm[0], invstd = sm[1];

    int fl  = tid & 31;
    int kd0 = tid >> 5;
    int f = f0 + fl;
    bool fok = (f <= 1024);
    float fr = (float)f * 19531.25f;
    float oc = fr * (1.0f / 1540.0f);

    #pragma unroll
    for (int i = 0; i < 16; ++i){
        int kd = kd0 + (i << 3);
        int rkd = __brev((unsigned)kd) >> 25;
        uint u = fok ? spec_u[((size_t)(bc * 128 + kd)) * N_FC + f] : 0u;
        float vr = __uint_as_float(u << 16);
        float vi = __uint_as_float(u & 0xFFFF0000u);
        if (f == 0) vr -= mean * 2048.f;
        float sc = apod[kd] * invstd;
        tile[rkd][fl] = make_float2(vr * sc, vi * sc);
    }
    if (bc == 0){
        #pragma unroll
        for (int i = 0; i < 16; ++i){
            int kd = kd0 + (i << 3);
            int sdx = (kd < 64) ? kd : kd - 128;
            float bb = (float)sdx * 26.0416666f;
            float kq = oc * oc - bb * bb;
            float kzr = (fok && kq > 0.f) ? sqrtf(kq) : 0.f;
            float tj = 1.5e-4f * kzr;
            tj -= floorf(tj);
            kzJ[(size_t)kd * N_FP + f] = make_float4(kzr, cos_rev(tj), sin_rev(tj), 0.f);
        }
    }
    __syncthreads();
    #pragma unroll
    for (int st = 0; st < 3; ++st){
        int h = 1 << (2 * st);
        #pragma unroll
        for (int it = 0; it < 4; ++it){
            int task = tid + (it << 8);
            int ff = task & 31;
            int q  = task >> 5;
            int k = q & (h - 1);
            int g = q >> (2 * st);
            int base = (g << (2 * st + 2)) + k;
            float2 x0 = tile[base][ff];
            float2 x1 = tile[base + h][ff];
            float2 x2 = tile[base + 2 * h][ff];
            float2 x3 = tile[base + 3 * h][ff];
            float a1 = -(float)M_PI * (float)k / (float)h;
            float s1, c1; __sincosf(a1, &s1, &c1);
            float a2 = 0.5f * a1;
            float s2, c2; __sincosf(a2, &s2, &c2);
            float2 t1 = make_float2(x1.x * c1 - x1.y * s1, x1.x * s1 + x1.y * c1);
            float2 t3 = make_float2(x3.x * c1 - x3.y * s1, x3.x * s1 + x3.y * c1);
            float2 y0 = make_float2(x0.x + t1.x, x0.y + t1.y);
            float2 y1 = make_float2(x0.x - t1.x, x0.y - t1.y);
            float2 y2 = make_float2(x2.x + t3.x, x2.y + t3.y);
            float2 y3 = make_float2(x2.x - t3.x, x2.y - t3.y);
            float2 u = make_float2(y2.x * c2 - y2.y * s2, y2.x * s2 + y2.y * c2);
            float2 v = make_float2(y3.x * c2 - y3.y * s2, y3.x * s2 + y3.y * c2);
            float2 w = make_float2(v.y, -v.x);
            tile[base][ff]         = make_float2(y0.x + u.x, y0.y + u.y);
            tile[base + 2 * h][ff] = make_float2(y0.x - u.x, y0.y - u.y);
            tile[base + h][ff]     = make_float2(y1.x + w.x, y1.y + w.y);
            tile[base + 3 * h][ff] = make_float2(y1.x - w.x, y1.y - w.y);
        }
        __syncthreads();
    }
    #pragma unroll
    for (int it = 0; it < 8; ++it){
        int task = tid + (it << 8);
        int ff = task & 31, j = task >> 5;
        int i1 = j, i2 = j + 64;
        float ang = -(float)M_PI * (float)j * (1.0f / 64.0f);
        float sn, cs; __sincosf(ang, &sn, &cs);
        float2 u = tile[i1][ff], v = tile[i2][ff];
        float2 t = make_float2(v.x * cs - v.y * sn, v.x * sn + v.y * cs);
        tile[i1][ff] = make_float2(u.x + t.x, u.y + t.y);
        tile[i2][ff] = make_float2(u.x - t.x, u.y - t.y);
    }
    __syncthreads();
    float fw = (f == 0 || f == 1024) ? 1.f : 2.f;
    #pragma unroll
    for (int i = 0; i < 16; ++i){
        int kd = kd0 + (i << 3);
        int sdx = (kd < 64) ? kd : kd - 128;
        float bb = (float)sdx * 26.0416666f;
        float m = (fok && (oc * oc - bb * bb > 0.f)) ? fw : 0.f;
        float2 v = tile[kd][fl];
        stAr[kd][fl] = cvt_bf16(v.x * m);
        stAi[kd][fl] = cvt_bf16(v.y * m);
    }
    __syncthreads();
    int kds = tid >> 1, hf = tid & 1;
    size_t rowoff = ((size_t)kds * 16 + bc) * N_FP + f0 + hf * 16;
    uint4 r0 = *(const uint4*)&stAr[kds][hf * 16];
    uint4 r1 = *(const uint4*)&stAr[kds][hf * 16 + 8];
    uint4 i0 = *(const uint4*)&stAi[kds][hf * 16];
    uint4 i1v = *(const uint4*)&stAi[kds][hf * 16 + 8];
    ((uint4*)(Arp + rowoff))[0] = r0;
    ((uint4*)(Arp + rowoff))[1] = r1;
    ((uint4*)(Aip + rowoff))[0] = i0;
    ((uint4*)(Aip + rowoff))[1] = i1v;
}

// ---------------- band via MFMA, f-split in 2 chunks: block=(kd, yh, fc) ----------------
__global__ __launch_bounds__(512) void k_band(const ushort* __restrict__ Ar,
                                              const ushort* __restrict__ Ai,
                                              const float4* __restrict__ kzJ,
                                              float2* __restrict__ band_p){
    int blk = blockIdx.x;
    int fc = blk & 1;
    int yh = (blk >> 1) & 1;
    int kd = blk >> 2;
    int nt = fc ? 17 : 16;
    int tid  = threadIdx.x;
    int wid  = tid >> 6;
    int lane = tid & 63;
    int fp = tid & 15;
    int yq = tid >> 4;
    float ymg = 1.0e-3f + 1.5e-4f * (float)(yh * 128 + yq * 4);

    __shared__ ushort Bls[2][2][128][40];

    int arow = lane & 15;
    int koff = (lane >> 4) * 8;
    int ylocal = wid * 16 + arow;
    const ushort* Arp = Ar + ((size_t)kd * 16 + arow) * N_FP + koff + fc * 512;
    const ushort* Aip = Ai + ((size_t)kd * 16 + arow) * N_FP + koff + fc * 512;
    const float4* kjb = kzJ + (size_t)kd * N_FP + fc * 512;

    auto GENC = [&](float4 k0, float4 k1, int buf){
        float t0 = ymg * k0.x; t0 -= floorf(t0);
        float t1 = ymg * k1.x; t1 -= floorf(t1);
        float cA = cos_rev(t0), sA = sin_rev(t0);
        float cB = cos_rev(t1), sB = sin_rev(t1);
        #pragma unroll
        for (int j = 0; j < 4; ++j){
            int y = yq * 4 + j;
            uint br, bi;
            asm("v_cvt_pk_bf16_f32 %0, %1, %2" : "=v"(br) : "v"(cA), "v"(cB));
            asm("v_cvt_pk_bf16_f32 %0, %1, %2" : "=v"(bi) : "v"(sA), "v"(sB));
            *(uint*)&Bls[buf][0][y][fp * 2] = br;
            *(uint*)&Bls[buf][1][y][fp * 2] = bi;
            if (j < 3){
                float nA = fmaf(cA, k0.y, -(sA * k0.z));
                float mA = fmaf(sA, k0.y,  (cA * k0.z));
                cA = nA; sA = mA;
                float nB = fmaf(cB, k1.y, -(sB * k1.z));
                float mB = fmaf(sB, k1.y,  (cB * k1.z));
                cB = nB; sB = mB;
            }
        }
    };

    f32x4 P1 = {0.f,0.f,0.f,0.f}, P2 = P1, P3 = P1, P4 = P1;

    bf16x8 car = *(const bf16x8*)(Arp);
    bf16x8 cai = *(const bf16x8*)(Aip);
    GENC(kjb[fp * 2], kjb[fp * 2 + 1], 0);
    __syncthreads();

    for (int t = 0; t < nt; ++t){
        bf16x8 nar, nai;
        float4 k0, k1;
        if (t < nt - 1){
            nar = *(const bf16x8*)(Arp + (t + 1) * 32);
            nai = *(const bf16x8*)(Aip + (t + 1) * 32);
            k0 = kjb[(t + 1) * 32 + fp * 2];
            k1 = kjb[(t + 1) * 32 + fp * 2 + 1];
        }
        int buf = t & 1;
        bf16x8 br = *(const bf16x8*)&Bls[buf][0][ylocal][koff];
        bf16x8 bi = *(const bf16x8*)&Bls[buf][1][ylocal][koff];
        P1 = __builtin_amdgcn_mfma_f32_16x16x32_bf16(car, br, P1, 0, 0, 0);
        P2 = __builtin_amdgcn_mfma_f32_16x16x32_bf16(cai, bi, P2, 0, 0, 0);
        P3 = __builtin_amdgcn_mfma_f32_16x16x32_bf16(car, bi, P3, 0, 0, 0);
        P4 = __builtin_amdgcn_mfma_f32_16x16x32_bf16(cai, br, P4, 0, 0, 0);
        if (t < nt - 1){
            GENC(k0, k1, buf ^ 1);
        }
        __syncthreads();
        if (t < nt - 1){ car = nar; cai = nai; }
    }

    int y = yh * 128 + wid * 16 + (lane & 15);
    #pragma unroll
    for (int r = 0; r < 4; ++r){
        int bc = (lane >> 4) * 4 + r;
        band_p[(((size_t)fc * 128 + kd) * 16 + bc) * 256 + y] = make_float2(P1[r] - P2[r], P3[r] + P4[r]);
    }
}

// ---------------- final: sum 2 partials, 128-pt inverse FFT over kd (stage-paired), |.| ----------------
__global__ __launch_bounds__(256) void k_final(const float2* __restrict__ band_p,
                                               const float* __restrict__ apod,
                                               float* __restrict__ out){
    int blk = blockIdx.x;            // bc*32 + yt
    int bc = blk >> 5, yt = blk & 31;
    __shared__ float2 tile[128][9];
    __shared__ float asum;
    int tid = threadIdx.x;
    if (tid < 64){
        float a = apod[tid] + apod[tid + 64];
        #pragma unroll
        for (int m = 1; m < 64; m <<= 1) a += __shfl_xor(a, m, 64);
        if (tid == 0) asum = a;
    }
    #pragma unroll
    for (int k2 = 0; k2 < 4; ++k2){
        int idx = tid + k2 * 256;
        int kd = idx >> 3, yi = idx & 7;
        size_t o0 = (((size_t)0 * 128 + kd) * 16 + bc) * 256 + yt * 8 + yi;
        size_t o1 = (((size_t)1 * 128 + kd) * 16 + bc) * 256 + yt * 8 + yi;
        float2 a = band_p[o0], b = band_p[o1];
        int rkd = __brev((unsigned)kd) >> 25;   // 7-bit reverse
        tile[rkd][yi] = make_float2(a.x + b.x, a.y + b.y);
    }
    __syncthreads();
    #pragma unroll
    for (int st = 0; st < 3; ++st){
        int h = 1 << (2 * st);            // 1,4,16
        int q  = tid >> 3;                // 0..31 quad
        int yi = tid & 7;
        int k = q & (h - 1);
        int g = q >> (2 * st);
        int base = (g << (2 * st + 2)) + k;
        float2 x0 = tile[base][yi];
        float2 x1 = tile[base + h][yi];
        float2 x2 = tile[base + 2 * h][yi];
        float2 x3 = tile[base + 3 * h][yi];
        float a1 = (float)M_PI * (float)k / (float)h;      // +ve: inverse
        float s1, c1; __sincosf(a1, &s1, &c1);
        float a2 = 0.5f * a1;
        float s2, c2; __sincosf(a2, &s2, &c2);
        float2 t1 = make_float2(x1.x * c1 - x1.y * s1, x1.x * s1 + x1.y * c1);
        float2 t3 = make_float2(x3.x * c1 - x3.y * s1, x3.x * s1 + x3.y * c1);
        float2 y0 = make_float2(x0.x + t1.x, x0.y + t1.y);
        float2 y1 = make_float2(x0.x - t1.x, x0.y - t1.y);
        float2 y2 = make_float2(x2.x + t3.x, x2.y + t3.y);
        float2 y3 = make_float2(x2.x - t3.x, x2.y - t3.y);
        float2 u = make_float2(y2.x * c2 - y2.y * s2, y2.x * s2 + y2.y * c2);
        float2 v = make_float2(y3.x * c2 - y3.y * s2, y3.x * s2 + y3.y * c2);
        float2 w = make_float2(-v.y, v.x);                 // +i * v (inverse)
        tile[base][yi]         = make_float2(y0.x + u.x, y0.y + u.y);
        tile[base + 2 * h][yi] = make_float2(y0.x - u.x, y0.y - u.y);
        tile[base + h][yi]     = make_float2(y1.x + w.x, y1.y + w.y);
        tile[base + 3 * h][yi] = make_float2(y1.x - w.x, y1.y - w.y);
        __syncthreads();
    }
    #pragma unroll
    for (int it = 0; it < 2; ++it){
        int task = tid + (it << 8);       // 0..511
        int yi = task & 7, j = task >> 3; // j = 0..63
        float ang = (float)M_PI * (float)j * (1.0f / 64.0f);
        float sn, cs; __sincosf(ang, &sn, &cs);
        float2 u = tile[j][yi], v = tile[j + 64][yi];
        float2 t = make_float2(v.x * cs - v.y * sn, v.x * sn + v.y * cs);
        tile[j][yi]      = make_float2(u.x + t.x, u.y + t.y);
        tile[j + 64][yi] = make_float2(u.x - t.x, u.y - t.y);
    }
    __syncthreads();
    float invnorm = 1.f / (fmaxf(asum, 1.1920929e-7f) * 2048.f);
    #pragma unroll
    for (int k2 = 0; k2 < 4; ++k2){
        int idx = tid + k2 * 256;
        int x = idx & 127, yi = idx >> 7;
        float2 v = tile[x][yi];
        int y = yt * 8 + yi;
        out[((size_t)bc * 256 + y) * 128 + x] = sqrtf(v.x * v.x + v.y * v.y) * invnorm;
    }
}

extern "C" void kernel_launch(void* const* d_in, const int* in_sizes, int n_in,
                              void* d_out, int out_size, void* d_ws, size_t ws_size,
                              hipStream_t stream){
    const float* sino = (const float*)d_in[0];
    const float* apod = (const float*)d_in[1];
    float* out = (float*)d_out;
    float* W = (float*)d_ws;
    // workspace layout (float offsets):
    //   [0..2047]      psum (per row)
    //   [2048..4095]   psq
    //   4096           spec_u : 16*128*1025 uint (bf16-packed complex) = 2,099,200
    //   6,195,...      Ar/Ai  : 16*128*1056 ushort each (1,081,344 floats each)
    //   then           kzJ    : 128*1056 float4 (540,672 floats)
    //   then           band_p : 2*128*16*256 float2 (4,194,304 floats)
    float* psum = W;
    float* psq  = W + 2048;
    uint*   spec_u = (uint*)(W + 4096);
    ushort* Arp    = (ushort*)(W + 4096 + 2099200);
    ushort* Aip    = Arp + (size_t)16 * 128 * N_FP;
    float4* kzJ    = (float4*)(W + 4096 + 2099200 + 2162688);
    float2* band_p = (float2*)(W + 4096 + 2099200 + 2162688 + 540672);

    k_tfft  <<<NBCC * N_DETC, 256, 0, stream>>>(sino, psum, psq, spec_u);
    k_dft   <<<33 * 16, 256, 0, stream>>>(spec_u, psum, psq, apod, Arp, Aip, kzJ);
    k_band  <<<512, 512, 0, stream>>>(Arp, Aip, kzJ, band_p);
    k_final <<<NBCC * 32, 256, 0, stream>>>(band_p, apod, out);
}

// Round 14
// 61.153 us; speedup vs baseline: 2.2372x; 1.0706x over previous
//
#include <hip/hip_runtime.h>
#include <math.h>

#define N_DETC 128
#define N_TC   2048
#define N_FC   1025
#define N_FP   1056    // padded f (33 K-steps of 32)
#define NXC    128
#define NYC    256
#define NBCC   16      // B*C = 8*2

#define MPAD(i) ((i) + ((i) >> 5))   // LDS anti-conflict padding map

typedef short bf16x8 __attribute__((ext_vector_type(8)));
typedef float f32x4  __attribute__((ext_vector_type(4)));

__device__ __forceinline__ float2 cmulf(float2 a, float2 b){
    return make_float2(a.x*b.x - a.y*b.y, a.x*b.y + a.y*b.x);
}

#if __has_builtin(__builtin_amdgcn_sinf) && __has_builtin(__builtin_amdgcn_cosf)
__device__ __forceinline__ float sin_rev(float tf){ return __builtin_amdgcn_sinf(tf); }   // sin(2*pi*tf)
__device__ __forceinline__ float cos_rev(float tf){ return __builtin_amdgcn_cosf(tf); }
#else
__device__ __forceinline__ float sin_rev(float tf){ return __sinf(6.28318530718f * tf); }
__device__ __forceinline__ float cos_rev(float tf){ return __cosf(6.28318530718f * tf); }
#endif

__device__ __forceinline__ ushort cvt_bf16(float x){
    uint u = __float_as_uint(x);
    return (ushort)((u + 0x7FFFu + ((u >> 16) & 1u)) >> 16);   // RNE
}

// ---------------- temporal rFFT on RAW sino + per-row stats; bf16-packed spec ----------------
__global__ __launch_bounds__(256) void k_tfft(const float* __restrict__ sino,
                                              float* __restrict__ psum,
                                              float* __restrict__ psq,
                                              uint* __restrict__ spec_u){
    int row = blockIdx.x;            // bc*128 + d
    __shared__ float2 z[1055];       // padded via MPAD
    __shared__ float ls[4], lq[4];
    int tid = threadIdx.x;
    const float2* p = (const float2*)(sino + (size_t)row * N_TC);
    float s = 0.f, q = 0.f;
    for (int n = tid; n < 1024; n += 256){
        float2 v = p[n];             // x[2n], x[2n+1]
        s += v.x + v.y;
        q += v.x * v.x + v.y * v.y;
        int r = __brev((unsigned)n) >> 22;   // 10-bit reverse
        z[MPAD(r)] = v;
    }
    #pragma unroll
    for (int m = 1; m < 64; m <<= 1){
        s += __shfl_xor(s, m, 64);
        q += __shfl_xor(q, m, 64);
    }
    int w = tid >> 6, lane = tid & 63;
    if (lane == 0){ ls[w] = s; lq[w] = q; }
    __syncthreads();
    if (tid == 0){
        psum[row] = ls[0] + ls[1] + ls[2] + ls[3];
        psq[row]  = lq[0] + lq[1] + lq[2] + lq[3];
    }
    #pragma unroll
    for (int st = 0; st < 5; ++st){
        int h = 1 << (2 * st);           // 1,4,16,64,256
        int qd = tid;
        int k = qd & (h - 1);
        int g = qd >> (2 * st);
        int base = (g << (2 * st + 2)) + k;
        float2 x0 = z[MPAD(base)];
        float2 x1 = z[MPAD(base + h)];
        float2 x2 = z[MPAD(base + 2 * h)];
        float2 x3 = z[MPAD(base + 3 * h)];
        float a1 = -(float)M_PI * (float)k / (float)h;
        float s1, c1; __sincosf(a1, &s1, &c1);
        float a2 = 0.5f * a1;
        float s2, c2; __sincosf(a2, &s2, &c2);
        float2 t1 = make_float2(x1.x * c1 - x1.y * s1, x1.x * s1 + x1.y * c1);
        float2 t3 = make_float2(x3.x * c1 - x3.y * s1, x3.x * s1 + x3.y * c1);
        float2 y0 = make_float2(x0.x + t1.x, x0.y + t1.y);
        float2 y1 = make_float2(x0.x - t1.x, x0.y - t1.y);
        float2 y2 = make_float2(x2.x + t3.x, x2.y + t3.y);
        float2 y3 = make_float2(x2.x - t3.x, x2.y - t3.y);
        float2 u = make_float2(y2.x * c2 - y2.y * s2, y2.x * s2 + y2.y * c2);
        float2 v = make_float2(y3.x * c2 - y3.y * s2, y3.x * s2 + y3.y * c2);
        float2 wv = make_float2(v.y, -v.x);          // -i * v
        z[MPAD(base)]         = make_float2(y0.x + u.x, y0.y + u.y);
        z[MPAD(base + 2 * h)] = make_float2(y0.x - u.x, y0.y - u.y);
        z[MPAD(base + h)]     = make_float2(y1.x + wv.x, y1.y + wv.y);
        z[MPAD(base + 3 * h)] = make_float2(y1.x - wv.x, y1.y - wv.y);
        __syncthreads();
    }
    // untangle + bf16 pack: X[k] = E + W*O, W = e^{-i*pi*k/1024}
    uint* o = spec_u + (size_t)row * N_FC;
    for (int k = tid; k < 1025; k += 256){
        float2 A  = z[MPAD(k & 1023)];
        float2 Bv = z[MPAD((1024 - k) & 1023)];
        float Br = Bv.x, Bi = -Bv.y;         // conj
        float Er = 0.5f * (A.x + Br), Ei = 0.5f * (A.y + Bi);
        float Dr = 0.5f * (A.x - Br), Di = 0.5f * (A.y - Bi);
        float Or = Di, Oi = -Dr;             // O = -i*D
        float ang = -(float)M_PI * (float)k * (1.0f / 1024.0f);
        float sn, cs; __sincosf(ang, &sn, &cs);
        float Xr = Er + cs * Or - sn * Oi;
        float Xi = Ei + cs * Oi + sn * Or;
        uint pk;
        asm("v_cvt_pk_bf16_f32 %0, %1, %2" : "=v"(pk) : "v"(Xr), "v"(Xi));
        o[k] = pk;
    }
}

// ---------------- detector FFT: stats-finalize + standardize + DC fix + kd-FFT -> bf16 A ----------------
// direct coalesced ushort stores (no staging LDS): 34 KB LDS -> 4 blocks/CU
__global__ __launch_bounds__(256) void k_dft(const uint* __restrict__ spec_u,
                                             const float* __restrict__ psum,
                                             const float* __restrict__ psq,
                                             const float* __restrict__ apod,
                                             ushort* __restrict__ Arp,
                                             ushort* __restrict__ Aip,
                                             float4* __restrict__ kzJ){
    int bid = blockIdx.x;
    int ft = bid >> 4, bc = bid & 15;
    int f0 = ft << 5;
    int tid = threadIdx.x;
    __shared__ float2 tile[128][33];
    __shared__ float sm[2];

    if (tid < 64){
        float s = psum[bc * 128 + tid] + psum[bc * 128 + 64 + tid];
        float q = psq[bc * 128 + tid] + psq[bc * 128 + 64 + tid];
        #pragma unroll
        for (int m = 1; m < 64; m <<= 1){
            s += __shfl_xor(s, m, 64);
            q += __shfl_xor(q, m, 64);
        }
        if (tid == 0){
            const float inv_n = 1.f / (float)(N_DETC * N_TC);
            float mean = s * inv_n;
            float var  = q * inv_n - mean * mean;
            sm[0] = mean;
            sm[1] = rsqrtf(fmaxf(var, 0.f) + 1.1920929e-7f);
        }
    }
    __syncthreads();
    float mean = sm[0], invstd = sm[1];

    int fl  = tid & 31;
    int kd0 = tid >> 5;
    int f = f0 + fl;
    bool fok = (f <= 1024);
    float fr = (float)f * 19531.25f;
    float oc = fr * (1.0f / 1540.0f);

    #pragma unroll
    for (int i = 0; i < 16; ++i){
        int kd = kd0 + (i << 3);
        int rkd = __brev((unsigned)kd) >> 25;
        uint u = fok ? spec_u[((size_t)(bc * 128 + kd)) * N_FC + f] : 0u;
        float vr = __uint_as_float(u << 16);
        float vi = __uint_as_float(u & 0xFFFF0000u);
        if (f == 0) vr -= mean * 2048.f;
        float sc = apod[kd] * invstd;
        tile[rkd][fl] = make_float2(vr * sc, vi * sc);
    }
    if (bc == 0){
        #pragma unroll
        for (int i = 0; i < 16; ++i){
            int kd = kd0 + (i << 3);
            int sdx = (kd < 64) ? kd : kd - 128;
            float bb = (float)sdx * 26.0416666f;
            float kq = oc * oc - bb * bb;
            float kzr = (fok && kq > 0.f) ? sqrtf(kq) : 0.f;
            float tj = 1.5e-4f * kzr;
            tj -= floorf(tj);
            kzJ[(size_t)kd * N_FP + f] = make_float4(kzr, cos_rev(tj), sin_rev(tj), 0.f);
        }
    }
    __syncthreads();
    #pragma unroll
    for (int st = 0; st < 3; ++st){
        int h = 1 << (2 * st);
        #pragma unroll
        for (int it = 0; it < 4; ++it){
            int task = tid + (it << 8);
            int ff = task & 31;
            int q  = task >> 5;
            int k = q & (h - 1);
            int g = q >> (2 * st);
            int base = (g << (2 * st + 2)) + k;
            float2 x0 = tile[base][ff];
            float2 x1 = tile[base + h][ff];
            float2 x2 = tile[base + 2 * h][ff];
            float2 x3 = tile[base + 3 * h][ff];
            float a1 = -(float)M_PI * (float)k / (float)h;
            float s1, c1; __sincosf(a1, &s1, &c1);
            float a2 = 0.5f * a1;
            float s2, c2; __sincosf(a2, &s2, &c2);
            float2 t1 = make_float2(x1.x * c1 - x1.y * s1, x1.x * s1 + x1.y * c1);
            float2 t3 = make_float2(x3.x * c1 - x3.y * s1, x3.x * s1 + x3.y * c1);
            float2 y0 = make_float2(x0.x + t1.x, x0.y + t1.y);
            float2 y1 = make_float2(x0.x - t1.x, x0.y - t1.y);
            float2 y2 = make_float2(x2.x + t3.x, x2.y + t3.y);
            float2 y3 = make_float2(x2.x - t3.x, x2.y - t3.y);
            float2 u = make_float2(y2.x * c2 - y2.y * s2, y2.x * s2 + y2.y * c2);
            float2 v = make_float2(y3.x * c2 - y3.y * s2, y3.x * s2 + y3.y * c2);
            float2 w = make_float2(v.y, -v.x);
            tile[base][ff]         = make_float2(y0.x + u.x, y0.y + u.y);
            tile[base + 2 * h][ff] = make_float2(y0.x - u.x, y0.y - u.y);
            tile[base + h][ff]     = make_float2(y1.x + w.x, y1.y + w.y);
            tile[base + 3 * h][ff] = make_float2(y1.x - w.x, y1.y - w.y);
        }
        __syncthreads();
    }
    #pragma unroll
    for (int it = 0; it < 8; ++it){
        int task = tid + (it << 8);
        int ff = task & 31, j = task >> 5;
        int i1 = j, i2 = j + 64;
        float ang = -(float)M_PI * (float)j * (1.0f / 64.0f);
        float sn, cs; __sincosf(ang, &sn, &cs);
        float2 u = tile[i1][ff], v = tile[i2][ff];
        float2 t = make_float2(v.x * cs - v.y * sn, v.x * sn + v.y * cs);
        tile[i1][ff] = make_float2(u.x + t.x, u.y + t.y);
        tile[i2][ff] = make_float2(u.x - t.x, u.y - t.y);
    }
    __syncthreads();
    float fw = (f == 0 || f == 1024) ? 1.f : 2.f;
    // direct stores: wave = 2 kd rows x 32 f -> 2x64B ushort segments per plane
    #pragma unroll
    for (int i = 0; i < 16; ++i){
        int kd = kd0 + (i << 3);
        int sdx = (kd < 64) ? kd : kd - 128;
        float bb = (float)sdx * 26.0416666f;
        float m = (fok && (oc * oc - bb * bb > 0.f)) ? fw : 0.f;
        float2 v = tile[kd][fl];
        size_t o = ((size_t)kd * 16 + bc) * N_FP + f;
        Arp[o] = cvt_bf16(v.x * m);
        Aip[o] = cvt_bf16(v.y * m);
    }
}

// ---------------- band via MFMA, f-split in 4 chunks: block=(kd, yh, fc); bf16 partials ----------------
__global__ __launch_bounds__(512) void k_band(const ushort* __restrict__ Ar,
                                              const ushort* __restrict__ Ai,
                                              const float4* __restrict__ kzJ,
                                              uint* __restrict__ band_u){
    int blk = blockIdx.x;
    int fc = blk & 3;
    int yh = (blk >> 2) & 1;
    int kd = blk >> 3;
    int nt = (fc == 3) ? 9 : 8;
    int tid  = threadIdx.x;
    int wid  = tid >> 6;
    int lane = tid & 63;
    int fp = tid & 15;
    int yq = tid >> 4;
    float ymg = 1.0e-3f + 1.5e-4f * (float)(yh * 128 + yq * 4);

    __shared__ ushort Bls[2][2][128][40];

    int arow = lane & 15;
    int koff = (lane >> 4) * 8;
    int ylocal = wid * 16 + arow;
    const ushort* Arp = Ar + ((size_t)kd * 16 + arow) * N_FP + koff + fc * 256;
    const ushort* Aip = Ai + ((size_t)kd * 16 + arow) * N_FP + koff + fc * 256;
    const float4* kjb = kzJ + (size_t)kd * N_FP + fc * 256;

    auto GENC = [&](float4 k0, float4 k1, int buf){
        float t0 = ymg * k0.x; t0 -= floorf(t0);
        float t1 = ymg * k1.x; t1 -= floorf(t1);
        float cA = cos_rev(t0), sA = sin_rev(t0);
        float cB = cos_rev(t1), sB = sin_rev(t1);
        #pragma unroll
        for (int j = 0; j < 4; ++j){
            int y = yq * 4 + j;
            uint br, bi;
            asm("v_cvt_pk_bf16_f32 %0, %1, %2" : "=v"(br) : "v"(cA), "v"(cB));
            asm("v_cvt_pk_bf16_f32 %0, %1, %2" : "=v"(bi) : "v"(sA), "v"(sB));
            *(uint*)&Bls[buf][0][y][fp * 2] = br;
            *(uint*)&Bls[buf][1][y][fp * 2] = bi;
            if (j < 3){
                float nA = fmaf(cA, k0.y, -(sA * k0.z));
                float mA = fmaf(sA, k0.y,  (cA * k0.z));
                cA = nA; sA = mA;
                float nB = fmaf(cB, k1.y, -(sB * k1.z));
                float mB = fmaf(sB, k1.y,  (cB * k1.z));
                cB = nB; sB = mB;
            }
        }
    };

    f32x4 P1 = {0.f,0.f,0.f,0.f}, P2 = P1, P3 = P1, P4 = P1;

    bf16x8 car = *(const bf16x8*)(Arp);
    bf16x8 cai = *(const bf16x8*)(Aip);
    GENC(kjb[fp * 2], kjb[fp * 2 + 1], 0);
    __syncthreads();

    for (int t = 0; t < nt; ++t){
        bf16x8 nar, nai;
        float4 k0, k1;
        if (t < nt - 1){
            nar = *(const bf16x8*)(Arp + (t + 1) * 32);
            nai = *(const bf16x8*)(Aip + (t + 1) * 32);
            k0 = kjb[(t + 1) * 32 + fp * 2];
            k1 = kjb[(t + 1) * 32 + fp * 2 + 1];
        }
        int buf = t & 1;
        bf16x8 br = *(const bf16x8*)&Bls[buf][0][ylocal][koff];
        bf16x8 bi = *(const bf16x8*)&Bls[buf][1][ylocal][koff];
        P1 = __builtin_amdgcn_mfma_f32_16x16x32_bf16(car, br, P1, 0, 0, 0);
        P2 = __builtin_amdgcn_mfma_f32_16x16x32_bf16(cai, bi, P2, 0, 0, 0);
        P3 = __builtin_amdgcn_mfma_f32_16x16x32_bf16(car, bi, P3, 0, 0, 0);
        P4 = __builtin_amdgcn_mfma_f32_16x16x32_bf16(cai, br, P4, 0, 0, 0);
        if (t < nt - 1){
            GENC(k0, k1, buf ^ 1);
        }
        __syncthreads();
        if (t < nt - 1){ car = nar; cai = nai; }
    }

    int y = yh * 128 + wid * 16 + (lane & 15);
    #pragma unroll
    for (int r = 0; r < 4; ++r){
        int bc = (lane >> 4) * 4 + r;
        float cr = P1[r] - P2[r];
        float ci = P3[r] + P4[r];
        uint pk;
        asm("v_cvt_pk_bf16_f32 %0, %1, %2" : "=v"(pk) : "v"(cr), "v"(ci));
        band_u[(((size_t)fc * 128 + kd) * 16 + bc) * 256 + y] = pk;
    }
}

// ---------------- final: sum 4 bf16 partials, 128-pt inverse FFT over kd (stage-paired), |.| ----------------
__global__ __launch_bounds__(256) void k_final(const uint* __restrict__ band_u,
                                               const float* __restrict__ apod,
                                               float* __restrict__ out){
    int blk = blockIdx.x;            // bc*32 + yt
    int bc = blk >> 5, yt = blk & 31;
    __shared__ float2 tile[128][9];
    __shared__ float asum;
    int tid = threadIdx.x;
    if (tid < 64){
        float a = apod[tid] + apod[tid + 64];
        #pragma unroll
        for (int m = 1; m < 64; m <<= 1) a += __shfl_xor(a, m, 64);
        if (tid == 0) asum = a;
    }
    #pragma unroll
    for (int k2 = 0; k2 < 4; ++k2){
        int idx = tid + k2 * 256;
        int kd = idx >> 3, yi = idx & 7;
        float sr = 0.f, si = 0.f;
        #pragma unroll
        for (int p = 0; p < 4; ++p){
            uint u = band_u[(((size_t)p * 128 + kd) * 16 + bc) * 256 + yt * 8 + yi];
            sr += __uint_as_float(u << 16);
            si += __uint_as_float(u & 0xFFFF0000u);
        }
        int rkd = __brev((unsigned)kd) >> 25;   // 7-bit reverse
        tile[rkd][yi] = make_float2(sr, si);
    }
    __syncthreads();
    #pragma unroll
    for (int st = 0; st < 3; ++st){
        int h = 1 << (2 * st);            // 1,4,16
        int q  = tid >> 3;                // 0..31 quad
        int yi = tid & 7;
        int k = q & (h - 1);
        int g = q >> (2 * st);
        int base = (g << (2 * st + 2)) + k;
        float2 x0 = tile[base][yi];
        float2 x1 = tile[base + h][yi];
        float2 x2 = tile[base + 2 * h][yi];
        float2 x3 = tile[base + 3 * h][yi];
        float a1 = (float)M_PI * (float)k / (float)h;      // +ve: inverse
        float s1, c1; __sincosf(a1, &s1, &c1);
        float a2 = 0.5f * a1;
        float s2, c2; __sincosf(a2, &s2, &c2);
        float2 t1 = make_float2(x1.x * c1 - x1.y * s1, x1.x * s1 + x1.y * c1);
        float2 t3 = make_float2(x3.x * c1 - x3.y * s1, x3.x * s1 + x3.y * c1);
        float2 y0 = make_float2(x0.x + t1.x, x0.y + t1.y);
        float2 y1 = make_float2(x0.x - t1.x, x0.y - t1.y);
        float2 y2 = make_float2(x2.x + t3.x, x2.y + t3.y);
        float2 y3 = make_float2(x2.x - t3.x, x2.y - t3.y);
        float2 u = make_float2(y2.x * c2 - y2.y * s2, y2.x * s2 + y2.y * c2);
        float2 v = make_float2(y3.x * c2 - y3.y * s2, y3.x * s2 + y3.y * c2);
        float2 w = make_float2(-v.y, v.x);                 // +i * v (inverse)
        tile[base][yi]         = make_float2(y0.x + u.x, y0.y + u.y);
        tile[base + 2 * h][yi] = make_float2(y0.x - u.x, y0.y - u.y);
        tile[base + h][yi]     = make_float2(y1.x + w.x, y1.y + w.y);
        tile[base + 3 * h][yi] = make_float2(y1.x - w.x, y1.y - w.y);
        __syncthreads();
    }
    #pragma unroll
    for (int it = 0; it < 2; ++it){
        int task = tid + (it << 8);       // 0..511
        int yi = task & 7, j = task >> 3; // j = 0..63
        float ang = (float)M_PI * (float)j * (1.0f / 64.0f);
        float sn, cs; __sincosf(ang, &sn, &cs);
        float2 u = tile[j][yi], v = tile[j + 64][yi];
        float2 t = make_float2(v.x * cs - v.y * sn, v.x * sn + v.y * cs);
        tile[j][yi]      = make_float2(u.x + t.x, u.y + t.y);
        tile[j + 64][yi] = make_float2(u.x - t.x, u.y - t.y);
    }
    __syncthreads();
    float invnorm = 1.f / (fmaxf(asum, 1.1920929e-7f) * 2048.f);
    #pragma unroll
    for (int k2 = 0; k2 < 4; ++k2){
        int idx = tid + k2 * 256;
        int x = idx & 127, yi = idx >> 7;
        float2 v = tile[x][yi];
        int y = yt * 8 + yi;
        out[((size_t)bc * 256 + y) * 128 + x] = sqrtf(v.x * v.x + v.y * v.y) * invnorm;
    }
}

extern "C" void kernel_launch(void* const* d_in, const int* in_sizes, int n_in,
                              void* d_out, int out_size, void* d_ws, size_t ws_size,
                              hipStream_t stream){
    const float* sino = (const float*)d_in[0];
    const float* apod = (const float*)d_in[1];
    float* out = (float*)d_out;
    float* W = (float*)d_ws;
    // workspace layout (float offsets):
    //   [0..2047]      psum (per row)
    //   [2048..4095]   psq
    //   4096           spec_u : 16*128*1025 uint = 2,099,200
    //   then           Ar/Ai  : 16*128*1056 ushort each (1,081,344 floats each)
    //   then           kzJ    : 128*1056 float4 (540,672 floats)
    //   then           band_u : 4*128*16*256 uint (2,097,152)
    float* psum = W;
    float* psq  = W + 2048;
    uint*   spec_u = (uint*)(W + 4096);
    ushort* Arp    = (ushort*)(W + 4096 + 2099200);
    ushort* Aip    = Arp + (size_t)16 * 128 * N_FP;
    float4* kzJ    = (float4*)(W + 4096 + 2099200 + 2162688);
    uint*   band_u = (uint*)(W + 4096 + 2099200 + 2162688 + 540672);

    k_tfft  <<<NBCC * N_DETC, 256, 0, stream>>>(sino, psum, psq, spec_u);
    k_dft   <<<33 * 16, 256, 0, stream>>>(spec_u, psum, psq, apod, Arp, Aip, kzJ);
    k_band  <<<1024, 512, 0, stream>>>(Arp, Aip, kzJ, band_u);
    k_final <<<NBCC * 32, 256, 0, stream>>>(band_u, apod, out);
}

// Round 15
// 60.530 us; speedup vs baseline: 2.2603x; 1.0103x over previous
//
#include <hip/hip_runtime.h>
#include <math.h>

#define N_DETC 128
#define N_TC   2048
#define N_FC   1025
#define N_FP   1056    // padded f (33 K-steps of 32)
#define NXC    128
#define NYC    256
#define NBCC   16      // B*C = 8*2

#define MPAD(i) ((i) + ((i) >> 5))   // LDS anti-conflict padding map

typedef short bf16x8 __attribute__((ext_vector_type(8)));
typedef float f32x4  __attribute__((ext_vector_type(4)));

__device__ __forceinline__ float2 cmulf(float2 a, float2 b){
    return make_float2(a.x*b.x - a.y*b.y, a.x*b.y + a.y*b.x);
}

#if __has_builtin(__builtin_amdgcn_sinf) && __has_builtin(__builtin_amdgcn_cosf)
__device__ __forceinline__ float sin_rev(float tf){ return __builtin_amdgcn_sinf(tf); }   // sin(2*pi*tf)
__device__ __forceinline__ float cos_rev(float tf){ return __builtin_amdgcn_cosf(tf); }
#else
__device__ __forceinline__ float sin_rev(float tf){ return __sinf(6.28318530718f * tf); }
__device__ __forceinline__ float cos_rev(float tf){ return __cosf(6.28318530718f * tf); }
#endif

__device__ __forceinline__ ushort cvt_bf16(float x){
    uint u = __float_as_uint(x);
    return (ushort)((u + 0x7FFFu + ((u >> 16) & 1u)) >> 16);   // RNE
}

// ---------------- temporal rFFT on RAW sino + per-row stats; bf16-packed spec ----------------
// twiddle table T[MPAD(j)] = exp(-i*pi*j/1024): replaces ~14 sincos/thread with 4
__global__ __launch_bounds__(256) void k_tfft(const float* __restrict__ sino,
                                              float* __restrict__ psum,
                                              float* __restrict__ psq,
                                              uint* __restrict__ spec_u){
    int row = blockIdx.x;            // bc*128 + d
    __shared__ float2 z[1055];       // padded via MPAD
    __shared__ float2 T[1055];       // twiddles, padded via MPAD
    __shared__ float ls[4], lq[4];
    int tid = threadIdx.x;
    const float4* p4 = (const float4*)(sino + (size_t)row * N_TC);
    float s = 0.f, q = 0.f;
    #pragma unroll
    for (int it = 0; it < 2; ++it){
        int n4 = tid + it * 256;     // 0..511
        float4 v = p4[n4];
        s += v.x + v.y + v.z + v.w;
        q += v.x*v.x + v.y*v.y + v.z*v.z + v.w*v.w;
        int r0 = __brev((unsigned)(2*n4))     >> 22;
        int r1 = __brev((unsigned)(2*n4 + 1)) >> 22;
        z[MPAD(r0)] = make_float2(v.x, v.y);
        z[MPAD(r1)] = make_float2(v.z, v.w);
    }
    #pragma unroll
    for (int it = 0; it < 4; ++it){
        int j = tid + it * 256;      // 0..1023
        float ang = -(float)M_PI * (float)j * (1.0f / 1024.0f);
        float sn, cs; __sincosf(ang, &sn, &cs);
        T[MPAD(j)] = make_float2(cs, sn);
    }
    #pragma unroll
    for (int m = 1; m < 64; m <<= 1){
        s += __shfl_xor(s, m, 64);
        q += __shfl_xor(q, m, 64);
    }
    int w = tid >> 6, lane = tid & 63;
    if (lane == 0){ ls[w] = s; lq[w] = q; }
    __syncthreads();
    if (tid == 0){
        psum[row] = ls[0] + ls[1] + ls[2] + ls[3];
        psq[row]  = lq[0] + lq[1] + lq[2] + lq[3];
    }
    #pragma unroll
    for (int st = 0; st < 5; ++st){
        int h = 1 << (2 * st);           // 1,4,16,64,256
        int k = tid & (h - 1);
        int g = tid >> (2 * st);
        int base = (g << (2 * st + 2)) + k;
        float2 x0 = z[MPAD(base)];
        float2 x1 = z[MPAD(base + h)];
        float2 x2 = z[MPAD(base + 2 * h)];
        float2 x3 = z[MPAD(base + 3 * h)];
        float2 W1 = T[MPAD(k << (10 - 2 * st))];   // exp(-i*pi*k/h)
        float2 W2 = T[MPAD(k << (9 - 2 * st))];    // exp(-i*pi*k/(2h))
        float c1 = W1.x, s1 = W1.y, c2 = W2.x, s2 = W2.y;
        float2 t1 = make_float2(x1.x * c1 - x1.y * s1, x1.x * s1 + x1.y * c1);
        float2 t3 = make_float2(x3.x * c1 - x3.y * s1, x3.x * s1 + x3.y * c1);
        float2 y0 = make_float2(x0.x + t1.x, x0.y + t1.y);
        float2 y1 = make_float2(x0.x - t1.x, x0.y - t1.y);
        float2 y2 = make_float2(x2.x + t3.x, x2.y + t3.y);
        float2 y3 = make_float2(x2.x - t3.x, x2.y - t3.y);
        float2 u = make_float2(y2.x * c2 - y2.y * s2, y2.x * s2 + y2.y * c2);
        float2 v = make_float2(y3.x * c2 - y3.y * s2, y3.x * s2 + y3.y * c2);
        float2 wv = make_float2(v.y, -v.x);          // -i * v
        z[MPAD(base)]         = make_float2(y0.x + u.x, y0.y + u.y);
        z[MPAD(base + 2 * h)] = make_float2(y0.x - u.x, y0.y - u.y);
        z[MPAD(base + h)]     = make_float2(y1.x + wv.x, y1.y + wv.y);
        z[MPAD(base + 3 * h)] = make_float2(y1.x - wv.x, y1.y - wv.y);
        __syncthreads();
    }
    // untangle + bf16 pack: X[k] = E + W*O, W = T[k] (k<1024), W(1024) = -1
    uint* o = spec_u + (size_t)row * N_FC;
    for (int k = tid; k < 1025; k += 256){
        float2 A  = z[MPAD(k & 1023)];
        float2 Bv = z[MPAD((1024 - k) & 1023)];
        float Br = Bv.x, Bi = -Bv.y;         // conj
        float Er = 0.5f * (A.x + Br), Ei = 0.5f * (A.y + Bi);
        float Dr = 0.5f * (A.x - Br), Di = 0.5f * (A.y - Bi);
        float Or = Di, Oi = -Dr;             // O = -i*D
        float cs, sn;
        if (k < 1024){ float2 Wt = T[MPAD(k)]; cs = Wt.x; sn = Wt.y; }
        else         { cs = -1.f; sn = 0.f; }
        float Xr = Er + cs * Or - sn * Oi;
        float Xi = Ei + cs * Oi + sn * Or;
        uint pk;
        asm("v_cvt_pk_bf16_f32 %0, %1, %2" : "=v"(pk) : "v"(Xr), "v"(Xi));
        o[k] = pk;
    }
}

// ---------------- detector FFT: stats-finalize + standardize + DC fix + kd-FFT -> bf16 A ----------------
// twiddle table Tk[j] = exp(-i*pi*j/128)
__global__ __launch_bounds__(256) void k_dft(const uint* __restrict__ spec_u,
                                             const float* __restrict__ psum,
                                             const float* __restrict__ psq,
                                             const float* __restrict__ apod,
                                             ushort* __restrict__ Arp,
                                             ushort* __restrict__ Aip,
                                             float4* __restrict__ kzJ){
    int bid = blockIdx.x;
    int ft = bid >> 4, bc = bid & 15;
    int f0 = ft << 5;
    int tid = threadIdx.x;
    __shared__ float2 tile[128][33];
    __shared__ float2 Tk[128];
    __shared__ float sm[2];

    if (tid < 64){
        float s = psum[bc * 128 + tid] + psum[bc * 128 + 64 + tid];
        float q = psq[bc * 128 + tid] + psq[bc * 128 + 64 + tid];
        #pragma unroll
        for (int m = 1; m < 64; m <<= 1){
            s += __shfl_xor(s, m, 64);
            q += __shfl_xor(q, m, 64);
        }
        if (tid == 0){
            const float inv_n = 1.f / (float)(N_DETC * N_TC);
            float mean = s * inv_n;
            float var  = q * inv_n - mean * mean;
            sm[0] = mean;
            sm[1] = rsqrtf(fmaxf(var, 0.f) + 1.1920929e-7f);
        }
    }
    if (tid >= 64 && tid < 192){
        int j = tid - 64;
        float ang = -(float)M_PI * (float)j * (1.0f / 128.0f);
        float sn, cs; __sincosf(ang, &sn, &cs);
        Tk[j] = make_float2(cs, sn);
    }
    __syncthreads();
    float mean = sm[0], invstd = sm[1];

    int fl  = tid & 31;
    int kd0 = tid >> 5;
    int f = f0 + fl;
    bool fok = (f <= 1024);
    float fr = (float)f * 19531.25f;
    float oc = fr * (1.0f / 1540.0f);

    #pragma unroll
    for (int i = 0; i < 16; ++i){
        int kd = kd0 + (i << 3);
        int rkd = __brev((unsigned)kd) >> 25;
        uint u = fok ? spec_u[((size_t)(bc * 128 + kd)) * N_FC + f] : 0u;
        float vr = __uint_as_float(u << 16);
        float vi = __uint_as_float(u & 0xFFFF0000u);
        if (f == 0) vr -= mean * 2048.f;
        float sc = apod[kd] * invstd;
        tile[rkd][fl] = make_float2(vr * sc, vi * sc);
    }
    if (bc == 0){
        #pragma unroll
        for (int i = 0; i < 16; ++i){
            int kd = kd0 + (i << 3);
            int sdx = (kd < 64) ? kd : kd - 128;
            float bb = (float)sdx * 26.0416666f;
            float kq = oc * oc - bb * bb;
            float kzr = (fok && kq > 0.f) ? sqrtf(kq) : 0.f;
            float tj = 1.5e-4f * kzr;
            tj -= floorf(tj);
            kzJ[(size_t)kd * N_FP + f] = make_float4(kzr, cos_rev(tj), sin_rev(tj), 0.f);
        }
    }
    __syncthreads();
    #pragma unroll
    for (int st = 0; st < 3; ++st){
        int h = 1 << (2 * st);
        #pragma unroll
        for (int it = 0; it < 4; ++it){
            int task = tid + (it << 8);
            int ff = task & 31;
            int q  = task >> 5;
            int k = q & (h - 1);
            int g = q >> (2 * st);
            int base = (g << (2 * st + 2)) + k;
            float2 x0 = tile[base][ff];
            float2 x1 = tile[base + h][ff];
            float2 x2 = tile[base + 2 * h][ff];
            float2 x3 = tile[base + 3 * h][ff];
            float2 W1 = Tk[k << (7 - 2 * st)];   // exp(-i*pi*k/h)
            float2 W2 = Tk[k << (6 - 2 * st)];   // exp(-i*pi*k/(2h))
            float c1 = W1.x, s1 = W1.y, c2 = W2.x, s2 = W2.y;
            float2 t1 = make_float2(x1.x * c1 - x1.y * s1, x1.x * s1 + x1.y * c1);
            float2 t3 = make_float2(x3.x * c1 - x3.y * s1, x3.x * s1 + x3.y * c1);
            float2 y0 = make_float2(x0.x + t1.x, x0.y + t1.y);
            float2 y1 = make_float2(x0.x - t1.x, x0.y - t1.y);
            float2 y2 = make_float2(x2.x + t3.x, x2.y + t3.y);
            float2 y3 = make_float2(x2.x - t3.x, x2.y - t3.y);
            float2 u = make_float2(y2.x * c2 - y2.y * s2, y2.x * s2 + y2.y * c2);
            float2 v = make_float2(y3.x * c2 - y3.y * s2, y3.x * s2 + y3.y * c2);
            float2 w = make_float2(v.y, -v.x);
            tile[base][ff]         = make_float2(y0.x + u.x, y0.y + u.y);
            tile[base + 2 * h][ff] = make_float2(y0.x - u.x, y0.y - u.y);
            tile[base + h][ff]     = make_float2(y1.x + w.x, y1.y + w.y);
            tile[base + 3 * h][ff] = make_float2(y1.x - w.x, y1.y - w.y);
        }
        __syncthreads();
    }
    #pragma unroll
    for (int it = 0; it < 8; ++it){
        int task = tid + (it << 8);
        int ff = task & 31, j = task >> 5;
        int i1 = j, i2 = j + 64;
        float2 Wt = Tk[j << 1];              // exp(-i*pi*j/64)
        float sn = Wt.y, cs = Wt.x;
        float2 u = tile[i1][ff], v = tile[i2][ff];
        float2 t = make_float2(v.x * cs - v.y * sn, v.x * sn + v.y * cs);
        tile[i1][ff] = make_float2(u.x + t.x, u.y + t.y);
        tile[i2][ff] = make_float2(u.x - t.x, u.y - t.y);
    }
    __syncthreads();
    float fw = (f == 0 || f == 1024) ? 1.f : 2.f;
    #pragma unroll
    for (int i = 0; i < 16; ++i){
        int kd = kd0 + (i << 3);
        int sdx = (kd < 64) ? kd : kd - 128;
        float bb = (float)sdx * 26.0416666f;
        float m = (fok && (oc * oc - bb * bb > 0.f)) ? fw : 0.f;
        float2 v = tile[kd][fl];
        size_t o = ((size_t)kd * 16 + bc) * N_FP + f;
        Arp[o] = cvt_bf16(v.x * m);
        Aip[o] = cvt_bf16(v.y * m);
    }
}

// ---------------- band via MFMA, f-split in 4 chunks: block=(kd, yh, fc); bf16 partials ----------------
__global__ __launch_bounds__(512) void k_band(const ushort* __restrict__ Ar,
                                              const ushort* __restrict__ Ai,
                                              const float4* __restrict__ kzJ,
                                              uint* __restrict__ band_u){
    int blk = blockIdx.x;
    int fc = blk & 3;
    int yh = (blk >> 2) & 1;
    int kd = blk >> 3;
    int nt = (fc == 3) ? 9 : 8;
    int tid  = threadIdx.x;
    int wid  = tid >> 6;
    int lane = tid & 63;
    int fp = tid & 15;
    int yq = tid >> 4;
    float ymg = 1.0e-3f + 1.5e-4f * (float)(yh * 128 + yq * 4);

    __shared__ ushort Bls[2][2][128][40];

    int arow = lane & 15;
    int koff = (lane >> 4) * 8;
    int ylocal = wid * 16 + arow;
    const ushort* Arp = Ar + ((size_t)kd * 16 + arow) * N_FP + koff + fc * 256;
    const ushort* Aip = Ai + ((size_t)kd * 16 + arow) * N_FP + koff + fc * 256;
    const float4* kjb = kzJ + (size_t)kd * N_FP + fc * 256;

    auto GENC = [&](float4 k0, float4 k1, int buf){
        float t0 = ymg * k0.x; t0 -= floorf(t0);
        float t1 = ymg * k1.x; t1 -= floorf(t1);
        float cA = cos_rev(t0), sA = sin_rev(t0);
        float cB = cos_rev(t1), sB = sin_rev(t1);
        #pragma unroll
        for (int j = 0; j < 4; ++j){
            int y = yq * 4 + j;
            uint br, bi;
            asm("v_cvt_pk_bf16_f32 %0, %1, %2" : "=v"(br) : "v"(cA), "v"(cB));
            asm("v_cvt_pk_bf16_f32 %0, %1, %2" : "=v"(bi) : "v"(sA), "v"(sB));
            *(uint*)&Bls[buf][0][y][fp * 2] = br;
            *(uint*)&Bls[buf][1][y][fp * 2] = bi;
            if (j < 3){
                float nA = fmaf(cA, k0.y, -(sA * k0.z));
                float mA = fmaf(sA, k0.y,  (cA * k0.z));
                cA = nA; sA = mA;
                float nB = fmaf(cB, k1.y, -(sB * k1.z));
                float mB = fmaf(sB, k1.y,  (cB * k1.z));
                cB = nB; sB = mB;
            }
        }
    };

    f32x4 P1 = {0.f,0.f,0.f,0.f}, P2 = P1, P3 = P1, P4 = P1;

    bf16x8 car = *(const bf16x8*)(Arp);
    bf16x8 cai = *(const bf16x8*)(Aip);
    GENC(kjb[fp * 2], kjb[fp * 2 + 1], 0);
    __syncthreads();

    for (int t = 0; t < nt; ++t){
        bf16x8 nar, nai;
        float4 k0, k1;
        if (t < nt - 1){
            nar = *(const bf16x8*)(Arp + (t + 1) * 32);
            nai = *(const bf16x8*)(Aip + (t + 1) * 32);
            k0 = kjb[(t + 1) * 32 + fp * 2];
            k1 = kjb[(t + 1) * 32 + fp * 2 + 1];
        }
        int buf = t & 1;
        bf16x8 br = *(const bf16x8*)&Bls[buf][0][ylocal][koff];
        bf16x8 bi = *(const bf16x8*)&Bls[buf][1][ylocal][koff];
        P1 = __builtin_amdgcn_mfma_f32_16x16x32_bf16(car, br, P1, 0, 0, 0);
        P2 = __builtin_amdgcn_mfma_f32_16x16x32_bf16(cai, bi, P2, 0, 0, 0);
        P3 = __builtin_amdgcn_mfma_f32_16x16x32_bf16(car, bi, P3, 0, 0, 0);
        P4 = __builtin_amdgcn_mfma_f32_16x16x32_bf16(cai, br, P4, 0, 0, 0);
        if (t < nt - 1){
            GENC(k0, k1, buf ^ 1);
        }
        __syncthreads();
        if (t < nt - 1){ car = nar; cai = nai; }
    }

    int y = yh * 128 + wid * 16 + (lane & 15);
    #pragma unroll
    for (int r = 0; r < 4; ++r){
        int bc = (lane >> 4) * 4 + r;
        float cr = P1[r] - P2[r];
        float ci = P3[r] + P4[r];
        uint pk;
        asm("v_cvt_pk_bf16_f32 %0, %1, %2" : "=v"(pk) : "v"(cr), "v"(ci));
        band_u[(((size_t)fc * 128 + kd) * 16 + bc) * 256 + y] = pk;
    }
}

// ---------------- final: sum 4 bf16 partials, 128-pt inverse FFT over kd (table twiddles), |.| ----------------
__global__ __launch_bounds__(256) void k_final(const uint* __restrict__ band_u,
                                               const float* __restrict__ apod,
                                               float* __restrict__ out){
    int blk = blockIdx.x;            // bc*32 + yt
    int bc = blk >> 5, yt = blk & 31;
    __shared__ float2 tile[128][9];
    __shared__ float2 Tk[128];       // exp(-i*pi*j/128); inverse uses conj
    __shared__ float asum;
    int tid = threadIdx.x;
    if (tid < 64){
        float a = apod[tid] + apod[tid + 64];
        #pragma unroll
        for (int m = 1; m < 64; m <<= 1) a += __shfl_xor(a, m, 64);
        if (tid == 0) asum = a;
    }
    if (tid >= 64 && tid < 192){
        int j = tid - 64;
        float ang = -(float)M_PI * (float)j * (1.0f / 128.0f);
        float sn, cs; __sincosf(ang, &sn, &cs);
        Tk[j] = make_float2(cs, sn);
    }
    #pragma unroll
    for (int k2 = 0; k2 < 4; ++k2){
        int idx = tid + k2 * 256;
        int kd = idx >> 3, yi = idx & 7;
        float sr = 0.f, si = 0.f;
        #pragma unroll
        for (int p = 0; p < 4; ++p){
            uint u = band_u[(((size_t)p * 128 + kd) * 16 + bc) * 256 + yt * 8 + yi];
            sr += __uint_as_float(u << 16);
            si += __uint_as_float(u & 0xFFFF0000u);
        }
        int rkd = __brev((unsigned)kd) >> 25;   // 7-bit reverse
        tile[rkd][yi] = make_float2(sr, si);
    }
    __syncthreads();
    #pragma unroll
    for (int st = 0; st < 3; ++st){
        int h = 1 << (2 * st);            // 1,4,16
        int q  = tid >> 3;                // 0..31 quad
        int yi = tid & 7;
        int k = q & (h - 1);
        int g = q >> (2 * st);
        int base = (g << (2 * st + 2)) + k;
        float2 x0 = tile[base][yi];
        float2 x1 = tile[base + h][yi];
        float2 x2 = tile[base + 2 * h][yi];
        float2 x3 = tile[base + 3 * h][yi];
        float2 W1 = Tk[k << (7 - 2 * st)];
        float2 W2 = Tk[k << (6 - 2 * st)];
        float c1 = W1.x, s1 = -W1.y;      // conj: inverse twiddle
        float c2 = W2.x, s2 = -W2.y;
        float2 t1 = make_float2(x1.x * c1 - x1.y * s1, x1.x * s1 + x1.y * c1);
        float2 t3 = make_float2(x3.x * c1 - x3.y * s1, x3.x * s1 + x3.y * c1);
        float2 y0 = make_float2(x0.x + t1.x, x0.y + t1.y);
        float2 y1 = make_float2(x0.x - t1.x, x0.y - t1.y);
        float2 y2 = make_float2(x2.x + t3.x, x2.y + t3.y);
        float2 y3 = make_float2(x2.x - t3.x, x2.y - t3.y);
        float2 u = make_float2(y2.x * c2 - y2.y * s2, y2.x * s2 + y2.y * c2);
        float2 v = make_float2(y3.x * c2 - y3.y * s2, y3.x * s2 + y3.y * c2);
        float2 w = make_float2(-v.y, v.x);                 // +i * v (inverse)
        tile[base][yi]         = make_float2(y0.x + u.x, y0.y + u.y);
        tile[base + 2 * h][yi] = make_float2(y0.x - u.x, y0.y - u.y);
        tile[base + h][yi]     = make_float2(y1.x + w.x, y1.y + w.y);
        tile[base + 3 * h][yi] = make_float2(y1.x - w.x, y1.y - w.y);
        __syncthreads();
    }
    #pragma unroll
    for (int it = 0; it < 2; ++it){
        int task = tid + (it << 8);       // 0..511
        int yi = task & 7, j = task >> 3; // j = 0..63
        float2 Wt = Tk[j << 1];
        float cs = Wt.x, sn = -Wt.y;      // conj
        float2 u = tile[j][yi], v = tile[j + 64][yi];
        float2 t = make_float2(v.x * cs - v.y * sn, v.x * sn + v.y * cs);
        tile[j][yi]      = make_float2(u.x + t.x, u.y + t.y);
        tile[j + 64][yi] = make_float2(u.x - t.x, u.y - t.y);
    }
    __syncthreads();
    float invnorm = 1.f / (fmaxf(asum, 1.1920929e-7f) * 2048.f);
    #pragma unroll
    for (int k2 = 0; k2 < 4; ++k2){
        int idx = tid + k2 * 256;
        int x = idx & 127, yi = idx >> 7;
        float2 v = tile[x][yi];
        int y = yt * 8 + yi;
        out[((size_t)bc * 256 + y) * 128 + x] = sqrtf(v.x * v.x + v.y * v.y) * invnorm;
    }
}

extern "C" void kernel_launch(void* const* d_in, const int* in_sizes, int n_in,
                              void* d_out, int out_size, void* d_ws, size_t ws_size,
                              hipStream_t stream){
    const float* sino = (const float*)d_in[0];
    const float* apod = (const float*)d_in[1];
    float* out = (float*)d_out;
    float* W = (float*)d_ws;
    // workspace layout (float offsets):
    //   [0..2047]      psum (per row)
    //   [2048..4095]   psq
    //   4096           spec_u : 16*128*1025 uint = 2,099,200
    //   then           Ar/Ai  : 16*128*1056 ushort each (1,081,344 floats each)
    //   then           kzJ    : 128*1056 float4 (540,672 floats)
    //   then           band_u : 4*128*16*256 uint (2,097,152)
    float* psum = W;
    float* psq  = W + 2048;
    uint*   spec_u = (uint*)(W + 4096);
    ushort* Arp    = (ushort*)(W + 4096 + 2099200);
    ushort* Aip    = Arp + (size_t)16 * 128 * N_FP;
    float4* kzJ    = (float4*)(W + 4096 + 2099200 + 2162688);
    uint*   band_u = (uint*)(W + 4096 + 2099200 + 2162688 + 540672);

    k_tfft  <<<NBCC * N_DETC, 256, 0, stream>>>(sino, psum, psq, spec_u);
    k_dft   <<<33 * 16, 256, 0, stream>>>(spec_u, psum, psq, apod, Arp, Aip, kzJ);
    k_band  <<<1024, 512, 0, stream>>>(Arp, Aip, kzJ, band_u);
    k_final <<<NBCC * 32, 256, 0, stream>>>(band_u, apod, out);
}

// Round 16
// 57.820 us; speedup vs baseline: 2.3662x; 1.0469x over previous
//
#include <hip/hip_runtime.h>
#include <math.h>

#define N_DETC 128
#define N_TC   2048
#define N_FC   1025
#define N_FP   1056    // padded f (33 K-steps of 32)
#define NXC    128
#define NYC    256
#define NBCC   16      // B*C = 8*2

#define MPAD(i) ((i) + ((i) >> 5))   // LDS anti-conflict padding map

typedef short bf16x8 __attribute__((ext_vector_type(8)));
typedef float f32x4  __attribute__((ext_vector_type(4)));

__device__ __forceinline__ float2 cmulf(float2 a, float2 b){
    return make_float2(a.x*b.x - a.y*b.y, a.x*b.y + a.y*b.x);
}

#if __has_builtin(__builtin_amdgcn_sinf) && __has_builtin(__builtin_amdgcn_cosf)
__device__ __forceinline__ float sin_rev(float tf){ return __builtin_amdgcn_sinf(tf); }   // sin(2*pi*tf)
__device__ __forceinline__ float cos_rev(float tf){ return __builtin_amdgcn_cosf(tf); }
#else
__device__ __forceinline__ float sin_rev(float tf){ return __sinf(6.28318530718f * tf); }
__device__ __forceinline__ float cos_rev(float tf){ return __cosf(6.28318530718f * tf); }
#endif

__device__ __forceinline__ ushort cvt_bf16(float x){
    uint u = __float_as_uint(x);
    return (ushort)((u + 0x7FFFu + ((u >> 16) & 1u)) >> 16);   // RNE
}

// ---------------- temporal rFFT: 2 rows per block (512 thr), shared twiddle table ----------------
__global__ __launch_bounds__(512) void k_tfft(const float* __restrict__ sino,
                                              float* __restrict__ psum,
                                              float* __restrict__ psq,
                                              uint* __restrict__ spec_u){
    int r0 = blockIdx.x * 2;
    int tid = threadIdx.x;
    int half = tid >> 8;            // which row
    int t = tid & 255;
    int row = r0 + half;
    __shared__ float2 z[2][1055];   // padded via MPAD
    __shared__ float2 T[1055];      // exp(-i*pi*j/1024), shared by both rows
    __shared__ float ls[2][4], lq[2][4];
    const float4* p4 = (const float4*)(sino + (size_t)row * N_TC);
    float s = 0.f, q = 0.f;
    #pragma unroll
    for (int it = 0; it < 2; ++it){
        int n4 = t + it * 256;      // 0..511
        float4 v = p4[n4];
        s += v.x + v.y + v.z + v.w;
        q += v.x*v.x + v.y*v.y + v.z*v.z + v.w*v.w;
        int e0 = __brev((unsigned)(2 * n4))     >> 22;
        int e1 = __brev((unsigned)(2 * n4 + 1)) >> 22;
        z[half][MPAD(e0)] = make_float2(v.x, v.y);
        z[half][MPAD(e1)] = make_float2(v.z, v.w);
    }
    #pragma unroll
    for (int it = 0; it < 2; ++it){
        int j = tid + it * 512;     // 0..1023
        float ang = -(float)M_PI * (float)j * (1.0f / 1024.0f);
        float sn, cs; __sincosf(ang, &sn, &cs);
        T[MPAD(j)] = make_float2(cs, sn);
    }
    #pragma unroll
    for (int m = 1; m < 64; m <<= 1){
        s += __shfl_xor(s, m, 64);
        q += __shfl_xor(q, m, 64);
    }
    int w = tid >> 6, lane = tid & 63;
    if (lane == 0){ ls[half][w & 3] = s; lq[half][w & 3] = q; }
    __syncthreads();
    if (t == 0){
        psum[row] = ls[half][0] + ls[half][1] + ls[half][2] + ls[half][3];
        psq[row]  = lq[half][0] + lq[half][1] + lq[half][2] + lq[half][3];
    }
    #pragma unroll
    for (int st = 0; st < 5; ++st){
        int h = 1 << (2 * st);           // 1,4,16,64,256
        int k = t & (h - 1);
        int g = t >> (2 * st);
        int base = (g << (2 * st + 2)) + k;
        float2 x0 = z[half][MPAD(base)];
        float2 x1 = z[half][MPAD(base + h)];
        float2 x2 = z[half][MPAD(base + 2 * h)];
        float2 x3 = z[half][MPAD(base + 3 * h)];
        float2 W1 = T[MPAD(k << (10 - 2 * st))];   // exp(-i*pi*k/h)
        float2 W2 = T[MPAD(k << (9 - 2 * st))];    // exp(-i*pi*k/(2h))
        float c1 = W1.x, s1 = W1.y, c2 = W2.x, s2 = W2.y;
        float2 t1 = make_float2(x1.x * c1 - x1.y * s1, x1.x * s1 + x1.y * c1);
        float2 t3 = make_float2(x3.x * c1 - x3.y * s1, x3.x * s1 + x3.y * c1);
        float2 y0 = make_float2(x0.x + t1.x, x0.y + t1.y);
        float2 y1 = make_float2(x0.x - t1.x, x0.y - t1.y);
        float2 y2 = make_float2(x2.x + t3.x, x2.y + t3.y);
        float2 y3 = make_float2(x2.x - t3.x, x2.y - t3.y);
        float2 u = make_float2(y2.x * c2 - y2.y * s2, y2.x * s2 + y2.y * c2);
        float2 v = make_float2(y3.x * c2 - y3.y * s2, y3.x * s2 + y3.y * c2);
        float2 wv = make_float2(v.y, -v.x);          // -i * v
        z[half][MPAD(base)]         = make_float2(y0.x + u.x, y0.y + u.y);
        z[half][MPAD(base + 2 * h)] = make_float2(y0.x - u.x, y0.y - u.y);
        z[half][MPAD(base + h)]     = make_float2(y1.x + wv.x, y1.y + wv.y);
        z[half][MPAD(base + 3 * h)] = make_float2(y1.x - wv.x, y1.y - wv.y);
        __syncthreads();
    }
    // untangle + bf16 pack: X[k] = E + W*O, W = T[k] (k<1024), W(1024) = -1
    uint* o = spec_u + (size_t)row * N_FC;
    for (int k = t; k < 1025; k += 256){
        float2 A  = z[half][MPAD(k & 1023)];
        float2 Bv = z[half][MPAD((1024 - k) & 1023)];
        float Br = Bv.x, Bi = -Bv.y;         // conj
        float Er = 0.5f * (A.x + Br), Ei = 0.5f * (A.y + Bi);
        float Dr = 0.5f * (A.x - Br), Di = 0.5f * (A.y - Bi);
        float Or = Di, Oi = -Dr;             // O = -i*D
        float cs, sn;
        if (k < 1024){ float2 Wt = T[MPAD(k)]; cs = Wt.x; sn = Wt.y; }
        else         { cs = -1.f; sn = 0.f; }
        float Xr = Er + cs * Or - sn * Oi;
        float Xi = Ei + cs * Oi + sn * Or;
        uint pk;
        asm("v_cvt_pk_bf16_f32 %0, %1, %2" : "=v"(pk) : "v"(Xr), "v"(Xi));
        o[k] = pk;
    }
}

// ---------------- detector FFT: stats-finalize + standardize + DC fix + kd-FFT -> bf16 A ----------------
__global__ __launch_bounds__(256) void k_dft(const uint* __restrict__ spec_u,
                                             const float* __restrict__ psum,
                                             const float* __restrict__ psq,
                                             const float* __restrict__ apod,
                                             ushort* __restrict__ Arp,
                                             ushort* __restrict__ Aip,
                                             float4* __restrict__ kzJ){
    int bid = blockIdx.x;
    int ft = bid >> 4, bc = bid & 15;
    int f0 = ft << 5;
    int tid = threadIdx.x;
    __shared__ float2 tile[128][33];
    __shared__ float2 Tk[128];
    __shared__ float sm[2];

    if (tid < 64){
        float s = psum[bc * 128 + tid] + psum[bc * 128 + 64 + tid];
        float q = psq[bc * 128 + tid] + psq[bc * 128 + 64 + tid];
        #pragma unroll
        for (int m = 1; m < 64; m <<= 1){
            s += __shfl_xor(s, m, 64);
            q += __shfl_xor(q, m, 64);
        }
        if (tid == 0){
            const float inv_n = 1.f / (float)(N_DETC * N_TC);
            float mean = s * inv_n;
            float var  = q * inv_n - mean * mean;
            sm[0] = mean;
            sm[1] = rsqrtf(fmaxf(var, 0.f) + 1.1920929e-7f);
        }
    }
    if (tid >= 64 && tid < 192){
        int j = tid - 64;
        float ang = -(float)M_PI * (float)j * (1.0f / 128.0f);
        float sn, cs; __sincosf(ang, &sn, &cs);
        Tk[j] = make_float2(cs, sn);
    }
    __syncthreads();
    float mean = sm[0], invstd = sm[1];

    int fl  = tid & 31;
    int kd0 = tid >> 5;
    int f = f0 + fl;
    bool fok = (f <= 1024);
    float fr = (float)f * 19531.25f;
    float oc = fr * (1.0f / 1540.0f);

    #pragma unroll
    for (int i = 0; i < 16; ++i){
        int kd = kd0 + (i << 3);
        int rkd = __brev((unsigned)kd) >> 25;
        uint u = fok ? spec_u[((size_t)(bc * 128 + kd)) * N_FC + f] : 0u;
        float vr = __uint_as_float(u << 16);
        float vi = __uint_as_float(u & 0xFFFF0000u);
        if (f == 0) vr -= mean * 2048.f;
        float sc = apod[kd] * invstd;
        tile[rkd][fl] = make_float2(vr * sc, vi * sc);
    }
    if (bc == 0){
        #pragma unroll
        for (int i = 0; i < 16; ++i){
            int kd = kd0 + (i << 3);
            int sdx = (kd < 64) ? kd : kd - 128;
            float bb = (float)sdx * 26.0416666f;
            float kq = oc * oc - bb * bb;
            float kzr = (fok && kq > 0.f) ? sqrtf(kq) : 0.f;
            float tj = 1.5e-4f * kzr;
            tj -= floorf(tj);
            kzJ[(size_t)kd * N_FP + f] = make_float4(kzr, cos_rev(tj), sin_rev(tj), 0.f);
        }
    }
    __syncthreads();
    #pragma unroll
    for (int st = 0; st < 3; ++st){
        int h = 1 << (2 * st);
        #pragma unroll
        for (int it = 0; it < 4; ++it){
            int task = tid + (it << 8);
            int ff = task & 31;
            int q  = task >> 5;
            int k = q & (h - 1);
            int g = q >> (2 * st);
            int base = (g << (2 * st + 2)) + k;
            float2 x0 = tile[base][ff];
            float2 x1 = tile[base + h][ff];
            float2 x2 = tile[base + 2 * h][ff];
            float2 x3 = tile[base + 3 * h][ff];
            float2 W1 = Tk[k << (7 - 2 * st)];   // exp(-i*pi*k/h)
            float2 W2 = Tk[k << (6 - 2 * st)];   // exp(-i*pi*k/(2h))
            float c1 = W1.x, s1 = W1.y, c2 = W2.x, s2 = W2.y;
            float2 t1 = make_float2(x1.x * c1 - x1.y * s1, x1.x * s1 + x1.y * c1);
            float2 t3 = make_float2(x3.x * c1 - x3.y * s1, x3.x * s1 + x3.y * c1);
            float2 y0 = make_float2(x0.x + t1.x, x0.y + t1.y);
            float2 y1 = make_float2(x0.x - t1.x, x0.y - t1.y);
            float2 y2 = make_float2(x2.x + t3.x, x2.y + t3.y);
            float2 y3 = make_float2(x2.x - t3.x, x2.y - t3.y);
            float2 u = make_float2(y2.x * c2 - y2.y * s2, y2.x * s2 + y2.y * c2);
            float2 v = make_float2(y3.x * c2 - y3.y * s2, y3.x * s2 + y3.y * c2);
            float2 w = make_float2(v.y, -v.x);
            tile[base][ff]         = make_float2(y0.x + u.x, y0.y + u.y);
            tile[base + 2 * h][ff] = make_float2(y0.x - u.x, y0.y - u.y);
            tile[base + h][ff]     = make_float2(y1.x + w.x, y1.y + w.y);
            tile[base + 3 * h][ff] = make_float2(y1.x - w.x, y1.y - w.y);
        }
        __syncthreads();
    }
    #pragma unroll
    for (int it = 0; it < 8; ++it){
        int task = tid + (it << 8);
        int ff = task & 31, j = task >> 5;
        int i1 = j, i2 = j + 64;
        float2 Wt = Tk[j << 1];              // exp(-i*pi*j/64)
        float sn = Wt.y, cs = Wt.x;
        float2 u = tile[i1][ff], v = tile[i2][ff];
        float2 t = make_float2(v.x * cs - v.y * sn, v.x * sn + v.y * cs);
        tile[i1][ff] = make_float2(u.x + t.x, u.y + t.y);
        tile[i2][ff] = make_float2(u.x - t.x, u.y - t.y);
    }
    __syncthreads();
    float fw = (f == 0 || f == 1024) ? 1.f : 2.f;
    #pragma unroll
    for (int i = 0; i < 16; ++i){
        int kd = kd0 + (i << 3);
        int sdx = (kd < 64) ? kd : kd - 128;
        float bb = (float)sdx * 26.0416666f;
        float m = (fok && (oc * oc - bb * bb > 0.f)) ? fw : 0.f;
        float2 v = tile[kd][fl];
        size_t o = ((size_t)kd * 16 + bc) * N_FP + f;
        Arp[o] = cvt_bf16(v.x * m);
        Aip[o] = cvt_bf16(v.y * m);
    }
}

// ---------------- band via MFMA, f-split in 4 chunks: block=(kd, yh, fc); bf16 partials ----------------
__global__ __launch_bounds__(512) void k_band(const ushort* __restrict__ Ar,
                                              const ushort* __restrict__ Ai,
                                              const float4* __restrict__ kzJ,
                                              uint* __restrict__ band_u){
    int blk = blockIdx.x;
    int fc = blk & 3;
    int yh = (blk >> 2) & 1;
    int kd = blk >> 3;
    int nt = (fc == 3) ? 9 : 8;
    int tid  = threadIdx.x;
    int wid  = tid >> 6;
    int lane = tid & 63;
    int fp = tid & 15;
    int yq = tid >> 4;
    float ymg = 1.0e-3f + 1.5e-4f * (float)(yh * 128 + yq * 4);

    __shared__ ushort Bls[2][2][128][40];

    int arow = lane & 15;
    int koff = (lane >> 4) * 8;
    int ylocal = wid * 16 + arow;
    const ushort* Arp = Ar + ((size_t)kd * 16 + arow) * N_FP + koff + fc * 256;
    const ushort* Aip = Ai + ((size_t)kd * 16 + arow) * N_FP + koff + fc * 256;
    const float4* kjb = kzJ + (size_t)kd * N_FP + fc * 256;

    auto GENC = [&](float4 k0, float4 k1, int buf){
        float t0 = ymg * k0.x; t0 -= floorf(t0);
        float t1 = ymg * k1.x; t1 -= floorf(t1);
        float cA = cos_rev(t0), sA = sin_rev(t0);
        float cB = cos_rev(t1), sB = sin_rev(t1);
        #pragma unroll
        for (int j = 0; j < 4; ++j){
            int y = yq * 4 + j;
            uint br, bi;
            asm("v_cvt_pk_bf16_f32 %0, %1, %2" : "=v"(br) : "v"(cA), "v"(cB));
            asm("v_cvt_pk_bf16_f32 %0, %1, %2" : "=v"(bi) : "v"(sA), "v"(sB));
            *(uint*)&Bls[buf][0][y][fp * 2] = br;
            *(uint*)&Bls[buf][1][y][fp * 2] = bi;
            if (j < 3){
                float nA = fmaf(cA, k0.y, -(sA * k0.z));
                float mA = fmaf(sA, k0.y,  (cA * k0.z));
                cA = nA; sA = mA;
                float nB = fmaf(cB, k1.y, -(sB * k1.z));
                float mB = fmaf(sB, k1.y,  (cB * k1.z));
                cB = nB; sB = mB;
            }
        }
    };

    f32x4 P1 = {0.f,0.f,0.f,0.f}, P2 = P1, P3 = P1, P4 = P1;

    bf16x8 car = *(const bf16x8*)(Arp);
    bf16x8 cai = *(const bf16x8*)(Aip);
    GENC(kjb[fp * 2], kjb[fp * 2 + 1], 0);
    __syncthreads();

    for (int t = 0; t < nt; ++t){
        bf16x8 nar, nai;
        float4 k0, k1;
        if (t < nt - 1){
            nar = *(const bf16x8*)(Arp + (t + 1) * 32);
            nai = *(const bf16x8*)(Aip + (t + 1) * 32);
            k0 = kjb[(t + 1) * 32 + fp * 2];
            k1 = kjb[(t + 1) * 32 + fp * 2 + 1];
        }
        int buf = t & 1;
        bf16x8 br = *(const bf16x8*)&Bls[buf][0][ylocal][koff];
        bf16x8 bi = *(const bf16x8*)&Bls[buf][1][ylocal][koff];
        P1 = __builtin_amdgcn_mfma_f32_16x16x32_bf16(car, br, P1, 0, 0, 0);
        P2 = __builtin_amdgcn_mfma_f32_16x16x32_bf16(cai, bi, P2, 0, 0, 0);
        P3 = __builtin_amdgcn_mfma_f32_16x16x32_bf16(car, bi, P3, 0, 0, 0);
        P4 = __builtin_amdgcn_mfma_f32_16x16x32_bf16(cai, br, P4, 0, 0, 0);
        if (t < nt - 1){
            GENC(k0, k1, buf ^ 1);
        }
        __syncthreads();
        if (t < nt - 1){ car = nar; cai = nai; }
    }

    int y = yh * 128 + wid * 16 + (lane & 15);
    #pragma unroll
    for (int r = 0; r < 4; ++r){
        int bc = (lane >> 4) * 4 + r;
        float cr = P1[r] - P2[r];
        float ci = P3[r] + P4[r];
        uint pk;
        asm("v_cvt_pk_bf16_f32 %0, %1, %2" : "=v"(pk) : "v"(cr), "v"(ci));
        band_u[(((size_t)fc * 128 + kd) * 16 + bc) * 256 + y] = pk;
    }
}

// ---------------- final: 2 y-tiles per block (512 thr); sum 4 bf16 partials, inverse kd-FFT, |.| ----------------
__global__ __launch_bounds__(512) void k_final(const uint* __restrict__ band_u,
                                               const float* __restrict__ apod,
                                               float* __restrict__ out){
    int blk = blockIdx.x;            // bc*16 + ytp
    int bc = blk >> 4, ytp = blk & 15;
    int tid = threadIdx.x;
    int half = tid >> 8;
    int t = tid & 255;
    int yt = ytp * 2 + half;
    __shared__ float2 tile[2][128][9];
    __shared__ float2 Tk[128];       // exp(-i*pi*j/128); inverse uses conj
    __shared__ float asum;
    if (tid < 64){
        float a = apod[tid] + apod[tid + 64];
        #pragma unroll
        for (int m = 1; m < 64; m <<= 1) a += __shfl_xor(a, m, 64);
        if (tid == 0) asum = a;
    }
    if (tid >= 64 && tid < 192){
        int j = tid - 64;
        float ang = -(float)M_PI * (float)j * (1.0f / 128.0f);
        float sn, cs; __sincosf(ang, &sn, &cs);
        Tk[j] = make_float2(cs, sn);
    }
    #pragma unroll
    for (int k2 = 0; k2 < 4; ++k2){
        int idx = t + k2 * 256;
        int kd = idx >> 3, yi = idx & 7;
        float sr = 0.f, si = 0.f;
        #pragma unroll
        for (int p = 0; p < 4; ++p){
            uint u = band_u[(((size_t)p * 128 + kd) * 16 + bc) * 256 + yt * 8 + yi];
            sr += __uint_as_float(u << 16);
            si += __uint_as_float(u & 0xFFFF0000u);
        }
        int rkd = __brev((unsigned)kd) >> 25;   // 7-bit reverse
        tile[half][rkd][yi] = make_float2(sr, si);
    }
    __syncthreads();
    #pragma unroll
    for (int st = 0; st < 3; ++st){
        int h = 1 << (2 * st);            // 1,4,16
        int q  = t >> 3;                  // 0..31 quad
        int yi = t & 7;
        int k = q & (h - 1);
        int g = q >> (2 * st);
        int base = (g << (2 * st + 2)) + k;
        float2 x0 = tile[half][base][yi];
        float2 x1 = tile[half][base + h][yi];
        float2 x2 = tile[half][base + 2 * h][yi];
        float2 x3 = tile[half][base + 3 * h][yi];
        float2 W1 = Tk[k << (7 - 2 * st)];
        float2 W2 = Tk[k << (6 - 2 * st)];
        float c1 = W1.x, s1 = -W1.y;      // conj: inverse twiddle
        float c2 = W2.x, s2 = -W2.y;
        float2 t1 = make_float2(x1.x * c1 - x1.y * s1, x1.x * s1 + x1.y * c1);
        float2 t3 = make_float2(x3.x * c1 - x3.y * s1, x3.x * s1 + x3.y * c1);
        float2 y0 = make_float2(x0.x + t1.x, x0.y + t1.y);
        float2 y1 = make_float2(x0.x - t1.x, x0.y - t1.y);
        float2 y2 = make_float2(x2.x + t3.x, x2.y + t3.y);
        float2 y3 = make_float2(x2.x - t3.x, x2.y - t3.y);
        float2 u = make_float2(y2.x * c2 - y2.y * s2, y2.x * s2 + y2.y * c2);
        float2 v = make_float2(y3.x * c2 - y3.y * s2, y3.x * s2 + y3.y * c2);
        float2 w = make_float2(-v.y, v.x);                 // +i * v (inverse)
        tile[half][base][yi]         = make_float2(y0.x + u.x, y0.y + u.y);
        tile[half][base + 2 * h][yi] = make_float2(y0.x - u.x, y0.y - u.y);
        tile[half][base + h][yi]     = make_float2(y1.x + w.x, y1.y + w.y);
        tile[half][base + 3 * h][yi] = make_float2(y1.x - w.x, y1.y - w.y);
        __syncthreads();
    }
    #pragma unroll
    for (int it = 0; it < 2; ++it){
        int task = t + (it << 8);         // 0..511
        int yi = task & 7, j = task >> 3; // j = 0..63
        float2 Wt = Tk[j << 1];
        float cs = Wt.x, sn = -Wt.y;      // conj
        float2 u = tile[half][j][yi], v = tile[half][j + 64][yi];
        float2 tt = make_float2(v.x * cs - v.y * sn, v.x * sn + v.y * cs);
        tile[half][j][yi]      = make_float2(u.x + tt.x, u.y + tt.y);
        tile[half][j + 64][yi] = make_float2(u.x - tt.x, u.y - tt.y);
    }
    __syncthreads();
    float invnorm = 1.f / (fmaxf(asum, 1.1920929e-7f) * 2048.f);
    #pragma unroll
    for (int k2 = 0; k2 < 4; ++k2){
        int idx = t + k2 * 256;
        int x = idx & 127, yi = idx >> 7;
        float2 v = tile[half][x][yi];
        int y = yt * 8 + yi;
        out[((size_t)bc * 256 + y) * 128 + x] = sqrtf(v.x * v.x + v.y * v.y) * invnorm;
    }
}

extern "C" void kernel_launch(void* const* d_in, const int* in_sizes, int n_in,
                              void* d_out, int out_size, void* d_ws, size_t ws_size,
                              hipStream_t stream){
    const float* sino = (const float*)d_in[0];
    const float* apod = (const float*)d_in[1];
    float* out = (float*)d_out;
    float* W = (float*)d_ws;
    // workspace layout (float offsets):
    //   [0..2047]      psum (per row)
    //   [2048..4095]   psq
    //   4096           spec_u : 16*128*1025 uint = 2,099,200
    //   then           Ar/Ai  : 16*128*1056 ushort each (1,081,344 floats each)
    //   then           kzJ    : 128*1056 float4 (540,672 floats)
    //   then           band_u : 4*128*16*256 uint (2,097,152)
    float* psum = W;
    float* psq  = W + 2048;
    uint*   spec_u = (uint*)(W + 4096);
    ushort* Arp    = (ushort*)(W + 4096 + 2099200);
    ushort* Aip    = Arp + (size_t)16 * 128 * N_FP;
    float4* kzJ    = (float4*)(W + 4096 + 2099200 + 2162688);
    uint*   band_u = (uint*)(W + 4096 + 2099200 + 2162688 + 540672);

    k_tfft  <<<NBCC * N_DETC / 2, 512, 0, stream>>>(sino, psum, psq, spec_u);
    k_dft   <<<33 * 16, 256, 0, stream>>>(spec_u, psum, psq, apod, Arp, Aip, kzJ);
    k_band  <<<1024, 512, 0, stream>>>(Arp, Aip, kzJ, band_u);
    k_final <<<NBCC * 16, 512, 0, stream>>>(band_u, apod, out);
}